// Round 7
// baseline (1927.707 us; speedup 1.0000x reference)
//
#include <hip/hip_runtime.h>
#include <hip/hip_bf16.h>

#define NN 100000
#define EE 3200000
#define FIN 512
#define HH 256
#define CC 64
#define KSTEPS 10
#define SB 391    // ceil(NN/256)
#define NBUC 782  // ceil(NN/128)
#define EPB 16384 // edges per block in binning kernels
#define NEB 196   // ceil(EE/EPB)
#define NSL 4     // channel slices
#define SLC 16    // channels per slice

typedef __attribute__((ext_vector_type(8))) short bf16x8;
typedef __attribute__((ext_vector_type(8))) short s16x8;
typedef __attribute__((ext_vector_type(4))) float f32x4;
typedef __attribute__((ext_vector_type(2))) float f32x2;
typedef __attribute__((ext_vector_type(4))) int i32x4;
typedef unsigned short ushort_t;

__device__ __forceinline__ short f2bf(float f) {
    union { __hip_bfloat16 h; short s; } u;
    u.h = __float2bfloat16(f);
    return u.s;
}

__device__ __forceinline__ void glds16(const void* g, void* l) {
    __builtin_amdgcn_global_load_lds(
        (const __attribute__((address_space(1))) void*)g,
        (__attribute__((address_space(3))) void*)l, 16, 0, 0);
}

// ---------------- weight prep: transpose + bf16 ----------------
__global__ void prep_w(const float* __restrict__ w0, const float* __restrict__ w1,
                       short* __restrict__ w0t, short* __restrict__ w1t) {
    int t = blockIdx.x * blockDim.x + threadIdx.x;
    if (t < FIN * HH) {                   // w0 [512][256] -> w0t [256][512]
        int k = t >> 8, n = t & 255;
        w0t[n * FIN + k] = f2bf(w0[t]);
    } else if (t < FIN * HH + HH * CC) {  // w1 [256][64] -> w1t [64][256]
        int u = t - FIN * HH;
        int k = u >> 6, n = u & 63;
        w1t[n * HH + k] = f2bf(w1[u]);
    }
}

// ---------------- x fp32 -> bf16 streaming conversion ----------------
__global__ __launch_bounds__(256) void x2b_kernel(const float* __restrict__ x,
                                                  ushort_t* __restrict__ xb) {
    const long NTOT = (long)NN * FIN;
    long stride = (long)gridDim.x * 256 * 8;
    for (long i = ((long)blockIdx.x * 256 + threadIdx.x) * 8; i < NTOT; i += stride) {
        float4 a = *(const float4*)(x + i);
        float4 b = *(const float4*)(x + i + 4);
        s16x8 o;
        o[0] = f2bf(a.x); o[1] = f2bf(a.y); o[2] = f2bf(a.z); o[3] = f2bf(a.w);
        o[4] = f2bf(b.x); o[5] = f2bf(b.y); o[6] = f2bf(b.z); o[7] = f2bf(b.w);
        *(s16x8*)(xb + i) = o;
    }
}

// ---------------- binned CSR build ----------------
__global__ __launch_bounds__(256) void bincnt(const int* __restrict__ ei,
                                              int* __restrict__ bcnt) {
    __shared__ int hb[NBUC];
    int tid = threadIdx.x;
    int base = blockIdx.x * EPB;
    for (int i = tid; i < NBUC; i += 256) hb[i] = 0;
    __syncthreads();
#pragma unroll 4
    for (int i = 0; i < EPB / 256; ++i) {
        int t = base + i * 256 + tid;
        if (t < EE) atomicAdd(&hb[(unsigned)ei[EE + t] >> 7], 1);
    }
    __syncthreads();
    for (int i = tid; i < NBUC; i += 256)
        if (hb[i]) atomicAdd(&bcnt[i], hb[i]);
}

__global__ __launch_bounds__(1024) void bscan(const int* __restrict__ bcnt,
                                              int* __restrict__ eboff) {
    __shared__ int sh[1024];
    int t = threadIdx.x;
    int v = (t < NBUC) ? bcnt[t] : 0;
    sh[t] = v;
    __syncthreads();
    for (int off = 1; off < 1024; off <<= 1) {
        int add = (t >= off) ? sh[t - off] : 0;
        __syncthreads();
        sh[t] += add;
        __syncthreads();
    }
    if (t < NBUC) eboff[t] = sh[t] - v;
}

__global__ __launch_bounds__(256) void binfill(const int* __restrict__ ei,
                                               const int* __restrict__ eboff,
                                               int* __restrict__ bfc,
                                               int* __restrict__ stg) {
    __shared__ int hb[NBUC];
    __shared__ int lb[NBUC];
    int tid = threadIdx.x;
    int base = blockIdx.x * EPB;
    for (int i = tid; i < NBUC; i += 256) hb[i] = 0;
    __syncthreads();
#pragma unroll 4
    for (int i = 0; i < EPB / 256; ++i) {
        int t = base + i * 256 + tid;
        if (t < EE) atomicAdd(&hb[(unsigned)ei[EE + t] >> 7], 1);
    }
    __syncthreads();
    for (int i = tid; i < NBUC; i += 256) {
        int c = hb[i];
        lb[i] = eboff[i] + (c ? atomicAdd(&bfc[i], c) : 0);
        hb[i] = 0;
    }
    __syncthreads();
#pragma unroll 4
    for (int i = 0; i < EPB / 256; ++i) {
        int t = base + i * 256 + tid;
        if (t < EE) {
            int s = ei[t];
            int d = ei[EE + t];
            int b = (unsigned)d >> 7;
            int o = atomicAdd(&hb[b], 1);
            stg[lb[b] + o] = (s << 7) | (d & 127);
        }
    }
}

__global__ __launch_bounds__(256) void bhist(const int* __restrict__ stg,
                                             const int* __restrict__ eboff,
                                             const int* __restrict__ bcnt,
                                             int* __restrict__ cnt) {
    __shared__ int nc[128];
    int b = blockIdx.x, tid = threadIdx.x;
    if (tid < 128) nc[tid] = 0;
    __syncthreads();
    int s0 = eboff[b], n = bcnt[b];
    for (int i = tid; i < n; i += 256) atomicAdd(&nc[stg[s0 + i] & 127], 1);
    __syncthreads();
    int node = b * 128 + tid;
    if (tid < 128 && node < NN) cnt[node] = nc[tid];
}

__global__ __launch_bounds__(256) void deg_kernel(const int* __restrict__ cnt,
                                                  float* __restrict__ dinv,
                                                  float* __restrict__ wco,
                                                  float* __restrict__ sdg,
                                                  int* __restrict__ bsum,
                                                  int* __restrict__ dbc) {
    __shared__ int red[256];
    __shared__ int h[64];
    int tid = threadIdx.x;
    if (tid < 64) h[tid] = 0;
    int i = blockIdx.x * 256 + tid;
    int d = 0, bin = 0;
    if (i < NN) {
        int c = cnt[i];
        d = c + 1;
        bin = min(c, 63);
        float fd = (float)d;
        dinv[i] = rsqrtf(fd);
        wco[i] = 0.9f / fd;
        sdg[i] = sqrtf(fd);
    }
    red[tid] = d;
    __syncthreads();
    if (i < NN) atomicAdd(&h[bin], 1);
    for (int off = 128; off > 0; off >>= 1) {
        if (tid < off) red[tid] += red[tid + off];
        __syncthreads();
    }
    if (tid == 0) bsum[blockIdx.x] = red[0];
    if (tid < 64 && h[tid]) atomicAdd(&dbc[tid], h[tid]);
}

__global__ __launch_bounds__(512) void scanb_kernel(const int* __restrict__ bsum,
                                                    int* __restrict__ boff,
                                                    const int* __restrict__ dbc,
                                                    int* __restrict__ dboff) {
    __shared__ int sh[512];
    int t = threadIdx.x;
    int v = (t < SB) ? bsum[t] : 0;
    sh[t] = v;
    __syncthreads();
    for (int off = 1; off < 512; off <<= 1) {
        int add = (t >= off) ? sh[t - off] : 0;
        __syncthreads();
        sh[t] += add;
        __syncthreads();
    }
    if (t < SB) boff[t] = sh[t] - v;  // exclusive
    __syncthreads();
    int v2 = (t < 64) ? dbc[t] : 0;
    __syncthreads();
    if (t < 64) sh[t] = v2;
    __syncthreads();
    for (int off = 1; off < 64; off <<= 1) {
        int add = (t >= off && t < 64) ? sh[t - off] : 0;
        __syncthreads();
        if (t < 64) sh[t] += add;
        __syncthreads();
    }
    if (t < 64) dboff[t] = sh[t] - v2;
}

__global__ __launch_bounds__(256) void rp_kernel(const int* __restrict__ cnt,
                                                 const int* __restrict__ boff,
                                                 int* __restrict__ rp) {
    __shared__ int sh[256];
    int i = blockIdx.x * 256 + threadIdx.x;
    int d = (i < NN) ? cnt[i] + 1 : 0;
    sh[threadIdx.x] = d;
    __syncthreads();
    for (int off = 1; off < 256; off <<= 1) {
        int add = (threadIdx.x >= off) ? sh[threadIdx.x - off] : 0;
        __syncthreads();
        sh[threadIdx.x] += add;
        __syncthreads();
    }
    int incl = sh[threadIdx.x];
    if (i < NN) rp[i] = boff[blockIdx.x] + incl - d;
    if (i == NN - 1) rp[NN] = boff[blockIdx.x] + incl;
}

__global__ __launch_bounds__(256) void bfill2(const int* __restrict__ stg,
                                              const int* __restrict__ eboff,
                                              const int* __restrict__ bcnt,
                                              const int* __restrict__ rp,
                                              int* __restrict__ eds) {
    __shared__ int nfc[128];
    __shared__ int rpl[129];
    int b = blockIdx.x, tid = threadIdx.x;
    int nodes = min(128, NN - b * 128);
    if (tid < 128) nfc[tid] = 0;
    if (tid <= 128) rpl[tid] = rp[min(b * 128 + tid, NN)];
    __syncthreads();
    int s0 = eboff[b], n = bcnt[b];
    for (int i = tid; i < n; i += 256) {
        int e = stg[s0 + i];
        int loc = e & 127;
        int o = atomicAdd(&nfc[loc], 1);
        eds[rpl[loc] + o] = e >> 7;
    }
    __syncthreads();
    if (tid < nodes) eds[rpl[tid + 1] - 1] = b * 128 + tid;  // self loop
}

__global__ __launch_bounds__(256) void dperm(const int* __restrict__ cnt,
                                             const int* __restrict__ dboff,
                                             int* __restrict__ dfc,
                                             int* __restrict__ perm) {
    __shared__ int h[64];
    __shared__ int base[64];
    int tid = threadIdx.x;
    int i = blockIdx.x * 256 + tid;
    if (tid < 64) h[tid] = 0;
    __syncthreads();
    int bin = 0, r = 0;
    bool ok = i < NN;
    if (ok) {
        bin = min(cnt[i], 63);
        r = atomicAdd(&h[bin], 1);
    }
    __syncthreads();
    if (tid < 64) {
        int c = h[tid];
        base[tid] = dboff[tid] + (c ? atomicAdd(&dfc[tid], c) : 0);
    }
    __syncthreads();
    if (ok) perm[base[bin] + r] = i;
}

// ---------------- GEMM1: h0 = relu(xb @ w0 + b0), bf16 in/out ----------------
__global__ __launch_bounds__(256) void gemm1(const ushort_t* __restrict__ xb,
                                             const short* __restrict__ w0t,
                                             const float* __restrict__ b0,
                                             short* __restrict__ h0) {
    __shared__ __align__(16) short As[2][128 * 64];
    __shared__ __align__(16) short Bs[2][128 * 64];
    const int tid = threadIdx.x;
    const int lane = tid & 63;
    const int wid = tid >> 6;
    const int wm = wid >> 1, wn = wid & 1;        // 64x64 per wave
    const int bn0 = blockIdx.x * 128;             // 0 or 128
    const long row0 = (long)blockIdx.y * 128;
    const int rl = lane >> 3;
    const int gko = (lane & 7) ^ rl;              // pre-swizzled global k-octet

    auto stage = [&](int kt, int buf) {
#pragma unroll
        for (int j = 0; j < 4; ++j) {
            int blk = wid * 4 + j;
            const ushort_t* g = xb + (row0 + blk * 8 + rl) * FIN + kt * 64 + gko * 8;
            glds16(g, &As[buf][blk * 512]);
        }
#pragma unroll
        for (int j = 0; j < 4; ++j) {
            int blk = wid * 4 + j;
            const short* g = w0t + (size_t)(bn0 + blk * 8 + rl) * FIN + kt * 64 + gko * 8;
            glds16(g, &Bs[buf][blk * 512]);
        }
    };

    f32x4 acc[4][4] = {};
    stage(0, 0);
    __syncthreads();
    for (int kt = 0; kt < FIN / 64; ++kt) {
        int cur = kt & 1;
        if (kt < FIN / 64 - 1) stage(kt + 1, cur ^ 1);
#pragma unroll
        for (int ks = 0; ks < 2; ++ks) {
            int ko = ks * 4 + (lane >> 4);
            int slot = ko ^ (lane & 7);
            bf16x8 af[4], bfr[4];
#pragma unroll
            for (int i = 0; i < 4; ++i) {
                int row = wm * 64 + i * 16 + (lane & 15);
                af[i] = *(const bf16x8*)(&As[cur][(row * 8 + slot) * 8]);
            }
#pragma unroll
            for (int j = 0; j < 4; ++j) {
                int col = wn * 64 + j * 16 + (lane & 15);
                bfr[j] = *(const bf16x8*)(&Bs[cur][(col * 8 + slot) * 8]);
            }
#pragma unroll
            for (int i = 0; i < 4; ++i)
#pragma unroll
                for (int j = 0; j < 4; ++j)
                    acc[i][j] = __builtin_amdgcn_mfma_f32_16x16x32_bf16(af[i], bfr[j], acc[i][j], 0, 0, 0);
        }
        __syncthreads();
    }
#pragma unroll
    for (int j = 0; j < 4; ++j) {
        int gcol = bn0 + wn * 64 + j * 16 + (lane & 15);
        float bias = b0[gcol];
#pragma unroll
        for (int i = 0; i < 4; ++i)
#pragma unroll
            for (int q = 0; q < 4; ++q) {
                long grow = row0 + wm * 64 + i * 16 + (lane >> 4) * 4 + q;
                float v = acc[i][j][q] + bias;
                if (v < 0.f) v = 0.f;
                h0[grow * HH + gcol] = f2bf(v);
            }
    }
}

// ---------------- GEMM2: h = h0 @ w1 + b1; emits sliced hvb=bf16(0.1*dinv*h), v0=bf16(dinv*h) ----
__global__ __launch_bounds__(256) void gemm2(const short* __restrict__ h0,
                                             const short* __restrict__ w1t,
                                             const float* __restrict__ b1,
                                             const float* __restrict__ dinv,
                                             ushort_t* __restrict__ hvb,
                                             ushort_t* __restrict__ v0) {
    __shared__ __align__(16) short As[2][128 * 64];
    __shared__ __align__(16) short Bs[2][64 * 64];
    const int tid = threadIdx.x;
    const int lane = tid & 63;
    const int wid = tid >> 6;
    const int wm = wid >> 1, wn = wid & 1;
    const long row0 = (long)blockIdx.x * 128;
    const int rl = lane >> 3;
    const int gko = (lane & 7) ^ rl;

    auto stage = [&](int kt, int buf) {
#pragma unroll
        for (int j = 0; j < 4; ++j) {
            int blk = wid * 4 + j;
            const short* g = h0 + (row0 + blk * 8 + rl) * HH + kt * 64 + gko * 8;
            glds16(g, &As[buf][blk * 512]);
        }
#pragma unroll
        for (int j = 0; j < 2; ++j) {
            int blk = wid * 2 + j;
            const short* g = w1t + (size_t)(blk * 8 + rl) * HH + kt * 64 + gko * 8;
            glds16(g, &Bs[buf][blk * 512]);
        }
    };

    f32x4 acc[4][2] = {};
    stage(0, 0);
    __syncthreads();
    for (int kt = 0; kt < HH / 64; ++kt) {
        int cur = kt & 1;
        if (kt < HH / 64 - 1) stage(kt + 1, cur ^ 1);
#pragma unroll
        for (int ks = 0; ks < 2; ++ks) {
            int ko = ks * 4 + (lane >> 4);
            int slot = ko ^ (lane & 7);
            bf16x8 af[4], bfr[2];
#pragma unroll
            for (int i = 0; i < 4; ++i) {
                int row = wm * 64 + i * 16 + (lane & 15);
                af[i] = *(const bf16x8*)(&As[cur][(row * 8 + slot) * 8]);
            }
#pragma unroll
            for (int j = 0; j < 2; ++j) {
                int col = wn * 32 + j * 16 + (lane & 15);
                bfr[j] = *(const bf16x8*)(&Bs[cur][(col * 8 + slot) * 8]);
            }
#pragma unroll
            for (int i = 0; i < 4; ++i)
#pragma unroll
                for (int j = 0; j < 2; ++j)
                    acc[i][j] = __builtin_amdgcn_mfma_f32_16x16x32_bf16(af[i], bfr[j], acc[i][j], 0, 0, 0);
        }
        __syncthreads();
    }
#pragma unroll
    for (int i = 0; i < 4; ++i)
#pragma unroll
        for (int j = 0; j < 2; ++j) {
            int col = wn * 32 + j * 16 + (lane & 15);
            float bias = b1[col];
            int sl = col >> 4, cw = col & 15;
#pragma unroll
            for (int q = 0; q < 4; ++q) {
                long grow = row0 + wm * 64 + i * 16 + (lane >> 4) * 4 + q;
                if (grow < NN) {
                    float hval = acc[i][j][q] + bias;
                    float dv = dinv[grow];
                    size_t idx = (size_t)sl * NN * SLC + grow * SLC + cw;
                    hvb[idx] = (ushort_t)f2bf(0.1f * dv * hval);
                    v0[idx] = (ushort_t)f2bf(dv * hval);
                }
            }
        }
}

// ---------------- sliced propagation: slice = blockIdx.y, 16 ch = 8 lanes x dword ----------------
__device__ __forceinline__ void gath16(float& ax, float& ay,
                                       const ushort_t* __restrict__ vs, int src, int l) {
    int r = *(const int*)(vs + ((size_t)src << 4) + (l << 1));
    ax += __int_as_float(r << 16);
    ay += __int_as_float(r & 0xffff0000);
}

template <int LAST>
__global__ __launch_bounds__(256) void prop16(const ushort_t* __restrict__ vin,   // [4][NN][16]
                                              const ushort_t* __restrict__ hvb,   // [4][NN][16]
                                              const float* __restrict__ wco,
                                              const float* __restrict__ sdg,
                                              ushort_t* __restrict__ vout,        // [4][NN][16]
                                              float* __restrict__ zout,           // [NN][64]
                                              const int* __restrict__ rp,
                                              const int* __restrict__ eds,
                                              const int* __restrict__ perm) {
    const int slice = blockIdx.y;
    const ushort_t* vs = vin + (size_t)slice * NN * SLC;
    int g = perm[blockIdx.x * 32 + (threadIdx.x >> 3)];
    int l = threadIdx.x & 7;
    int beg = rp[g], end = rp[g + 1];
    float ax0 = 0.f, ay0 = 0.f, ax1 = 0.f, ay1 = 0.f;
    float ax2 = 0.f, ay2 = 0.f, ax3 = 0.f, ay3 = 0.f;
    int e = beg;
    int head = (beg + 3) & ~3;
    if (head > end) head = end;
    for (; e < head; ++e) gath16(ax0, ay0, vs, eds[e], l);
    for (; e + 3 < end; e += 4) {
        i32x4 ee = __builtin_nontemporal_load((const i32x4*)(eds + e));
        gath16(ax0, ay0, vs, ee[0], l);
        gath16(ax1, ay1, vs, ee[1], l);
        gath16(ax2, ay2, vs, ee[2], l);
        gath16(ax3, ay3, vs, ee[3], l);
    }
    for (; e < end; ++e) gath16(ax1, ay1, vs, eds[e], l);

    float w = wco[g];
    int hb = __builtin_nontemporal_load(
        (const int*)(hvb + (size_t)slice * NN * SLC + ((size_t)g << 4) + (l << 1)));
    float r0 = w * ((ax0 + ax1) + (ax2 + ax3)) + __int_as_float(hb << 16);
    float r1 = w * ((ay0 + ay1) + (ay2 + ay3)) + __int_as_float(hb & 0xffff0000);
    if (!LAST) {
        int o = ((int)(unsigned short)f2bf(r0)) | (((int)(unsigned short)f2bf(r1)) << 16);
        __builtin_nontemporal_store(
            o, (int*)(vout + (size_t)slice * NN * SLC + ((size_t)g << 4) + (l << 1)));
    } else {
        float sd = sdg[g];
        f32x2 o;
        o[0] = r0 * sd;
        o[1] = r1 * sd;
        *(f32x2*)(zout + ((size_t)g << 6) + slice * SLC + (l << 1)) = o;
    }
}

// ---------------- log_softmax over rows of 64, in-place on d_out ----------------
__global__ __launch_bounds__(256) void lsm(float* __restrict__ z) {
    int node = blockIdx.x * 4 + (threadIdx.x >> 6);
    if (node >= NN) return;
    int lane = threadIdx.x & 63;
    float v = z[((size_t)node << 6) + lane];
    float m = v;
#pragma unroll
    for (int off = 32; off > 0; off >>= 1) m = fmaxf(m, __shfl_xor(m, off));
    float e = expf(v - m);
    float s = e;
#pragma unroll
    for (int off = 32; off > 0; off >>= 1) s += __shfl_xor(s, off);
    z[((size_t)node << 6) + lane] = v - m - logf(s);
}

extern "C" void kernel_launch(void* const* d_in, const int* in_sizes, int n_in,
                              void* d_out, int out_size, void* d_ws, size_t ws_size,
                              hipStream_t stream) {
    const float* x  = (const float*)d_in[0];
    const float* w0 = (const float*)d_in[1];
    const float* b0 = (const float*)d_in[2];
    const float* w1 = (const float*)d_in[3];
    const float* b1 = (const float*)d_in[4];
    const int*   ei = (const int*)d_in[5];

    char* ws = (char*)d_ws;
    size_t off = 0;
    auto take = [&](size_t n) { size_t r = off; off += (n + 255) & ~(size_t)255; return r; };
    size_t o_h0    = take((size_t)100096 * HH * 2);   // bf16 h0; later reused as vB
    size_t o_vA    = take((size_t)NN * CC * 2);       // bf16 v ping buffer (sliced layout)
    size_t o_hv    = take((size_t)NN * CC * 2);       // bf16 hv (sliced); earlier aliased as stg
    size_t o_ed    = take((size_t)(EE + NN) * 4);     // CSR src indices
    size_t o_rp    = take((size_t)(NN + 1) * 4);
    size_t o_cnt   = take((size_t)NN * 4);
    size_t o_dinv  = take((size_t)NN * 4);
    size_t o_wco   = take((size_t)NN * 4);
    size_t o_sdg   = take((size_t)NN * 4);
    size_t o_perm  = take((size_t)NN * 4);
    size_t o_w0t   = take((size_t)HH * FIN * 2);
    size_t o_w1t   = take((size_t)CC * HH * 2);
    size_t o_bs    = take((size_t)SB * 4);
    size_t o_bo    = take((size_t)SB * 4);
    size_t o_eboff = take((size_t)NBUC * 4);
    size_t o_dboff = take((size_t)64 * 4);
    size_t o_z     = take((size_t)(NBUC + NBUC + 64 + 64) * 4);  // bcnt,bfc,dbc,dfc (zeroed)
    size_t o_xb    = take((size_t)100096 * FIN * 2);  // bf16 x

    short*    h0    = (short*)(ws + o_h0);
    ushort_t* vA    = (ushort_t*)(ws + o_vA);
    ushort_t* vB    = (ushort_t*)(ws + o_h0);   // alias h0 (dead after gemm2)
    ushort_t* hvb   = (ushort_t*)(ws + o_hv);
    int*      stg   = (int*)(ws + o_hv);        // alias hvb (stg dead before gemm2 writes hvb)
    int*      eds   = (int*)(ws + o_ed);
    int*      rp    = (int*)(ws + o_rp);
    int*      cnt   = (int*)(ws + o_cnt);
    float*    dinv  = (float*)(ws + o_dinv);
    float*    wco   = (float*)(ws + o_wco);
    float*    sdg   = (float*)(ws + o_sdg);
    int*      perm  = (int*)(ws + o_perm);
    short*    w0t   = (short*)(ws + o_w0t);
    short*    w1t   = (short*)(ws + o_w1t);
    int*      bs    = (int*)(ws + o_bs);
    int*      bo    = (int*)(ws + o_bo);
    int*      eboff = (int*)(ws + o_eboff);
    int*      dboff = (int*)(ws + o_dboff);
    int*      bcnt  = (int*)(ws + o_z);
    int*      bfc   = bcnt + NBUC;
    int*      dbc   = bfc + NBUC;
    int*      dfc   = dbc + 64;
    ushort_t* xb    = (ushort_t*)(ws + o_xb);
    float*    zout  = (float*)d_out;

    prep_w<<<(FIN * HH + HH * CC + 255) / 256, 256, 0, stream>>>(w0, w1, w0t, w1t);
    hipMemsetAsync(ws + o_z, 0, (size_t)(NBUC + NBUC + 64 + 64) * 4, stream);

    bincnt<<<NEB, 256, 0, stream>>>(ei, bcnt);
    bscan<<<1, 1024, 0, stream>>>(bcnt, eboff);
    binfill<<<NEB, 256, 0, stream>>>(ei, eboff, bfc, stg);
    bhist<<<NBUC, 256, 0, stream>>>(stg, eboff, bcnt, cnt);
    deg_kernel<<<SB, 256, 0, stream>>>(cnt, dinv, wco, sdg, bs, dbc);
    scanb_kernel<<<1, 512, 0, stream>>>(bs, bo, dbc, dboff);
    rp_kernel<<<SB, 256, 0, stream>>>(cnt, bo, rp);
    bfill2<<<NBUC, 256, 0, stream>>>(stg, eboff, bcnt, rp, eds);
    dperm<<<SB, 256, 0, stream>>>(cnt, dboff, dfc, perm);

    x2b_kernel<<<2048, 256, 0, stream>>>(x, xb);
    gemm1<<<dim3(2, 782), 256, 0, stream>>>(xb, w0t, b0, h0);
    gemm2<<<782, 256, 0, stream>>>(h0, w1t, b1, dinv, hvb, vA);

    const ushort_t* in = vA;
    for (int k = 0; k < KSTEPS; ++k) {
        if (k == KSTEPS - 1) {
            prop16<1><<<dim3(NN / 32, NSL), 256, 0, stream>>>(in, hvb, wco, sdg, nullptr, zout, rp, eds, perm);
        } else {
            ushort_t* o = (k & 1) ? vA : vB;
            prop16<0><<<dim3(NN / 32, NSL), 256, 0, stream>>>(in, hvb, wco, sdg, o, nullptr, rp, eds, perm);
            in = o;
        }
    }
    lsm<<<(NN + 3) / 4, 256, 0, stream>>>(zout);
}

// Round 8
// 1020.069 us; speedup vs baseline: 1.8898x; 1.8898x over previous
//
#include <hip/hip_runtime.h>
#include <hip/hip_bf16.h>

#define NN 100000
#define EE 3200000
#define FIN 512
#define HH 256
#define CC 64
#define KSTEPS 10
#define SB 391    // ceil(NN/256)
#define NBUC 782  // ceil(NN/128)
#define EPB 16384 // edges per block in binning kernels
#define NEB 196   // ceil(EE/EPB)

typedef __attribute__((ext_vector_type(8))) short bf16x8;
typedef __attribute__((ext_vector_type(8))) short s16x8;
typedef __attribute__((ext_vector_type(4))) float f32x4;
typedef __attribute__((ext_vector_type(4))) int i32x4;
typedef unsigned short ushort_t;

__device__ __forceinline__ short f2bf(float f) {
    union { __hip_bfloat16 h; short s; } u;
    u.h = __float2bfloat16(f);
    return u.s;
}

__device__ __forceinline__ void glds16(const void* g, void* l) {
    __builtin_amdgcn_global_load_lds(
        (const __attribute__((address_space(1))) void*)g,
        (__attribute__((address_space(3))) void*)l, 16, 0, 0);
}

// ---------------- weight prep: transpose + bf16 ----------------
__global__ void prep_w(const float* __restrict__ w0, const float* __restrict__ w1,
                       short* __restrict__ w0t, short* __restrict__ w1t) {
    int t = blockIdx.x * blockDim.x + threadIdx.x;
    if (t < FIN * HH) {                   // w0 [512][256] -> w0t [256][512]
        int k = t >> 8, n = t & 255;
        w0t[n * FIN + k] = f2bf(w0[t]);
    } else if (t < FIN * HH + HH * CC) {  // w1 [256][64] -> w1t [64][256]
        int u = t - FIN * HH;
        int k = u >> 6, n = u & 63;
        w1t[n * HH + k] = f2bf(w1[u]);
    }
}

// ---------------- x fp32 -> bf16 streaming conversion ----------------
__global__ __launch_bounds__(256) void x2b_kernel(const float* __restrict__ x,
                                                  ushort_t* __restrict__ xb) {
    const long NTOT = (long)NN * FIN;
    long stride = (long)gridDim.x * 256 * 8;
    for (long i = ((long)blockIdx.x * 256 + threadIdx.x) * 8; i < NTOT; i += stride) {
        float4 a = *(const float4*)(x + i);
        float4 b = *(const float4*)(x + i + 4);
        s16x8 o;
        o[0] = f2bf(a.x); o[1] = f2bf(a.y); o[2] = f2bf(a.z); o[3] = f2bf(a.w);
        o[4] = f2bf(b.x); o[5] = f2bf(b.y); o[6] = f2bf(b.z); o[7] = f2bf(b.w);
        *(s16x8*)(xb + i) = o;
    }
}

// ---------------- binned CSR build ----------------
// 1. count edges per 128-node bucket (LDS hist, block-aggregated)
__global__ __launch_bounds__(256) void bincnt(const int* __restrict__ ei,
                                              int* __restrict__ bcnt) {
    __shared__ int hb[NBUC];
    int tid = threadIdx.x;
    int base = blockIdx.x * EPB;
    for (int i = tid; i < NBUC; i += 256) hb[i] = 0;
    __syncthreads();
#pragma unroll 4
    for (int i = 0; i < EPB / 256; ++i) {
        int t = base + i * 256 + tid;
        if (t < EE) atomicAdd(&hb[(unsigned)ei[EE + t] >> 7], 1);
    }
    __syncthreads();
    for (int i = tid; i < NBUC; i += 256)
        if (hb[i]) atomicAdd(&bcnt[i], hb[i]);
}

// 2. exclusive scan of bucket counts
__global__ __launch_bounds__(1024) void bscan(const int* __restrict__ bcnt,
                                              int* __restrict__ eboff) {
    __shared__ int sh[1024];
    int t = threadIdx.x;
    int v = (t < NBUC) ? bcnt[t] : 0;
    sh[t] = v;
    __syncthreads();
    for (int off = 1; off < 1024; off <<= 1) {
        int add = (t >= off) ? sh[t - off] : 0;
        __syncthreads();
        sh[t] += add;
        __syncthreads();
    }
    if (t < NBUC) eboff[t] = sh[t] - v;
}

// 3. scatter edges into bucket-ordered staging (packed src<<7 | dst&127)
__global__ __launch_bounds__(256) void binfill(const int* __restrict__ ei,
                                               const int* __restrict__ eboff,
                                               int* __restrict__ bfc,
                                               int* __restrict__ stg) {
    __shared__ int hb[NBUC];
    __shared__ int lb[NBUC];
    int tid = threadIdx.x;
    int base = blockIdx.x * EPB;
    for (int i = tid; i < NBUC; i += 256) hb[i] = 0;
    __syncthreads();
#pragma unroll 4
    for (int i = 0; i < EPB / 256; ++i) {
        int t = base + i * 256 + tid;
        if (t < EE) atomicAdd(&hb[(unsigned)ei[EE + t] >> 7], 1);
    }
    __syncthreads();
    for (int i = tid; i < NBUC; i += 256) {
        int c = hb[i];
        lb[i] = eboff[i] + (c ? atomicAdd(&bfc[i], c) : 0);
        hb[i] = 0;
    }
    __syncthreads();
#pragma unroll 4
    for (int i = 0; i < EPB / 256; ++i) {
        int t = base + i * 256 + tid;
        if (t < EE) {
            int s = ei[t];
            int d = ei[EE + t];
            int b = (unsigned)d >> 7;
            int o = atomicAdd(&hb[b], 1);
            stg[lb[b] + o] = (s << 7) | (d & 127);
        }
    }
}

// 4. fused per-bucket finish: node hist -> local scan -> rp/coeffs -> scatter eds + self loops
//    rp[node] = eboff[b] + 128*b (self loops before b) + local_prefix
__global__ __launch_bounds__(256) void bucket_finish(
    const int* __restrict__ stg, const int* __restrict__ eboff,
    const int* __restrict__ bcnt,
    int* __restrict__ cnt, float* __restrict__ dinv, float* __restrict__ wco,
    float* __restrict__ sdg, int* __restrict__ rp, int* __restrict__ eds,
    int* __restrict__ dbc) {
    __shared__ int nc[128];
    __shared__ int sc[128];
    __shared__ int lrp[128];
    __shared__ int nfc[128];
    __shared__ int h64[64];
    int b = blockIdx.x, tid = threadIdx.x;
    int nodes = min(128, NN - b * 128);
    if (tid < 128) { nc[tid] = 0; nfc[tid] = 0; }
    if (tid < 64) h64[tid] = 0;
    __syncthreads();
    int s0 = eboff[b], n = bcnt[b];
    for (int i = tid; i < n; i += 256) atomicAdd(&nc[stg[s0 + i] & 127], 1);
    __syncthreads();
    // inclusive scan of (deg = nc+1) over the bucket's nodes
    if (tid < 128) sc[tid] = (tid < nodes) ? nc[tid] + 1 : 0;
    __syncthreads();
    for (int off = 1; off < 128; off <<= 1) {
        int add = (tid < 128 && tid >= off) ? sc[tid - off] : 0;
        __syncthreads();
        if (tid < 128) sc[tid] += add;
        __syncthreads();
    }
    int base = eboff[b] + b * 128;
    if (tid < nodes) {
        int node = b * 128 + tid;
        int c = nc[tid];
        int excl = base + sc[tid] - (c + 1);
        lrp[tid] = excl;
        rp[node] = excl;
        cnt[node] = c;
        float fd = (float)(c + 1);
        dinv[node] = rsqrtf(fd);
        wco[node] = 0.9f / fd;
        sdg[node] = sqrtf(fd);
        atomicAdd(&h64[min(c, 63)], 1);
    }
    if (b == NBUC - 1 && tid == 0) rp[NN] = base + n + nodes;
    __syncthreads();
    if (tid < 64 && h64[tid]) atomicAdd(&dbc[tid], h64[tid]);
    // scatter edges into this bucket's CSR region
    for (int i = tid; i < n; i += 256) {
        int e = stg[s0 + i];
        int loc = e & 127;
        int o = atomicAdd(&nfc[loc], 1);
        eds[lrp[loc] + o] = e >> 7;
    }
    __syncthreads();
    if (tid < nodes) eds[lrp[tid] + nc[tid]] = b * 128 + tid;  // self loop (last slot)
}

// 5. exclusive scan of the 64 degree bins
__global__ void dscan(const int* __restrict__ dbc, int* __restrict__ dboff) {
    __shared__ int sh[64];
    int t = threadIdx.x;
    int v = dbc[t];
    sh[t] = v;
    __syncthreads();
    for (int off = 1; off < 64; off <<= 1) {
        int add = (t >= off) ? sh[t - off] : 0;
        __syncthreads();
        sh[t] += add;
        __syncthreads();
    }
    dboff[t] = sh[t] - v;
}

// 6. degree-sorted permutation (counting sort, LDS rank trick)
__global__ __launch_bounds__(256) void dperm(const int* __restrict__ cnt,
                                             const int* __restrict__ dboff,
                                             int* __restrict__ dfc,
                                             int* __restrict__ perm) {
    __shared__ int h[64];
    __shared__ int base[64];
    int tid = threadIdx.x;
    int i = blockIdx.x * 256 + tid;
    if (tid < 64) h[tid] = 0;
    __syncthreads();
    int bin = 0, r = 0;
    bool ok = i < NN;
    if (ok) {
        bin = min(cnt[i], 63);
        r = atomicAdd(&h[bin], 1);
    }
    __syncthreads();
    if (tid < 64) {
        int c = h[tid];
        base[tid] = dboff[tid] + (c ? atomicAdd(&dfc[tid], c) : 0);
    }
    __syncthreads();
    if (ok) perm[base[bin] + r] = i;
}

// ---------------- GEMM1: h0 = relu(xb @ w0 + b0), bf16 in/out ----------------
__global__ __launch_bounds__(256) void gemm1(const ushort_t* __restrict__ xb,
                                             const short* __restrict__ w0t,
                                             const float* __restrict__ b0,
                                             short* __restrict__ h0) {
    __shared__ __align__(16) short As[2][128 * 64];
    __shared__ __align__(16) short Bs[2][128 * 64];
    const int tid = threadIdx.x;
    const int lane = tid & 63;
    const int wid = tid >> 6;
    const int wm = wid >> 1, wn = wid & 1;        // 64x64 per wave
    const int bn0 = blockIdx.x * 128;             // 0 or 128
    const long row0 = (long)blockIdx.y * 128;
    const int rl = lane >> 3;
    const int gko = (lane & 7) ^ rl;              // pre-swizzled global k-octet

    auto stage = [&](int kt, int buf) {
#pragma unroll
        for (int j = 0; j < 4; ++j) {
            int blk = wid * 4 + j;
            const ushort_t* g = xb + (row0 + blk * 8 + rl) * FIN + kt * 64 + gko * 8;
            glds16(g, &As[buf][blk * 512]);
        }
#pragma unroll
        for (int j = 0; j < 4; ++j) {
            int blk = wid * 4 + j;
            const short* g = w0t + (size_t)(bn0 + blk * 8 + rl) * FIN + kt * 64 + gko * 8;
            glds16(g, &Bs[buf][blk * 512]);
        }
    };

    f32x4 acc[4][4] = {};
    stage(0, 0);
    __syncthreads();
    for (int kt = 0; kt < FIN / 64; ++kt) {
        int cur = kt & 1;
        if (kt < FIN / 64 - 1) stage(kt + 1, cur ^ 1);
#pragma unroll
        for (int ks = 0; ks < 2; ++ks) {
            int ko = ks * 4 + (lane >> 4);
            int slot = ko ^ (lane & 7);
            bf16x8 af[4], bfr[4];
#pragma unroll
            for (int i = 0; i < 4; ++i) {
                int row = wm * 64 + i * 16 + (lane & 15);
                af[i] = *(const bf16x8*)(&As[cur][(row * 8 + slot) * 8]);
            }
#pragma unroll
            for (int j = 0; j < 4; ++j) {
                int col = wn * 64 + j * 16 + (lane & 15);
                bfr[j] = *(const bf16x8*)(&Bs[cur][(col * 8 + slot) * 8]);
            }
#pragma unroll
            for (int i = 0; i < 4; ++i)
#pragma unroll
                for (int j = 0; j < 4; ++j)
                    acc[i][j] = __builtin_amdgcn_mfma_f32_16x16x32_bf16(af[i], bfr[j], acc[i][j], 0, 0, 0);
        }
        __syncthreads();
    }
#pragma unroll
    for (int j = 0; j < 4; ++j) {
        int gcol = bn0 + wn * 64 + j * 16 + (lane & 15);
        float bias = b0[gcol];
#pragma unroll
        for (int i = 0; i < 4; ++i)
#pragma unroll
            for (int q = 0; q < 4; ++q) {
                long grow = row0 + wm * 64 + i * 16 + (lane >> 4) * 4 + q;
                float v = acc[i][j][q] + bias;
                if (v < 0.f) v = 0.f;
                h0[grow * HH + gcol] = f2bf(v);
            }
    }
}

// ---------------- GEMM2: h = h0 @ w1 + b1; emits hvb = bf16(0.1*dinv*h) and v0 = bf16(dinv*h) ----
__global__ __launch_bounds__(256) void gemm2(const short* __restrict__ h0,
                                             const short* __restrict__ w1t,
                                             const float* __restrict__ b1,
                                             const float* __restrict__ dinv,
                                             ushort_t* __restrict__ hvb,
                                             ushort_t* __restrict__ v0) {
    __shared__ __align__(16) short As[2][128 * 64];
    __shared__ __align__(16) short Bs[2][64 * 64];
    const int tid = threadIdx.x;
    const int lane = tid & 63;
    const int wid = tid >> 6;
    const int wm = wid >> 1, wn = wid & 1;
    const long row0 = (long)blockIdx.x * 128;
    const int rl = lane >> 3;
    const int gko = (lane & 7) ^ rl;

    auto stage = [&](int kt, int buf) {
#pragma unroll
        for (int j = 0; j < 4; ++j) {
            int blk = wid * 4 + j;
            const short* g = h0 + (row0 + blk * 8 + rl) * HH + kt * 64 + gko * 8;
            glds16(g, &As[buf][blk * 512]);
        }
#pragma unroll
        for (int j = 0; j < 2; ++j) {
            int blk = wid * 2 + j;
            const short* g = w1t + (size_t)(blk * 8 + rl) * HH + kt * 64 + gko * 8;
            glds16(g, &Bs[buf][blk * 512]);
        }
    };

    f32x4 acc[4][2] = {};
    stage(0, 0);
    __syncthreads();
    for (int kt = 0; kt < HH / 64; ++kt) {
        int cur = kt & 1;
        if (kt < HH / 64 - 1) stage(kt + 1, cur ^ 1);
#pragma unroll
        for (int ks = 0; ks < 2; ++ks) {
            int ko = ks * 4 + (lane >> 4);
            int slot = ko ^ (lane & 7);
            bf16x8 af[4], bfr[2];
#pragma unroll
            for (int i = 0; i < 4; ++i) {
                int row = wm * 64 + i * 16 + (lane & 15);
                af[i] = *(const bf16x8*)(&As[cur][(row * 8 + slot) * 8]);
            }
#pragma unroll
            for (int j = 0; j < 2; ++j) {
                int col = wn * 32 + j * 16 + (lane & 15);
                bfr[j] = *(const bf16x8*)(&Bs[cur][(col * 8 + slot) * 8]);
            }
#pragma unroll
            for (int i = 0; i < 4; ++i)
#pragma unroll
                for (int j = 0; j < 2; ++j)
                    acc[i][j] = __builtin_amdgcn_mfma_f32_16x16x32_bf16(af[i], bfr[j], acc[i][j], 0, 0, 0);
        }
        __syncthreads();
    }
#pragma unroll
    for (int i = 0; i < 4; ++i)
#pragma unroll
        for (int j = 0; j < 2; ++j) {
            int col = wn * 32 + j * 16 + (lane & 15);
            float bias = b1[col];
#pragma unroll
            for (int q = 0; q < 4; ++q) {
                long grow = row0 + wm * 64 + i * 16 + (lane >> 4) * 4 + q;
                if (grow < NN) {
                    float hval = acc[i][j][q] + bias;
                    float dv = dinv[grow];
                    hvb[grow * CC + col] = (ushort_t)f2bf(0.1f * dv * hval);
                    v0[grow * CC + col] = (ushort_t)f2bf(dv * hval);
                }
            }
        }
}

// ---------------- propagation (degree-sorted node order, 64-ch rows) ----------------
__device__ __forceinline__ void gath(float a[8], const ushort_t* __restrict__ vin,
                                     int src, int l) {
    const int4 r = *(const int4*)(vin + ((size_t)src << 6) + (l << 3));
    a[0] += __int_as_float(r.x << 16);
    a[1] += __int_as_float(r.x & 0xffff0000);
    a[2] += __int_as_float(r.y << 16);
    a[3] += __int_as_float(r.y & 0xffff0000);
    a[4] += __int_as_float(r.z << 16);
    a[5] += __int_as_float(r.z & 0xffff0000);
    a[6] += __int_as_float(r.w << 16);
    a[7] += __int_as_float(r.w & 0xffff0000);
}

template <int LAST>
__global__ __launch_bounds__(256) void prop(const ushort_t* __restrict__ vin,
                                            const ushort_t* __restrict__ hvb,
                                            const float* __restrict__ wco,
                                            const float* __restrict__ sdg,
                                            ushort_t* __restrict__ vout,
                                            float* __restrict__ zout,
                                            const int* __restrict__ rp,
                                            const int* __restrict__ eds,
                                            const int* __restrict__ perm) {
    int g = perm[blockIdx.x * 32 + (threadIdx.x >> 3)];
    int l = threadIdx.x & 7;
    int beg = rp[g], end = rp[g + 1];
    float a0[8] = {}, a1[8] = {}, a2[8] = {}, a3[8] = {};
    int e = beg;
    int head = (beg + 3) & ~3;
    if (head > end) head = end;
    for (; e < head; ++e) gath(a0, vin, eds[e], l);
    for (; e + 3 < end; e += 4) {
        i32x4 ee = __builtin_nontemporal_load((const i32x4*)(eds + e));
        gath(a0, vin, ee[0], l);
        gath(a1, vin, ee[1], l);
        gath(a2, vin, ee[2], l);
        gath(a3, vin, ee[3], l);
    }
    for (; e < end; ++e) gath(a1, vin, eds[e], l);

    float w = wco[g];
    i32x4 hb = __builtin_nontemporal_load(
        (const i32x4*)(hvb + ((size_t)g << 6) + (l << 3)));
    float tv[8];
    tv[0] = __int_as_float(hb[0] << 16);
    tv[1] = __int_as_float(hb[0] & 0xffff0000);
    tv[2] = __int_as_float(hb[1] << 16);
    tv[3] = __int_as_float(hb[1] & 0xffff0000);
    tv[4] = __int_as_float(hb[2] << 16);
    tv[5] = __int_as_float(hb[2] & 0xffff0000);
    tv[6] = __int_as_float(hb[3] << 16);
    tv[7] = __int_as_float(hb[3] & 0xffff0000);
    float r[8];
#pragma unroll
    for (int c = 0; c < 8; ++c)
        r[c] = w * ((a0[c] + a1[c]) + (a2[c] + a3[c])) + tv[c];
    if (!LAST) {
        s16x8 o;
#pragma unroll
        for (int c = 0; c < 8; ++c) o[c] = f2bf(r[c]);
        __builtin_nontemporal_store(o, (s16x8*)(vout + ((size_t)g << 6) + (l << 3)));
    } else {
        float sd = sdg[g];
#pragma unroll
        for (int c = 0; c < 8; ++c) r[c] *= sd;
        float m = r[0];
#pragma unroll
        for (int c = 1; c < 8; ++c) m = fmaxf(m, r[c]);
#pragma unroll
        for (int off = 1; off < 8; off <<= 1) m = fmaxf(m, __shfl_xor(m, off));
        float s = 0.f;
#pragma unroll
        for (int c = 0; c < 8; ++c) s += expf(r[c] - m);
#pragma unroll
        for (int off = 1; off < 8; off <<= 1) s += __shfl_xor(s, off);
        float ls = m + logf(s);
        f32x4 o0, o1;
#pragma unroll
        for (int c = 0; c < 4; ++c) { o0[c] = r[c] - ls; o1[c] = r[c + 4] - ls; }
        *(f32x4*)(zout + ((size_t)g << 6) + (l << 3)) = o0;
        *(f32x4*)(zout + ((size_t)g << 6) + (l << 3) + 4) = o1;
    }
}

extern "C" void kernel_launch(void* const* d_in, const int* in_sizes, int n_in,
                              void* d_out, int out_size, void* d_ws, size_t ws_size,
                              hipStream_t stream) {
    const float* x  = (const float*)d_in[0];
    const float* w0 = (const float*)d_in[1];
    const float* b0 = (const float*)d_in[2];
    const float* w1 = (const float*)d_in[3];
    const float* b1 = (const float*)d_in[4];
    const int*   ei = (const int*)d_in[5];

    char* ws = (char*)d_ws;
    size_t off = 0;
    auto take = [&](size_t n) { size_t r = off; off += (n + 255) & ~(size_t)255; return r; };
    size_t o_h0    = take((size_t)100096 * HH * 2);   // bf16 h0; later reused as vB
    size_t o_vA    = take((size_t)NN * CC * 2);       // bf16 v ping buffer
    size_t o_hv    = take((size_t)NN * CC * 2);       // bf16 0.1*dinv*h; earlier aliased as stg
    size_t o_ed    = take((size_t)(EE + NN) * 4);     // CSR src indices
    size_t o_rp    = take((size_t)(NN + 1) * 4);
    size_t o_cnt   = take((size_t)NN * 4);
    size_t o_dinv  = take((size_t)NN * 4);
    size_t o_wco   = take((size_t)NN * 4);
    size_t o_sdg   = take((size_t)NN * 4);
    size_t o_perm  = take((size_t)NN * 4);
    size_t o_w0t   = take((size_t)HH * FIN * 2);
    size_t o_w1t   = take((size_t)CC * HH * 2);
    size_t o_eboff = take((size_t)NBUC * 4);
    size_t o_dboff = take((size_t)64 * 4);
    size_t o_z     = take((size_t)(NBUC + NBUC + 64 + 64) * 4);  // bcnt,bfc,dbc,dfc (zeroed)
    size_t o_xb    = take((size_t)100096 * FIN * 2);  // bf16 x

    short*    h0    = (short*)(ws + o_h0);
    ushort_t* vA    = (ushort_t*)(ws + o_vA);
    ushort_t* vB    = (ushort_t*)(ws + o_h0);   // alias h0 (dead after gemm2)
    ushort_t* hvb   = (ushort_t*)(ws + o_hv);
    int*      stg   = (int*)(ws + o_hv);        // alias hvb (stg dead before gemm2 writes hvb)
    int*      eds   = (int*)(ws + o_ed);
    int*      rp    = (int*)(ws + o_rp);
    int*      cnt   = (int*)(ws + o_cnt);
    float*    dinv  = (float*)(ws + o_dinv);
    float*    wco   = (float*)(ws + o_wco);
    float*    sdg   = (float*)(ws + o_sdg);
    int*      perm  = (int*)(ws + o_perm);
    short*    w0t   = (short*)(ws + o_w0t);
    short*    w1t   = (short*)(ws + o_w1t);
    int*      eboff = (int*)(ws + o_eboff);
    int*      dboff = (int*)(ws + o_dboff);
    int*      bcnt  = (int*)(ws + o_z);
    int*      bfc   = bcnt + NBUC;
    int*      dbc   = bfc + NBUC;
    int*      dfc   = dbc + 64;
    ushort_t* xb    = (ushort_t*)(ws + o_xb);
    float*    zout  = (float*)d_out;

    prep_w<<<(FIN * HH + HH * CC + 255) / 256, 256, 0, stream>>>(w0, w1, w0t, w1t);
    hipMemsetAsync(ws + o_z, 0, (size_t)(NBUC + NBUC + 64 + 64) * 4, stream);

    bincnt<<<NEB, 256, 0, stream>>>(ei, bcnt);
    bscan<<<1, 1024, 0, stream>>>(bcnt, eboff);
    binfill<<<NEB, 256, 0, stream>>>(ei, eboff, bfc, stg);
    bucket_finish<<<NBUC, 256, 0, stream>>>(stg, eboff, bcnt, cnt, dinv, wco, sdg, rp, eds, dbc);
    dscan<<<1, 64, 0, stream>>>(dbc, dboff);
    dperm<<<SB, 256, 0, stream>>>(cnt, dboff, dfc, perm);

    x2b_kernel<<<2048, 256, 0, stream>>>(x, xb);
    gemm1<<<dim3(2, 782), 256, 0, stream>>>(xb, w0t, b0, h0);
    gemm2<<<782, 256, 0, stream>>>(h0, w1t, b1, dinv, hvb, vA);

    const ushort_t* in = vA;
    for (int k = 0; k < KSTEPS; ++k) {
        if (k == KSTEPS - 1) {
            prop<1><<<NN / 32, 256, 0, stream>>>(in, hvb, wco, sdg, nullptr, zout, rp, eds, perm);
        } else {
            ushort_t* o = (k & 1) ? vA : vB;
            prop<0><<<NN / 32, 256, 0, stream>>>(in, hvb, wco, sdg, o, nullptr, rp, eds, perm);
            in = o;
        }
    }
}

// Round 9
// 921.753 us; speedup vs baseline: 2.0913x; 1.1067x over previous
//
#include <hip/hip_runtime.h>
#include <hip/hip_bf16.h>

#define NN 100000
#define EE 3200000
#define FIN 512
#define HH 256
#define CC 64
#define KSTEPS 10
#define SB 391    // ceil(NN/256)
#define NBUC 782  // ceil(NN/128)
#define EPB 16384 // edges per block in binning kernels
#define NEB 196   // ceil(EE/EPB)

typedef __attribute__((ext_vector_type(8))) short bf16x8;
typedef __attribute__((ext_vector_type(8))) short s16x8;
typedef __attribute__((ext_vector_type(4))) float f32x4;
typedef unsigned short ushort_t;

__device__ __forceinline__ short f2bf(float f) {
    union { __hip_bfloat16 h; short s; } u;
    u.h = __float2bfloat16(f);
    return u.s;
}

__device__ __forceinline__ void glds16(const void* g, void* l) {
    __builtin_amdgcn_global_load_lds(
        (const __attribute__((address_space(1))) void*)g,
        (__attribute__((address_space(3))) void*)l, 16, 0, 0);
}

// ---------------- weight prep: transpose + bf16 ----------------
__global__ void prep_w(const float* __restrict__ w0, const float* __restrict__ w1,
                       short* __restrict__ w0t, short* __restrict__ w1t) {
    int t = blockIdx.x * blockDim.x + threadIdx.x;
    if (t < FIN * HH) {                   // w0 [512][256] -> w0t [256][512]
        int k = t >> 8, n = t & 255;
        w0t[n * FIN + k] = f2bf(w0[t]);
    } else if (t < FIN * HH + HH * CC) {  // w1 [256][64] -> w1t [64][256]
        int u = t - FIN * HH;
        int k = u >> 6, n = u & 63;
        w1t[n * HH + k] = f2bf(w1[u]);
    }
}

// ---------------- x fp32 -> bf16 streaming conversion ----------------
__global__ __launch_bounds__(256) void x2b_kernel(const float* __restrict__ x,
                                                  ushort_t* __restrict__ xb) {
    const long NTOT = (long)NN * FIN;
    long stride = (long)gridDim.x * 256 * 8;
    for (long i = ((long)blockIdx.x * 256 + threadIdx.x) * 8; i < NTOT; i += stride) {
        float4 a = *(const float4*)(x + i);
        float4 b = *(const float4*)(x + i + 4);
        s16x8 o;
        o[0] = f2bf(a.x); o[1] = f2bf(a.y); o[2] = f2bf(a.z); o[3] = f2bf(a.w);
        o[4] = f2bf(b.x); o[5] = f2bf(b.y); o[6] = f2bf(b.z); o[7] = f2bf(b.w);
        *(s16x8*)(xb + i) = o;
    }
}

// ---------------- binned CSR build ----------------
// 1. count edges per 128-node bucket (LDS hist, block-aggregated)
__global__ __launch_bounds__(256) void bincnt(const int* __restrict__ ei,
                                              int* __restrict__ bcnt) {
    __shared__ int hb[NBUC];
    int tid = threadIdx.x;
    int base = blockIdx.x * EPB;
    for (int i = tid; i < NBUC; i += 256) hb[i] = 0;
    __syncthreads();
#pragma unroll 4
    for (int i = 0; i < EPB / 256; ++i) {
        int t = base + i * 256 + tid;
        if (t < EE) atomicAdd(&hb[(unsigned)ei[EE + t] >> 7], 1);
    }
    __syncthreads();
    for (int i = tid; i < NBUC; i += 256)
        if (hb[i]) atomicAdd(&bcnt[i], hb[i]);
}

// 2. exclusive scan of bucket counts
__global__ __launch_bounds__(1024) void bscan(const int* __restrict__ bcnt,
                                              int* __restrict__ eboff) {
    __shared__ int sh[1024];
    int t = threadIdx.x;
    int v = (t < NBUC) ? bcnt[t] : 0;
    sh[t] = v;
    __syncthreads();
    for (int off = 1; off < 1024; off <<= 1) {
        int add = (t >= off) ? sh[t - off] : 0;
        __syncthreads();
        sh[t] += add;
        __syncthreads();
    }
    if (t < NBUC) eboff[t] = sh[t] - v;
}

// 3. scatter edges into bucket-ordered staging (packed src<<7 | dst&127)
__global__ __launch_bounds__(256) void binfill(const int* __restrict__ ei,
                                               const int* __restrict__ eboff,
                                               int* __restrict__ bfc,
                                               int* __restrict__ stg) {
    __shared__ int hb[NBUC];
    __shared__ int lb[NBUC];
    int tid = threadIdx.x;
    int base = blockIdx.x * EPB;
    for (int i = tid; i < NBUC; i += 256) hb[i] = 0;
    __syncthreads();
#pragma unroll 4
    for (int i = 0; i < EPB / 256; ++i) {
        int t = base + i * 256 + tid;
        if (t < EE) atomicAdd(&hb[(unsigned)ei[EE + t] >> 7], 1);
    }
    __syncthreads();
    for (int i = tid; i < NBUC; i += 256) {
        int c = hb[i];
        lb[i] = eboff[i] + (c ? atomicAdd(&bfc[i], c) : 0);
        hb[i] = 0;
    }
    __syncthreads();
#pragma unroll 4
    for (int i = 0; i < EPB / 256; ++i) {
        int t = base + i * 256 + tid;
        if (t < EE) {
            int s = ei[t];
            int d = ei[EE + t];
            int b = (unsigned)d >> 7;
            int o = atomicAdd(&hb[b], 1);
            stg[lb[b] + o] = (s << 7) | (d & 127);
        }
    }
}

// 4. fused per-bucket finish: node hist -> local scan -> rp/coeffs -> scatter eds + self loops
__global__ __launch_bounds__(256) void bucket_finish(
    const int* __restrict__ stg, const int* __restrict__ eboff,
    const int* __restrict__ bcnt,
    int* __restrict__ cnt, float* __restrict__ dinv, float* __restrict__ wco,
    float* __restrict__ sdg, int* __restrict__ rp, int* __restrict__ eds,
    int* __restrict__ dbc) {
    __shared__ int nc[128];
    __shared__ int sc[128];
    __shared__ int lrp[128];
    __shared__ int nfc[128];
    __shared__ int h64[64];
    int b = blockIdx.x, tid = threadIdx.x;
    int nodes = min(128, NN - b * 128);
    if (tid < 128) { nc[tid] = 0; nfc[tid] = 0; }
    if (tid < 64) h64[tid] = 0;
    __syncthreads();
    int s0 = eboff[b], n = bcnt[b];
    for (int i = tid; i < n; i += 256) atomicAdd(&nc[stg[s0 + i] & 127], 1);
    __syncthreads();
    if (tid < 128) sc[tid] = (tid < nodes) ? nc[tid] + 1 : 0;
    __syncthreads();
    for (int off = 1; off < 128; off <<= 1) {
        int add = (tid < 128 && tid >= off) ? sc[tid - off] : 0;
        __syncthreads();
        if (tid < 128) sc[tid] += add;
        __syncthreads();
    }
    int base = eboff[b] + b * 128;
    if (tid < nodes) {
        int node = b * 128 + tid;
        int c = nc[tid];
        int excl = base + sc[tid] - (c + 1);
        lrp[tid] = excl;
        rp[node] = excl;
        cnt[node] = c;
        float fd = (float)(c + 1);
        dinv[node] = rsqrtf(fd);
        wco[node] = 0.9f / fd;
        sdg[node] = sqrtf(fd);
        atomicAdd(&h64[min(c, 63)], 1);
    }
    if (b == NBUC - 1 && tid == 0) rp[NN] = base + n + nodes;
    __syncthreads();
    if (tid < 64 && h64[tid]) atomicAdd(&dbc[tid], h64[tid]);
    for (int i = tid; i < n; i += 256) {
        int e = stg[s0 + i];
        int loc = e & 127;
        int o = atomicAdd(&nfc[loc], 1);
        eds[lrp[loc] + o] = e >> 7;
    }
    __syncthreads();
    if (tid < nodes) eds[lrp[tid] + nc[tid]] = b * 128 + tid;  // self loop (last slot)
}

// 5. exclusive scan of the 64 degree bins
__global__ void dscan(const int* __restrict__ dbc, int* __restrict__ dboff) {
    __shared__ int sh[64];
    int t = threadIdx.x;
    int v = dbc[t];
    sh[t] = v;
    __syncthreads();
    for (int off = 1; off < 64; off <<= 1) {
        int add = (t >= off) ? sh[t - off] : 0;
        __syncthreads();
        sh[t] += add;
        __syncthreads();
    }
    dboff[t] = sh[t] - v;
}

// 6. degree-sorted permutation (counting sort, LDS rank trick)
__global__ __launch_bounds__(256) void dperm(const int* __restrict__ cnt,
                                             const int* __restrict__ dboff,
                                             int* __restrict__ dfc,
                                             int* __restrict__ perm) {
    __shared__ int h[64];
    __shared__ int base[64];
    int tid = threadIdx.x;
    int i = blockIdx.x * 256 + tid;
    if (tid < 64) h[tid] = 0;
    __syncthreads();
    int bin = 0, r = 0;
    bool ok = i < NN;
    if (ok) {
        bin = min(cnt[i], 63);
        r = atomicAdd(&h[bin], 1);
    }
    __syncthreads();
    if (tid < 64) {
        int c = h[tid];
        base[tid] = dboff[tid] + (c ? atomicAdd(&dfc[tid], c) : 0);
    }
    __syncthreads();
    if (ok) perm[base[bin] + r] = i;
}

// ---------------- GEMM1: h0 = relu(xb @ w0 + b0), bf16 in/out ----------------
__global__ __launch_bounds__(256) void gemm1(const ushort_t* __restrict__ xb,
                                             const short* __restrict__ w0t,
                                             const float* __restrict__ b0,
                                             short* __restrict__ h0) {
    __shared__ __align__(16) short As[2][128 * 64];
    __shared__ __align__(16) short Bs[2][128 * 64];
    const int tid = threadIdx.x;
    const int lane = tid & 63;
    const int wid = tid >> 6;
    const int wm = wid >> 1, wn = wid & 1;        // 64x64 per wave
    const int bn0 = blockIdx.x * 128;             // 0 or 128
    const long row0 = (long)blockIdx.y * 128;
    const int rl = lane >> 3;
    const int gko = (lane & 7) ^ rl;              // pre-swizzled global k-octet

    auto stage = [&](int kt, int buf) {
#pragma unroll
        for (int j = 0; j < 4; ++j) {
            int blk = wid * 4 + j;
            const ushort_t* g = xb + (row0 + blk * 8 + rl) * FIN + kt * 64 + gko * 8;
            glds16(g, &As[buf][blk * 512]);
        }
#pragma unroll
        for (int j = 0; j < 4; ++j) {
            int blk = wid * 4 + j;
            const short* g = w0t + (size_t)(bn0 + blk * 8 + rl) * FIN + kt * 64 + gko * 8;
            glds16(g, &Bs[buf][blk * 512]);
        }
    };

    f32x4 acc[4][4] = {};
    stage(0, 0);
    __syncthreads();
    for (int kt = 0; kt < FIN / 64; ++kt) {
        int cur = kt & 1;
        if (kt < FIN / 64 - 1) stage(kt + 1, cur ^ 1);
#pragma unroll
        for (int ks = 0; ks < 2; ++ks) {
            int ko = ks * 4 + (lane >> 4);
            int slot = ko ^ (lane & 7);
            bf16x8 af[4], bfr[4];
#pragma unroll
            for (int i = 0; i < 4; ++i) {
                int row = wm * 64 + i * 16 + (lane & 15);
                af[i] = *(const bf16x8*)(&As[cur][(row * 8 + slot) * 8]);
            }
#pragma unroll
            for (int j = 0; j < 4; ++j) {
                int col = wn * 64 + j * 16 + (lane & 15);
                bfr[j] = *(const bf16x8*)(&Bs[cur][(col * 8 + slot) * 8]);
            }
#pragma unroll
            for (int i = 0; i < 4; ++i)
#pragma unroll
                for (int j = 0; j < 4; ++j)
                    acc[i][j] = __builtin_amdgcn_mfma_f32_16x16x32_bf16(af[i], bfr[j], acc[i][j], 0, 0, 0);
        }
        __syncthreads();
    }
#pragma unroll
    for (int j = 0; j < 4; ++j) {
        int gcol = bn0 + wn * 64 + j * 16 + (lane & 15);
        float bias = b0[gcol];
#pragma unroll
        for (int i = 0; i < 4; ++i)
#pragma unroll
            for (int q = 0; q < 4; ++q) {
                long grow = row0 + wm * 64 + i * 16 + (lane >> 4) * 4 + q;
                float v = acc[i][j][q] + bias;
                if (v < 0.f) v = 0.f;
                h0[grow * HH + gcol] = f2bf(v);
            }
    }
}

// ---------------- GEMM2: h = h0 @ w1 + b1; emits hvb = bf16(0.1*dinv*h) and v0 = bf16(dinv*h) ----
__global__ __launch_bounds__(256) void gemm2(const short* __restrict__ h0,
                                             const short* __restrict__ w1t,
                                             const float* __restrict__ b1,
                                             const float* __restrict__ dinv,
                                             ushort_t* __restrict__ hvb,
                                             ushort_t* __restrict__ v0) {
    __shared__ __align__(16) short As[2][128 * 64];
    __shared__ __align__(16) short Bs[2][64 * 64];
    const int tid = threadIdx.x;
    const int lane = tid & 63;
    const int wid = tid >> 6;
    const int wm = wid >> 1, wn = wid & 1;
    const long row0 = (long)blockIdx.x * 128;
    const int rl = lane >> 3;
    const int gko = (lane & 7) ^ rl;

    auto stage = [&](int kt, int buf) {
#pragma unroll
        for (int j = 0; j < 4; ++j) {
            int blk = wid * 4 + j;
            const short* g = h0 + (row0 + blk * 8 + rl) * HH + kt * 64 + gko * 8;
            glds16(g, &As[buf][blk * 512]);
        }
#pragma unroll
        for (int j = 0; j < 2; ++j) {
            int blk = wid * 2 + j;
            const short* g = w1t + (size_t)(blk * 8 + rl) * HH + kt * 64 + gko * 8;
            glds16(g, &Bs[buf][blk * 512]);
        }
    };

    f32x4 acc[4][2] = {};
    stage(0, 0);
    __syncthreads();
    for (int kt = 0; kt < HH / 64; ++kt) {
        int cur = kt & 1;
        if (kt < HH / 64 - 1) stage(kt + 1, cur ^ 1);
#pragma unroll
        for (int ks = 0; ks < 2; ++ks) {
            int ko = ks * 4 + (lane >> 4);
            int slot = ko ^ (lane & 7);
            bf16x8 af[4], bfr[2];
#pragma unroll
            for (int i = 0; i < 4; ++i) {
                int row = wm * 64 + i * 16 + (lane & 15);
                af[i] = *(const bf16x8*)(&As[cur][(row * 8 + slot) * 8]);
            }
#pragma unroll
            for (int j = 0; j < 2; ++j) {
                int col = wn * 32 + j * 16 + (lane & 15);
                bfr[j] = *(const bf16x8*)(&Bs[cur][(col * 8 + slot) * 8]);
            }
#pragma unroll
            for (int i = 0; i < 4; ++i)
#pragma unroll
                for (int j = 0; j < 2; ++j)
                    acc[i][j] = __builtin_amdgcn_mfma_f32_16x16x32_bf16(af[i], bfr[j], acc[i][j], 0, 0, 0);
        }
        __syncthreads();
    }
#pragma unroll
    for (int i = 0; i < 4; ++i)
#pragma unroll
        for (int j = 0; j < 2; ++j) {
            int col = wn * 32 + j * 16 + (lane & 15);
            float bias = b1[col];
#pragma unroll
            for (int q = 0; q < 4; ++q) {
                long grow = row0 + wm * 64 + i * 16 + (lane >> 4) * 4 + q;
                if (grow < NN) {
                    float hval = acc[i][j][q] + bias;
                    float dv = dinv[grow];
                    hvb[grow * CC + col] = (ushort_t)f2bf(0.1f * dv * hval);
                    v0[grow * CC + col] = (ushort_t)f2bf(dv * hval);
                }
            }
        }
}

// ---------------- propagation (degree-sorted node order, 64-ch rows) ----------------
__device__ __forceinline__ void gath(float a[8], const ushort_t* __restrict__ vin,
                                     int src, int l) {
    const int4 r = *(const int4*)(vin + ((size_t)src << 6) + (l << 3));
    a[0] += __int_as_float(r.x << 16);
    a[1] += __int_as_float(r.x & 0xffff0000);
    a[2] += __int_as_float(r.y << 16);
    a[3] += __int_as_float(r.y & 0xffff0000);
    a[4] += __int_as_float(r.z << 16);
    a[5] += __int_as_float(r.z & 0xffff0000);
    a[6] += __int_as_float(r.w << 16);
    a[7] += __int_as_float(r.w & 0xffff0000);
}

template <int LAST>
__global__ __launch_bounds__(256) void prop(const ushort_t* __restrict__ vin,
                                            const ushort_t* __restrict__ hvb,
                                            const float* __restrict__ wco,
                                            const float* __restrict__ sdg,
                                            ushort_t* __restrict__ vout,
                                            float* __restrict__ zout,
                                            const int* __restrict__ rp,
                                            const int* __restrict__ eds,
                                            const int* __restrict__ perm) {
    int g = perm[blockIdx.x * 32 + (threadIdx.x >> 3)];
    int l = threadIdx.x & 7;
    int beg = rp[g], end = rp[g + 1];
    float a0[8] = {}, a1[8] = {}, a2[8] = {}, a3[8] = {};
    int e = beg;
    int head = (beg + 3) & ~3;
    if (head > end) head = end;
    for (; e < head; ++e) gath(a0, vin, eds[e], l);
    for (; e + 3 < end; e += 4) {
        int4 ee = *(const int4*)(eds + e);
        gath(a0, vin, ee.x, l);
        gath(a1, vin, ee.y, l);
        gath(a2, vin, ee.z, l);
        gath(a3, vin, ee.w, l);
    }
    for (; e < end; ++e) gath(a1, vin, eds[e], l);

    float w = wco[g];
    const int4 hb = *(const int4*)(hvb + ((size_t)g << 6) + (l << 3));
    float tv[8];
    tv[0] = __int_as_float(hb.x << 16);
    tv[1] = __int_as_float(hb.x & 0xffff0000);
    tv[2] = __int_as_float(hb.y << 16);
    tv[3] = __int_as_float(hb.y & 0xffff0000);
    tv[4] = __int_as_float(hb.z << 16);
    tv[5] = __int_as_float(hb.z & 0xffff0000);
    tv[6] = __int_as_float(hb.w << 16);
    tv[7] = __int_as_float(hb.w & 0xffff0000);
    float r[8];
#pragma unroll
    for (int c = 0; c < 8; ++c)
        r[c] = w * ((a0[c] + a1[c]) + (a2[c] + a3[c])) + tv[c];
    if (!LAST) {
        s16x8 o;
#pragma unroll
        for (int c = 0; c < 8; ++c) o[c] = f2bf(r[c]);
        *(s16x8*)(vout + ((size_t)g << 6) + (l << 3)) = o;
    } else {
        float sd = sdg[g];
#pragma unroll
        for (int c = 0; c < 8; ++c) r[c] *= sd;
        float m = r[0];
#pragma unroll
        for (int c = 1; c < 8; ++c) m = fmaxf(m, r[c]);
#pragma unroll
        for (int off = 1; off < 8; off <<= 1) m = fmaxf(m, __shfl_xor(m, off));
        float s = 0.f;
#pragma unroll
        for (int c = 0; c < 8; ++c) s += expf(r[c] - m);
#pragma unroll
        for (int off = 1; off < 8; off <<= 1) s += __shfl_xor(s, off);
        float ls = m + logf(s);
        f32x4 o0, o1;
#pragma unroll
        for (int c = 0; c < 4; ++c) { o0[c] = r[c] - ls; o1[c] = r[c + 4] - ls; }
        *(f32x4*)(zout + ((size_t)g << 6) + (l << 3)) = o0;
        *(f32x4*)(zout + ((size_t)g << 6) + (l << 3) + 4) = o1;
    }
}

extern "C" void kernel_launch(void* const* d_in, const int* in_sizes, int n_in,
                              void* d_out, int out_size, void* d_ws, size_t ws_size,
                              hipStream_t stream) {
    const float* x  = (const float*)d_in[0];
    const float* w0 = (const float*)d_in[1];
    const float* b0 = (const float*)d_in[2];
    const float* w1 = (const float*)d_in[3];
    const float* b1 = (const float*)d_in[4];
    const int*   ei = (const int*)d_in[5];

    char* ws = (char*)d_ws;
    size_t off = 0;
    auto take = [&](size_t n) { size_t r = off; off += (n + 255) & ~(size_t)255; return r; };
    size_t o_h0    = take((size_t)100096 * HH * 2);   // bf16 h0; later reused as vB
    size_t o_vA    = take((size_t)NN * CC * 2);       // bf16 v ping buffer
    size_t o_hv    = take((size_t)NN * CC * 2);       // bf16 0.1*dinv*h; earlier aliased as stg
    size_t o_ed    = take((size_t)(EE + NN) * 4);     // CSR src indices
    size_t o_rp    = take((size_t)(NN + 1) * 4);
    size_t o_cnt   = take((size_t)NN * 4);
    size_t o_dinv  = take((size_t)NN * 4);
    size_t o_wco   = take((size_t)NN * 4);
    size_t o_sdg   = take((size_t)NN * 4);
    size_t o_perm  = take((size_t)NN * 4);
    size_t o_w0t   = take((size_t)HH * FIN * 2);
    size_t o_w1t   = take((size_t)CC * HH * 2);
    size_t o_eboff = take((size_t)NBUC * 4);
    size_t o_dboff = take((size_t)64 * 4);
    size_t o_z     = take((size_t)(NBUC + NBUC + 64 + 64) * 4);  // bcnt,bfc,dbc,dfc (zeroed)
    size_t o_xb    = take((size_t)100096 * FIN * 2);  // bf16 x

    short*    h0    = (short*)(ws + o_h0);
    ushort_t* vA    = (ushort_t*)(ws + o_vA);
    ushort_t* vB    = (ushort_t*)(ws + o_h0);   // alias h0 (dead after gemm2)
    ushort_t* hvb   = (ushort_t*)(ws + o_hv);
    int*      stg   = (int*)(ws + o_hv);        // alias hvb (stg dead before gemm2 writes hvb)
    int*      eds   = (int*)(ws + o_ed);
    int*      rp    = (int*)(ws + o_rp);
    int*      cnt   = (int*)(ws + o_cnt);
    float*    dinv  = (float*)(ws + o_dinv);
    float*    wco   = (float*)(ws + o_wco);
    float*    sdg   = (float*)(ws + o_sdg);
    int*      perm  = (int*)(ws + o_perm);
    short*    w0t   = (short*)(ws + o_w0t);
    short*    w1t   = (short*)(ws + o_w1t);
    int*      eboff = (int*)(ws + o_eboff);
    int*      dboff = (int*)(ws + o_dboff);
    int*      bcnt  = (int*)(ws + o_z);
    int*      bfc   = bcnt + NBUC;
    int*      dbc   = bfc + NBUC;
    int*      dfc   = dbc + 64;
    ushort_t* xb    = (ushort_t*)(ws + o_xb);
    float*    zout  = (float*)d_out;

    prep_w<<<(FIN * HH + HH * CC + 255) / 256, 256, 0, stream>>>(w0, w1, w0t, w1t);
    hipMemsetAsync(ws + o_z, 0, (size_t)(NBUC + NBUC + 64 + 64) * 4, stream);

    bincnt<<<NEB, 256, 0, stream>>>(ei, bcnt);
    bscan<<<1, 1024, 0, stream>>>(bcnt, eboff);
    binfill<<<NEB, 256, 0, stream>>>(ei, eboff, bfc, stg);
    bucket_finish<<<NBUC, 256, 0, stream>>>(stg, eboff, bcnt, cnt, dinv, wco, sdg, rp, eds, dbc);
    dscan<<<1, 64, 0, stream>>>(dbc, dboff);
    dperm<<<SB, 256, 0, stream>>>(cnt, dboff, dfc, perm);

    x2b_kernel<<<2048, 256, 0, stream>>>(x, xb);
    gemm1<<<dim3(2, 782), 256, 0, stream>>>(xb, w0t, b0, h0);
    gemm2<<<782, 256, 0, stream>>>(h0, w1t, b1, dinv, hvb, vA);

    const ushort_t* in = vA;
    for (int k = 0; k < KSTEPS; ++k) {
        if (k == KSTEPS - 1) {
            prop<1><<<NN / 32, 256, 0, stream>>>(in, hvb, wco, sdg, nullptr, zout, rp, eds, perm);
        } else {
            ushort_t* o = (k & 1) ? vA : vB;
            prop<0><<<NN / 32, 256, 0, stream>>>(in, hvb, wco, sdg, o, nullptr, rp, eds, perm);
            in = o;
        }
    }
}

// Round 10
// 880.818 us; speedup vs baseline: 2.1885x; 1.0465x over previous
//
#include <hip/hip_runtime.h>
#include <hip/hip_bf16.h>

#define NN 100000
#define EE 3200000
#define FIN 512
#define HH 256
#define CC 64
#define KSTEPS 10
#define SB 391    // ceil(NN/256)
#define NBUC 782  // ceil(NN/128)
#define EPB 4096  // edges per block in binning kernels (4x occupancy vs 16384)
#define NEB 782   // ceil(EE/EPB)

typedef __attribute__((ext_vector_type(8))) short bf16x8;
typedef __attribute__((ext_vector_type(8))) short s16x8;
typedef __attribute__((ext_vector_type(4))) float f32x4;
typedef unsigned short ushort_t;

__device__ __forceinline__ short f2bf(float f) {
    union { __hip_bfloat16 h; short s; } u;
    u.h = __float2bfloat16(f);
    return u.s;
}

__device__ __forceinline__ void glds16(const void* g, void* l) {
    __builtin_amdgcn_global_load_lds(
        (const __attribute__((address_space(1))) void*)g,
        (__attribute__((address_space(3))) void*)l, 16, 0, 0);
}

// ---------------- weight prep: transpose + bf16 ----------------
__global__ void prep_w(const float* __restrict__ w0, const float* __restrict__ w1,
                       short* __restrict__ w0t, short* __restrict__ w1t) {
    int t = blockIdx.x * blockDim.x + threadIdx.x;
    if (t < FIN * HH) {                   // w0 [512][256] -> w0t [256][512]
        int k = t >> 8, n = t & 255;
        w0t[n * FIN + k] = f2bf(w0[t]);
    } else if (t < FIN * HH + HH * CC) {  // w1 [256][64] -> w1t [64][256]
        int u = t - FIN * HH;
        int k = u >> 6, n = u & 63;
        w1t[n * HH + k] = f2bf(w1[u]);
    }
}

// ---------------- x fp32 -> bf16 streaming conversion ----------------
__global__ __launch_bounds__(256) void x2b_kernel(const float* __restrict__ x,
                                                  ushort_t* __restrict__ xb) {
    const long NTOT = (long)NN * FIN;
    long stride = (long)gridDim.x * 256 * 8;
    for (long i = ((long)blockIdx.x * 256 + threadIdx.x) * 8; i < NTOT; i += stride) {
        float4 a = *(const float4*)(x + i);
        float4 b = *(const float4*)(x + i + 4);
        s16x8 o;
        o[0] = f2bf(a.x); o[1] = f2bf(a.y); o[2] = f2bf(a.z); o[3] = f2bf(a.w);
        o[4] = f2bf(b.x); o[5] = f2bf(b.y); o[6] = f2bf(b.z); o[7] = f2bf(b.w);
        *(s16x8*)(xb + i) = o;
    }
}

// ---------------- binned CSR build ----------------
// 1. count edges per 128-node bucket (LDS hist, block-aggregated)
__global__ __launch_bounds__(256) void bincnt(const int* __restrict__ ei,
                                              int* __restrict__ bcnt) {
    __shared__ int hb[NBUC];
    int tid = threadIdx.x;
    int base = blockIdx.x * EPB;
    for (int i = tid; i < NBUC; i += 256) hb[i] = 0;
    __syncthreads();
#pragma unroll 4
    for (int i = 0; i < EPB / 256; ++i) {
        int t = base + i * 256 + tid;
        if (t < EE) atomicAdd(&hb[(unsigned)ei[EE + t] >> 7], 1);
    }
    __syncthreads();
    for (int i = tid; i < NBUC; i += 256)
        if (hb[i]) atomicAdd(&bcnt[i], hb[i]);
}

// 2. exclusive scan of bucket counts
__global__ __launch_bounds__(1024) void bscan(const int* __restrict__ bcnt,
                                              int* __restrict__ eboff) {
    __shared__ int sh[1024];
    int t = threadIdx.x;
    int v = (t < NBUC) ? bcnt[t] : 0;
    sh[t] = v;
    __syncthreads();
    for (int off = 1; off < 1024; off <<= 1) {
        int add = (t >= off) ? sh[t - off] : 0;
        __syncthreads();
        sh[t] += add;
        __syncthreads();
    }
    if (t < NBUC) eboff[t] = sh[t] - v;
}

// 3. scatter edges into bucket-ordered staging (packed src<<7 | dst&127)
__global__ __launch_bounds__(256) void binfill(const int* __restrict__ ei,
                                               const int* __restrict__ eboff,
                                               int* __restrict__ bfc,
                                               int* __restrict__ stg) {
    __shared__ int hb[NBUC];
    __shared__ int lb[NBUC];
    int tid = threadIdx.x;
    int base = blockIdx.x * EPB;
    for (int i = tid; i < NBUC; i += 256) hb[i] = 0;
    __syncthreads();
#pragma unroll 4
    for (int i = 0; i < EPB / 256; ++i) {
        int t = base + i * 256 + tid;
        if (t < EE) atomicAdd(&hb[(unsigned)ei[EE + t] >> 7], 1);
    }
    __syncthreads();
    for (int i = tid; i < NBUC; i += 256) {
        int c = hb[i];
        lb[i] = eboff[i] + (c ? atomicAdd(&bfc[i], c) : 0);
        hb[i] = 0;
    }
    __syncthreads();
#pragma unroll 4
    for (int i = 0; i < EPB / 256; ++i) {
        int t = base + i * 256 + tid;
        if (t < EE) {
            int s = ei[t];
            int d = ei[EE + t];
            int b = (unsigned)d >> 7;
            int o = atomicAdd(&hb[b], 1);
            stg[lb[b] + o] = (s << 7) | (d & 127);
        }
    }
}

// 4. fused per-bucket finish with SRC-RANGE-ORDERED scatter:
//    per node, edges grouped by src>>14 (8 ranges of 16K nodes = 2 MB of v each)
//    so prop's sequential edge walk sweeps v in phase across all blocks.
__global__ __launch_bounds__(256) void bucket_finish(
    const int* __restrict__ stg, const int* __restrict__ eboff,
    const int* __restrict__ bcnt,
    int* __restrict__ cnt, float* __restrict__ dinv, float* __restrict__ wco,
    float* __restrict__ sdg, int* __restrict__ rp, int* __restrict__ eds,
    int* __restrict__ dbc) {
    __shared__ int nc8[128 * 8];   // per-(node,range) counts -> running offsets
    __shared__ int nc[128];        // per-node totals
    __shared__ int sc[128];
    __shared__ int lrp[128];
    __shared__ int h64[64];
    int b = blockIdx.x, tid = threadIdx.x;
    int nodes = min(128, NN - b * 128);
    for (int i = tid; i < 128 * 8; i += 256) nc8[i] = 0;
    if (tid < 64) h64[tid] = 0;
    __syncthreads();
    int s0 = eboff[b], n = bcnt[b];
    for (int i = tid; i < n; i += 256) {
        int e = stg[s0 + i];
        atomicAdd(&nc8[(e & 127) * 8 + ((e >> 7) >> 14)], 1);
    }
    __syncthreads();
    if (tid < 128) {
        int excl = 0;
#pragma unroll
        for (int r = 0; r < 8; ++r) {
            int c = nc8[tid * 8 + r];
            nc8[tid * 8 + r] = excl;   // exclusive offset within node's list
            excl += c;
        }
        nc[tid] = excl;
        sc[tid] = (tid < nodes) ? excl + 1 : 0;   // +1 self loop
    }
    __syncthreads();
    for (int off = 1; off < 128; off <<= 1) {
        int add = (tid < 128 && tid >= off) ? sc[tid - off] : 0;
        __syncthreads();
        if (tid < 128) sc[tid] += add;
        __syncthreads();
    }
    int base = eboff[b] + b * 128;
    if (tid < nodes) {
        int node = b * 128 + tid;
        int c = nc[tid];
        int excl = base + sc[tid] - (c + 1);
        lrp[tid] = excl;
        rp[node] = excl;
        cnt[node] = c;
        float fd = (float)(c + 1);
        dinv[node] = rsqrtf(fd);
        wco[node] = 0.9f / fd;
        sdg[node] = sqrtf(fd);
        atomicAdd(&h64[min(c, 63)], 1);
    }
    if (b == NBUC - 1 && tid == 0) rp[NN] = base + n + nodes;
    __syncthreads();
    if (tid < 64 && h64[tid]) atomicAdd(&dbc[tid], h64[tid]);
    for (int i = tid; i < n; i += 256) {
        int e = stg[s0 + i];
        int src = e >> 7, loc = e & 127;
        int o = atomicAdd(&nc8[loc * 8 + (src >> 14)], 1);
        eds[lrp[loc] + o] = src;
    }
    __syncthreads();
    if (tid < nodes) eds[lrp[tid] + nc[tid]] = b * 128 + tid;  // self loop (last slot)
}

// 5. exclusive scan of the 64 degree bins
__global__ void dscan(const int* __restrict__ dbc, int* __restrict__ dboff) {
    __shared__ int sh[64];
    int t = threadIdx.x;
    int v = dbc[t];
    sh[t] = v;
    __syncthreads();
    for (int off = 1; off < 64; off <<= 1) {
        int add = (t >= off) ? sh[t - off] : 0;
        __syncthreads();
        sh[t] += add;
        __syncthreads();
    }
    dboff[t] = sh[t] - v;
}

// 6. degree-sorted permutation (counting sort, LDS rank trick)
__global__ __launch_bounds__(256) void dperm(const int* __restrict__ cnt,
                                             const int* __restrict__ dboff,
                                             int* __restrict__ dfc,
                                             int* __restrict__ perm) {
    __shared__ int h[64];
    __shared__ int base[64];
    int tid = threadIdx.x;
    int i = blockIdx.x * 256 + tid;
    if (tid < 64) h[tid] = 0;
    __syncthreads();
    int bin = 0, r = 0;
    bool ok = i < NN;
    if (ok) {
        bin = min(cnt[i], 63);
        r = atomicAdd(&h[bin], 1);
    }
    __syncthreads();
    if (tid < 64) {
        int c = h[tid];
        base[tid] = dboff[tid] + (c ? atomicAdd(&dfc[tid], c) : 0);
    }
    __syncthreads();
    if (ok) perm[base[bin] + r] = i;
}

// ---------------- GEMM1: h0 = relu(xb @ w0 + b0), bf16 in/out ----------------
__global__ __launch_bounds__(256) void gemm1(const ushort_t* __restrict__ xb,
                                             const short* __restrict__ w0t,
                                             const float* __restrict__ b0,
                                             short* __restrict__ h0) {
    __shared__ __align__(16) short As[2][128 * 64];
    __shared__ __align__(16) short Bs[2][128 * 64];
    const int tid = threadIdx.x;
    const int lane = tid & 63;
    const int wid = tid >> 6;
    const int wm = wid >> 1, wn = wid & 1;        // 64x64 per wave
    const int bn0 = blockIdx.x * 128;             // 0 or 128
    const long row0 = (long)blockIdx.y * 128;
    const int rl = lane >> 3;
    const int gko = (lane & 7) ^ rl;              // pre-swizzled global k-octet

    auto stage = [&](int kt, int buf) {
#pragma unroll
        for (int j = 0; j < 4; ++j) {
            int blk = wid * 4 + j;
            const ushort_t* g = xb + (row0 + blk * 8 + rl) * FIN + kt * 64 + gko * 8;
            glds16(g, &As[buf][blk * 512]);
        }
#pragma unroll
        for (int j = 0; j < 4; ++j) {
            int blk = wid * 4 + j;
            const short* g = w0t + (size_t)(bn0 + blk * 8 + rl) * FIN + kt * 64 + gko * 8;
            glds16(g, &Bs[buf][blk * 512]);
        }
    };

    f32x4 acc[4][4] = {};
    stage(0, 0);
    __syncthreads();
    for (int kt = 0; kt < FIN / 64; ++kt) {
        int cur = kt & 1;
        if (kt < FIN / 64 - 1) stage(kt + 1, cur ^ 1);
#pragma unroll
        for (int ks = 0; ks < 2; ++ks) {
            int ko = ks * 4 + (lane >> 4);
            int slot = ko ^ (lane & 7);
            bf16x8 af[4], bfr[4];
#pragma unroll
            for (int i = 0; i < 4; ++i) {
                int row = wm * 64 + i * 16 + (lane & 15);
                af[i] = *(const bf16x8*)(&As[cur][(row * 8 + slot) * 8]);
            }
#pragma unroll
            for (int j = 0; j < 4; ++j) {
                int col = wn * 64 + j * 16 + (lane & 15);
                bfr[j] = *(const bf16x8*)(&Bs[cur][(col * 8 + slot) * 8]);
            }
#pragma unroll
            for (int i = 0; i < 4; ++i)
#pragma unroll
                for (int j = 0; j < 4; ++j)
                    acc[i][j] = __builtin_amdgcn_mfma_f32_16x16x32_bf16(af[i], bfr[j], acc[i][j], 0, 0, 0);
        }
        __syncthreads();
    }
#pragma unroll
    for (int j = 0; j < 4; ++j) {
        int gcol = bn0 + wn * 64 + j * 16 + (lane & 15);
        float bias = b0[gcol];
#pragma unroll
        for (int i = 0; i < 4; ++i)
#pragma unroll
            for (int q = 0; q < 4; ++q) {
                long grow = row0 + wm * 64 + i * 16 + (lane >> 4) * 4 + q;
                float v = acc[i][j][q] + bias;
                if (v < 0.f) v = 0.f;
                h0[grow * HH + gcol] = f2bf(v);
            }
    }
}

// ---------------- GEMM2: h = h0 @ w1 + b1; emits hvb = bf16(0.1*dinv*h) and v0 = bf16(dinv*h) ----
__global__ __launch_bounds__(256) void gemm2(const short* __restrict__ h0,
                                             const short* __restrict__ w1t,
                                             const float* __restrict__ b1,
                                             const float* __restrict__ dinv,
                                             ushort_t* __restrict__ hvb,
                                             ushort_t* __restrict__ v0) {
    __shared__ __align__(16) short As[2][128 * 64];
    __shared__ __align__(16) short Bs[2][64 * 64];
    const int tid = threadIdx.x;
    const int lane = tid & 63;
    const int wid = tid >> 6;
    const int wm = wid >> 1, wn = wid & 1;
    const long row0 = (long)blockIdx.x * 128;
    const int rl = lane >> 3;
    const int gko = (lane & 7) ^ rl;

    auto stage = [&](int kt, int buf) {
#pragma unroll
        for (int j = 0; j < 4; ++j) {
            int blk = wid * 4 + j;
            const short* g = h0 + (row0 + blk * 8 + rl) * HH + kt * 64 + gko * 8;
            glds16(g, &As[buf][blk * 512]);
        }
#pragma unroll
        for (int j = 0; j < 2; ++j) {
            int blk = wid * 2 + j;
            const short* g = w1t + (size_t)(blk * 8 + rl) * HH + kt * 64 + gko * 8;
            glds16(g, &Bs[buf][blk * 512]);
        }
    };

    f32x4 acc[4][2] = {};
    stage(0, 0);
    __syncthreads();
    for (int kt = 0; kt < HH / 64; ++kt) {
        int cur = kt & 1;
        if (kt < HH / 64 - 1) stage(kt + 1, cur ^ 1);
#pragma unroll
        for (int ks = 0; ks < 2; ++ks) {
            int ko = ks * 4 + (lane >> 4);
            int slot = ko ^ (lane & 7);
            bf16x8 af[4], bfr[2];
#pragma unroll
            for (int i = 0; i < 4; ++i) {
                int row = wm * 64 + i * 16 + (lane & 15);
                af[i] = *(const bf16x8*)(&As[cur][(row * 8 + slot) * 8]);
            }
#pragma unroll
            for (int j = 0; j < 2; ++j) {
                int col = wn * 32 + j * 16 + (lane & 15);
                bfr[j] = *(const bf16x8*)(&Bs[cur][(col * 8 + slot) * 8]);
            }
#pragma unroll
            for (int i = 0; i < 4; ++i)
#pragma unroll
                for (int j = 0; j < 2; ++j)
                    acc[i][j] = __builtin_amdgcn_mfma_f32_16x16x32_bf16(af[i], bfr[j], acc[i][j], 0, 0, 0);
        }
        __syncthreads();
    }
#pragma unroll
    for (int i = 0; i < 4; ++i)
#pragma unroll
        for (int j = 0; j < 2; ++j) {
            int col = wn * 32 + j * 16 + (lane & 15);
            float bias = b1[col];
#pragma unroll
            for (int q = 0; q < 4; ++q) {
                long grow = row0 + wm * 64 + i * 16 + (lane >> 4) * 4 + q;
                if (grow < NN) {
                    float hval = acc[i][j][q] + bias;
                    float dv = dinv[grow];
                    hvb[grow * CC + col] = (ushort_t)f2bf(0.1f * dv * hval);
                    v0[grow * CC + col] = (ushort_t)f2bf(dv * hval);
                }
            }
        }
}

// ---------------- propagation (degree-sorted node order, 64-ch rows) ----------------
__device__ __forceinline__ void gath(float a[8], const ushort_t* __restrict__ vin,
                                     int src, int l) {
    const int4 r = *(const int4*)(vin + ((size_t)src << 6) + (l << 3));
    a[0] += __int_as_float(r.x << 16);
    a[1] += __int_as_float(r.x & 0xffff0000);
    a[2] += __int_as_float(r.y << 16);
    a[3] += __int_as_float(r.y & 0xffff0000);
    a[4] += __int_as_float(r.z << 16);
    a[5] += __int_as_float(r.z & 0xffff0000);
    a[6] += __int_as_float(r.w << 16);
    a[7] += __int_as_float(r.w & 0xffff0000);
}

template <int LAST>
__global__ __launch_bounds__(256) void prop(const ushort_t* __restrict__ vin,
                                            const ushort_t* __restrict__ hvb,
                                            const float* __restrict__ wco,
                                            const float* __restrict__ sdg,
                                            ushort_t* __restrict__ vout,
                                            float* __restrict__ zout,
                                            const int* __restrict__ rp,
                                            const int* __restrict__ eds,
                                            const int* __restrict__ perm) {
    int g = perm[blockIdx.x * 32 + (threadIdx.x >> 3)];
    int l = threadIdx.x & 7;
    int beg = rp[g], end = rp[g + 1];
    float a0[8] = {}, a1[8] = {}, a2[8] = {}, a3[8] = {};
    int e = beg;
    int head = (beg + 3) & ~3;
    if (head > end) head = end;
    for (; e < head; ++e) gath(a0, vin, eds[e], l);
    for (; e + 3 < end; e += 4) {
        int4 ee = *(const int4*)(eds + e);
        gath(a0, vin, ee.x, l);
        gath(a1, vin, ee.y, l);
        gath(a2, vin, ee.z, l);
        gath(a3, vin, ee.w, l);
    }
    for (; e < end; ++e) gath(a1, vin, eds[e], l);

    float w = wco[g];
    const int4 hb = *(const int4*)(hvb + ((size_t)g << 6) + (l << 3));
    float tv[8];
    tv[0] = __int_as_float(hb.x << 16);
    tv[1] = __int_as_float(hb.x & 0xffff0000);
    tv[2] = __int_as_float(hb.y << 16);
    tv[3] = __int_as_float(hb.y & 0xffff0000);
    tv[4] = __int_as_float(hb.z << 16);
    tv[5] = __int_as_float(hb.z & 0xffff0000);
    tv[6] = __int_as_float(hb.w << 16);
    tv[7] = __int_as_float(hb.w & 0xffff0000);
    float r[8];
#pragma unroll
    for (int c = 0; c < 8; ++c)
        r[c] = w * ((a0[c] + a1[c]) + (a2[c] + a3[c])) + tv[c];
    if (!LAST) {
        s16x8 o;
#pragma unroll
        for (int c = 0; c < 8; ++c) o[c] = f2bf(r[c]);
        *(s16x8*)(vout + ((size_t)g << 6) + (l << 3)) = o;
    } else {
        float sd = sdg[g];
#pragma unroll
        for (int c = 0; c < 8; ++c) r[c] *= sd;
        float m = r[0];
#pragma unroll
        for (int c = 1; c < 8; ++c) m = fmaxf(m, r[c]);
#pragma unroll
        for (int off = 1; off < 8; off <<= 1) m = fmaxf(m, __shfl_xor(m, off));
        float s = 0.f;
#pragma unroll
        for (int c = 0; c < 8; ++c) s += expf(r[c] - m);
#pragma unroll
        for (int off = 1; off < 8; off <<= 1) s += __shfl_xor(s, off);
        float ls = m + logf(s);
        f32x4 o0, o1;
#pragma unroll
        for (int c = 0; c < 4; ++c) { o0[c] = r[c] - ls; o1[c] = r[c + 4] - ls; }
        *(f32x4*)(zout + ((size_t)g << 6) + (l << 3)) = o0;
        *(f32x4*)(zout + ((size_t)g << 6) + (l << 3) + 4) = o1;
    }
}

extern "C" void kernel_launch(void* const* d_in, const int* in_sizes, int n_in,
                              void* d_out, int out_size, void* d_ws, size_t ws_size,
                              hipStream_t stream) {
    const float* x  = (const float*)d_in[0];
    const float* w0 = (const float*)d_in[1];
    const float* b0 = (const float*)d_in[2];
    const float* w1 = (const float*)d_in[3];
    const float* b1 = (const float*)d_in[4];
    const int*   ei = (const int*)d_in[5];

    char* ws = (char*)d_ws;
    size_t off = 0;
    auto take = [&](size_t n) { size_t r = off; off += (n + 255) & ~(size_t)255; return r; };
    size_t o_h0    = take((size_t)100096 * HH * 2);   // bf16 h0; later reused as vB
    size_t o_vA    = take((size_t)NN * CC * 2);       // bf16 v ping buffer
    size_t o_hv    = take((size_t)NN * CC * 2);       // bf16 0.1*dinv*h; earlier aliased as stg
    size_t o_ed    = take((size_t)(EE + NN) * 4);     // CSR src indices
    size_t o_rp    = take((size_t)(NN + 1) * 4);
    size_t o_cnt   = take((size_t)NN * 4);
    size_t o_dinv  = take((size_t)NN * 4);
    size_t o_wco   = take((size_t)NN * 4);
    size_t o_sdg   = take((size_t)NN * 4);
    size_t o_perm  = take((size_t)NN * 4);
    size_t o_w0t   = take((size_t)HH * FIN * 2);
    size_t o_w1t   = take((size_t)CC * HH * 2);
    size_t o_eboff = take((size_t)NBUC * 4);
    size_t o_dboff = take((size_t)64 * 4);
    size_t o_z     = take((size_t)(NBUC + NBUC + 64 + 64) * 4);  // bcnt,bfc,dbc,dfc (zeroed)
    size_t o_xb    = take((size_t)100096 * FIN * 2);  // bf16 x

    short*    h0    = (short*)(ws + o_h0);
    ushort_t* vA    = (ushort_t*)(ws + o_vA);
    ushort_t* vB    = (ushort_t*)(ws + o_h0);   // alias h0 (dead after gemm2)
    ushort_t* hvb   = (ushort_t*)(ws + o_hv);
    int*      stg   = (int*)(ws + o_hv);        // alias hvb (stg dead before gemm2 writes hvb)
    int*      eds   = (int*)(ws + o_ed);
    int*      rp    = (int*)(ws + o_rp);
    int*      cnt   = (int*)(ws + o_cnt);
    float*    dinv  = (float*)(ws + o_dinv);
    float*    wco   = (float*)(ws + o_wco);
    float*    sdg   = (float*)(ws + o_sdg);
    int*      perm  = (int*)(ws + o_perm);
    short*    w0t   = (short*)(ws + o_w0t);
    short*    w1t   = (short*)(ws + o_w1t);
    int*      eboff = (int*)(ws + o_eboff);
    int*      dboff = (int*)(ws + o_dboff);
    int*      bcnt  = (int*)(ws + o_z);
    int*      bfc   = bcnt + NBUC;
    int*      dbc   = bfc + NBUC;
    int*      dfc   = dbc + 64;
    ushort_t* xb    = (ushort_t*)(ws + o_xb);
    float*    zout  = (float*)d_out;

    prep_w<<<(FIN * HH + HH * CC + 255) / 256, 256, 0, stream>>>(w0, w1, w0t, w1t);
    hipMemsetAsync(ws + o_z, 0, (size_t)(NBUC + NBUC + 64 + 64) * 4, stream);

    bincnt<<<NEB, 256, 0, stream>>>(ei, bcnt);
    bscan<<<1, 1024, 0, stream>>>(bcnt, eboff);
    binfill<<<NEB, 256, 0, stream>>>(ei, eboff, bfc, stg);
    bucket_finish<<<NBUC, 256, 0, stream>>>(stg, eboff, bcnt, cnt, dinv, wco, sdg, rp, eds, dbc);
    dscan<<<1, 64, 0, stream>>>(dbc, dboff);
    dperm<<<SB, 256, 0, stream>>>(cnt, dboff, dfc, perm);

    x2b_kernel<<<2048, 256, 0, stream>>>(x, xb);
    gemm1<<<dim3(2, 782), 256, 0, stream>>>(xb, w0t, b0, h0);
    gemm2<<<782, 256, 0, stream>>>(h0, w1t, b1, dinv, hvb, vA);

    const ushort_t* in = vA;
    for (int k = 0; k < KSTEPS; ++k) {
        if (k == KSTEPS - 1) {
            prop<1><<<NN / 32, 256, 0, stream>>>(in, hvb, wco, sdg, nullptr, zout, rp, eds, perm);
        } else {
            ushort_t* o = (k & 1) ? vA : vB;
            prop<0><<<NN / 32, 256, 0, stream>>>(in, hvb, wco, sdg, o, nullptr, rp, eds, perm);
            in = o;
        }
    }
}

// Round 12
// 860.452 us; speedup vs baseline: 2.2403x; 1.0237x over previous
//
#include <hip/hip_runtime.h>
#include <hip/hip_bf16.h>

#define NN 100000
#define EE 3200000
#define FIN 512
#define HH 256
#define CC 64
#define KSTEPS 10
#define SB 391    // ceil(NN/256)
#define NBUC 782  // ceil(NN/128)
#define EPB 4096  // edges per block in binning kernels
#define NEB 782   // ceil(EE/EPB)
#define NB_X2B 2048
#define NB_PREP 576   // ceil((FIN*HH + HH*CC)/256)

typedef __attribute__((ext_vector_type(8))) short bf16x8;
typedef __attribute__((ext_vector_type(8))) short s16x8;
typedef __attribute__((ext_vector_type(4))) float f32x4;
typedef unsigned short ushort_t;

__device__ __forceinline__ short f2bf(float f) {
    union { __hip_bfloat16 h; short s; } u;
    u.h = __float2bfloat16(f);
    return u.s;
}

__device__ __forceinline__ void glds16(const void* g, void* l) {
    __builtin_amdgcn_global_load_lds(
        (const __attribute__((address_space(1))) void*)g,
        (__attribute__((address_space(3))) void*)l, 16, 0, 0);
}

// ================= fused1 bodies (disjoint buffers, provably race-free) =================

__device__ void dev_x2b(int bx, const float* __restrict__ x, ushort_t* __restrict__ xb) {
    const long NTOT = (long)NN * FIN;
    const long stride = (long)NB_X2B * 256 * 8;
    for (long i = ((long)bx * 256 + threadIdx.x) * 8; i < NTOT; i += stride) {
        float4 a = *(const float4*)(x + i);
        float4 b = *(const float4*)(x + i + 4);
        s16x8 o;
        o[0] = f2bf(a.x); o[1] = f2bf(a.y); o[2] = f2bf(a.z); o[3] = f2bf(a.w);
        o[4] = f2bf(b.x); o[5] = f2bf(b.y); o[6] = f2bf(b.z); o[7] = f2bf(b.w);
        *(s16x8*)(xb + i) = o;
    }
}

__device__ void dev_prep_w(int bx, const float* __restrict__ w0, const float* __restrict__ w1,
                           short* __restrict__ w0t, short* __restrict__ w1t) {
    int t = bx * 256 + threadIdx.x;
    if (t < FIN * HH) {
        int k = t >> 8, n = t & 255;
        w0t[n * FIN + k] = f2bf(w0[t]);
    } else if (t < FIN * HH + HH * CC) {
        int u = t - FIN * HH;
        int k = u >> 6, n = u & 63;
        w1t[n * HH + k] = f2bf(w1[u]);
    }
}

__device__ void dev_bincnt(int bx, const int* __restrict__ ei, int* __restrict__ bcnt,
                           int* __restrict__ hb) {
    int tid = threadIdx.x;
    int base = bx * EPB;
    for (int i = tid; i < NBUC; i += 256) hb[i] = 0;
    __syncthreads();
#pragma unroll 4
    for (int i = 0; i < EPB / 256; ++i) {
        int t = base + i * 256 + tid;
        if (t < EE) atomicAdd(&hb[(unsigned)ei[EE + t] >> 7], 1);
    }
    __syncthreads();
    for (int i = tid; i < NBUC; i += 256)
        if (hb[i]) atomicAdd(&bcnt[i], hb[i]);
}

__global__ __launch_bounds__(256) void fused1(const float* __restrict__ x,
                                              ushort_t* __restrict__ xb,
                                              const int* __restrict__ ei,
                                              int* __restrict__ bcnt,
                                              const float* __restrict__ w0,
                                              const float* __restrict__ w1,
                                              short* __restrict__ w0t,
                                              short* __restrict__ w1t) {
    __shared__ int hb[NBUC];
    int bx = blockIdx.x;
    if (bx < NB_X2B) dev_x2b(bx, x, xb);
    else if (bx < NB_X2B + NEB) dev_bincnt(bx - NB_X2B, ei, bcnt, hb);
    else dev_prep_w(bx - NB_X2B - NEB, w0, w1, w0t, w1t);
}

// ================= CSR build (R10-proven, standalone) =================

__global__ __launch_bounds__(1024) void bscan(const int* __restrict__ bcnt,
                                              int* __restrict__ eboff) {
    __shared__ int sh[1024];
    int t = threadIdx.x;
    int v = (t < NBUC) ? bcnt[t] : 0;
    sh[t] = v;
    __syncthreads();
    for (int off = 1; off < 1024; off <<= 1) {
        int add = (t >= off) ? sh[t - off] : 0;
        __syncthreads();
        sh[t] += add;
        __syncthreads();
    }
    if (t < NBUC) eboff[t] = sh[t] - v;
}

__global__ __launch_bounds__(256) void binfill(const int* __restrict__ ei,
                                               const int* __restrict__ eboff,
                                               int* __restrict__ bfc,
                                               int* __restrict__ stg) {
    __shared__ int hb[NBUC];
    __shared__ int lb[NBUC];
    int tid = threadIdx.x;
    int base = blockIdx.x * EPB;
    for (int i = tid; i < NBUC; i += 256) hb[i] = 0;
    __syncthreads();
#pragma unroll 4
    for (int i = 0; i < EPB / 256; ++i) {
        int t = base + i * 256 + tid;
        if (t < EE) atomicAdd(&hb[(unsigned)ei[EE + t] >> 7], 1);
    }
    __syncthreads();
    for (int i = tid; i < NBUC; i += 256) {
        int c = hb[i];
        lb[i] = eboff[i] + (c ? atomicAdd(&bfc[i], c) : 0);
        hb[i] = 0;
    }
    __syncthreads();
#pragma unroll 4
    for (int i = 0; i < EPB / 256; ++i) {
        int t = base + i * 256 + tid;
        if (t < EE) {
            int s = ei[t];
            int d = ei[EE + t];
            int b = (unsigned)d >> 7;
            int o = atomicAdd(&hb[b], 1);
            stg[lb[b] + o] = (s << 7) | (d & 127);
        }
    }
}

// fused per-bucket finish with src-range-ordered scatter (R10-proven)
__global__ __launch_bounds__(256) void bucket_finish(
    const int* __restrict__ stg, const int* __restrict__ eboff,
    const int* __restrict__ bcnt,
    int* __restrict__ cnt, float* __restrict__ dinv, float* __restrict__ wco,
    float* __restrict__ sdg, int* __restrict__ rp, int* __restrict__ eds,
    int* __restrict__ dbc) {
    __shared__ int nc8[128 * 8];
    __shared__ int nc[128];
    __shared__ int sc[128];
    __shared__ int lrp[128];
    __shared__ int h64[64];
    int b = blockIdx.x, tid = threadIdx.x;
    int nodes = min(128, NN - b * 128);
    for (int i = tid; i < 128 * 8; i += 256) nc8[i] = 0;
    if (tid < 64) h64[tid] = 0;
    __syncthreads();
    int s0 = eboff[b], n = bcnt[b];
    for (int i = tid; i < n; i += 256) {
        int e = stg[s0 + i];
        atomicAdd(&nc8[(e & 127) * 8 + ((e >> 7) >> 14)], 1);
    }
    __syncthreads();
    if (tid < 128) {
        int excl = 0;
#pragma unroll
        for (int r = 0; r < 8; ++r) {
            int c = nc8[tid * 8 + r];
            nc8[tid * 8 + r] = excl;
            excl += c;
        }
        nc[tid] = excl;
        sc[tid] = (tid < nodes) ? excl + 1 : 0;
    }
    __syncthreads();
    for (int off = 1; off < 128; off <<= 1) {
        int add = (tid < 128 && tid >= off) ? sc[tid - off] : 0;
        __syncthreads();
        if (tid < 128) sc[tid] += add;
        __syncthreads();
    }
    int base = eboff[b] + b * 128;
    if (tid < nodes) {
        int node = b * 128 + tid;
        int c = nc[tid];
        int excl = base + sc[tid] - (c + 1);
        lrp[tid] = excl;
        rp[node] = excl;
        cnt[node] = c;
        float fd = (float)(c + 1);
        dinv[node] = rsqrtf(fd);
        wco[node] = 0.9f / fd;
        sdg[node] = sqrtf(fd);
        atomicAdd(&h64[min(c, 63)], 1);
    }
    if (b == NBUC - 1 && tid == 0) rp[NN] = base + n + nodes;
    __syncthreads();
    if (tid < 64 && h64[tid]) atomicAdd(&dbc[tid], h64[tid]);
    for (int i = tid; i < n; i += 256) {
        int e = stg[s0 + i];
        int src = e >> 7, loc = e & 127;
        int o = atomicAdd(&nc8[loc * 8 + (src >> 14)], 1);
        eds[lrp[loc] + o] = src;
    }
    __syncthreads();
    if (tid < nodes) eds[lrp[tid] + nc[tid]] = b * 128 + tid;  // self loop (last slot)
}

__global__ void dscan(const int* __restrict__ dbc, int* __restrict__ dboff) {
    __shared__ int sh[64];
    int t = threadIdx.x;
    int v = dbc[t];
    sh[t] = v;
    __syncthreads();
    for (int off = 1; off < 64; off <<= 1) {
        int add = (t >= off) ? sh[t - off] : 0;
        __syncthreads();
        sh[t] += add;
        __syncthreads();
    }
    dboff[t] = sh[t] - v;
}

__global__ __launch_bounds__(256) void dperm(const int* __restrict__ cnt,
                                             const int* __restrict__ dboff,
                                             int* __restrict__ dfc,
                                             int* __restrict__ perm) {
    __shared__ int h[64];
    __shared__ int base[64];
    int tid = threadIdx.x;
    int i = blockIdx.x * 256 + tid;
    if (tid < 64) h[tid] = 0;
    __syncthreads();
    int bin = 0, r = 0;
    bool ok = i < NN;
    if (ok) {
        bin = min(cnt[i], 63);
        r = atomicAdd(&h[bin], 1);
    }
    __syncthreads();
    if (tid < 64) {
        int c = h[tid];
        base[tid] = dboff[tid] + (c ? atomicAdd(&dfc[tid], c) : 0);
    }
    __syncthreads();
    if (ok) perm[base[bin] + r] = i;
}

// ---------------- GEMM1: h0 = relu(xb @ w0 + b0), bf16 in/out ----------------
__global__ __launch_bounds__(256) void gemm1(const ushort_t* __restrict__ xb,
                                             const short* __restrict__ w0t,
                                             const float* __restrict__ b0,
                                             short* __restrict__ h0) {
    __shared__ __align__(16) short As[2][128 * 64];
    __shared__ __align__(16) short Bs[2][128 * 64];
    const int tid = threadIdx.x;
    const int lane = tid & 63;
    const int wid = tid >> 6;
    const int wm = wid >> 1, wn = wid & 1;        // 64x64 per wave
    const int bn0 = blockIdx.x * 128;             // 0 or 128
    const long row0 = (long)blockIdx.y * 128;
    const int rl = lane >> 3;
    const int gko = (lane & 7) ^ rl;              // pre-swizzled global k-octet

    auto stage = [&](int kt, int buf) {
#pragma unroll
        for (int j = 0; j < 4; ++j) {
            int blk = wid * 4 + j;
            const ushort_t* g = xb + (row0 + blk * 8 + rl) * FIN + kt * 64 + gko * 8;
            glds16(g, &As[buf][blk * 512]);
        }
#pragma unroll
        for (int j = 0; j < 4; ++j) {
            int blk = wid * 4 + j;
            const short* g = w0t + (size_t)(bn0 + blk * 8 + rl) * FIN + kt * 64 + gko * 8;
            glds16(g, &Bs[buf][blk * 512]);
        }
    };

    f32x4 acc[4][4] = {};
    stage(0, 0);
    __syncthreads();
    for (int kt = 0; kt < FIN / 64; ++kt) {
        int cur = kt & 1;
        if (kt < FIN / 64 - 1) stage(kt + 1, cur ^ 1);
#pragma unroll
        for (int ks = 0; ks < 2; ++ks) {
            int ko = ks * 4 + (lane >> 4);
            int slot = ko ^ (lane & 7);
            bf16x8 af[4], bfr[4];
#pragma unroll
            for (int i = 0; i < 4; ++i) {
                int row = wm * 64 + i * 16 + (lane & 15);
                af[i] = *(const bf16x8*)(&As[cur][(row * 8 + slot) * 8]);
            }
#pragma unroll
            for (int j = 0; j < 4; ++j) {
                int col = wn * 64 + j * 16 + (lane & 15);
                bfr[j] = *(const bf16x8*)(&Bs[cur][(col * 8 + slot) * 8]);
            }
#pragma unroll
            for (int i = 0; i < 4; ++i)
#pragma unroll
                for (int j = 0; j < 4; ++j)
                    acc[i][j] = __builtin_amdgcn_mfma_f32_16x16x32_bf16(af[i], bfr[j], acc[i][j], 0, 0, 0);
        }
        __syncthreads();
    }
#pragma unroll
    for (int j = 0; j < 4; ++j) {
        int gcol = bn0 + wn * 64 + j * 16 + (lane & 15);
        float bias = b0[gcol];
#pragma unroll
        for (int i = 0; i < 4; ++i)
#pragma unroll
            for (int q = 0; q < 4; ++q) {
                long grow = row0 + wm * 64 + i * 16 + (lane >> 4) * 4 + q;
                float v = acc[i][j][q] + bias;
                if (v < 0.f) v = 0.f;
                h0[grow * HH + gcol] = f2bf(v);
            }
    }
}

// ---------------- GEMM2: h = h0 @ w1 + b1; emits hvb = bf16(0.1*dinv*h) and v0 = bf16(dinv*h) ----
__global__ __launch_bounds__(256) void gemm2(const short* __restrict__ h0,
                                             const short* __restrict__ w1t,
                                             const float* __restrict__ b1,
                                             const float* __restrict__ dinv,
                                             ushort_t* __restrict__ hvb,
                                             ushort_t* __restrict__ v0) {
    __shared__ __align__(16) short As[2][128 * 64];
    __shared__ __align__(16) short Bs[2][64 * 64];
    const int tid = threadIdx.x;
    const int lane = tid & 63;
    const int wid = tid >> 6;
    const int wm = wid >> 1, wn = wid & 1;
    const long row0 = (long)blockIdx.x * 128;
    const int rl = lane >> 3;
    const int gko = (lane & 7) ^ rl;

    auto stage = [&](int kt, int buf) {
#pragma unroll
        for (int j = 0; j < 4; ++j) {
            int blk = wid * 4 + j;
            const short* g = h0 + (row0 + blk * 8 + rl) * HH + kt * 64 + gko * 8;
            glds16(g, &As[buf][blk * 512]);
        }
#pragma unroll
        for (int j = 0; j < 2; ++j) {
            int blk = wid * 2 + j;
            const short* g = w1t + (size_t)(blk * 8 + rl) * HH + kt * 64 + gko * 8;
            glds16(g, &Bs[buf][blk * 512]);
        }
    };

    f32x4 acc[4][2] = {};
    stage(0, 0);
    __syncthreads();
    for (int kt = 0; kt < HH / 64; ++kt) {
        int cur = kt & 1;
        if (kt < HH / 64 - 1) stage(kt + 1, cur ^ 1);
#pragma unroll
        for (int ks = 0; ks < 2; ++ks) {
            int ko = ks * 4 + (lane >> 4);
            int slot = ko ^ (lane & 7);
            bf16x8 af[4], bfr[2];
#pragma unroll
            for (int i = 0; i < 4; ++i) {
                int row = wm * 64 + i * 16 + (lane & 15);
                af[i] = *(const bf16x8*)(&As[cur][(row * 8 + slot) * 8]);
            }
#pragma unroll
            for (int j = 0; j < 2; ++j) {
                int col = wn * 32 + j * 16 + (lane & 15);
                bfr[j] = *(const bf16x8*)(&Bs[cur][(col * 8 + slot) * 8]);
            }
#pragma unroll
            for (int i = 0; i < 4; ++i)
#pragma unroll
                for (int j = 0; j < 2; ++j)
                    acc[i][j] = __builtin_amdgcn_mfma_f32_16x16x32_bf16(af[i], bfr[j], acc[i][j], 0, 0, 0);
        }
        __syncthreads();
    }
#pragma unroll
    for (int i = 0; i < 4; ++i)
#pragma unroll
        for (int j = 0; j < 2; ++j) {
            int col = wn * 32 + j * 16 + (lane & 15);
            float bias = b1[col];
#pragma unroll
            for (int q = 0; q < 4; ++q) {
                long grow = row0 + wm * 64 + i * 16 + (lane >> 4) * 4 + q;
                if (grow < NN) {
                    float hval = acc[i][j][q] + bias;
                    float dv = dinv[grow];
                    hvb[grow * CC + col] = (ushort_t)f2bf(0.1f * dv * hval);
                    v0[grow * CC + col] = (ushort_t)f2bf(dv * hval);
                }
            }
        }
}

// ---------------- propagation (degree-sorted node order, 64-ch rows) ----------------
__device__ __forceinline__ void gath(float a[8], const ushort_t* __restrict__ vin,
                                     int src, int l) {
    const int4 r = *(const int4*)(vin + ((size_t)src << 6) + (l << 3));
    a[0] += __int_as_float(r.x << 16);
    a[1] += __int_as_float(r.x & 0xffff0000);
    a[2] += __int_as_float(r.y << 16);
    a[3] += __int_as_float(r.y & 0xffff0000);
    a[4] += __int_as_float(r.z << 16);
    a[5] += __int_as_float(r.z & 0xffff0000);
    a[6] += __int_as_float(r.w << 16);
    a[7] += __int_as_float(r.w & 0xffff0000);
}

template <int LAST>
__global__ __launch_bounds__(256) void prop(const ushort_t* __restrict__ vin,
                                            const ushort_t* __restrict__ hvb,
                                            const float* __restrict__ wco,
                                            const float* __restrict__ sdg,
                                            ushort_t* __restrict__ vout,
                                            float* __restrict__ zout,
                                            const int* __restrict__ rp,
                                            const int* __restrict__ eds,
                                            const int* __restrict__ perm) {
    int g = perm[blockIdx.x * 32 + (threadIdx.x >> 3)];
    int l = threadIdx.x & 7;
    int beg = rp[g], end = rp[g + 1];
    float a0[8] = {}, a1[8] = {}, a2[8] = {}, a3[8] = {};
    int e = beg;
    int head = (beg + 3) & ~3;
    if (head > end) head = end;
    for (; e < head; ++e) gath(a0, vin, eds[e], l);
    for (; e + 3 < end; e += 4) {
        int4 ee = *(const int4*)(eds + e);
        gath(a0, vin, ee.x, l);
        gath(a1, vin, ee.y, l);
        gath(a2, vin, ee.z, l);
        gath(a3, vin, ee.w, l);
    }
    for (; e < end; ++e) gath(a1, vin, eds[e], l);

    float w = wco[g];
    const int4 hb = *(const int4*)(hvb + ((size_t)g << 6) + (l << 3));
    float tv[8];
    tv[0] = __int_as_float(hb.x << 16);
    tv[1] = __int_as_float(hb.x & 0xffff0000);
    tv[2] = __int_as_float(hb.y << 16);
    tv[3] = __int_as_float(hb.y & 0xffff0000);
    tv[4] = __int_as_float(hb.z << 16);
    tv[5] = __int_as_float(hb.z & 0xffff0000);
    tv[6] = __int_as_float(hb.w << 16);
    tv[7] = __int_as_float(hb.w & 0xffff0000);
    float r[8];
#pragma unroll
    for (int c = 0; c < 8; ++c)
        r[c] = w * ((a0[c] + a1[c]) + (a2[c] + a3[c])) + tv[c];
    if (!LAST) {
        s16x8 o;
#pragma unroll
        for (int c = 0; c < 8; ++c) o[c] = f2bf(r[c]);
        *(s16x8*)(vout + ((size_t)g << 6) + (l << 3)) = o;
    } else {
        float sd = sdg[g];
#pragma unroll
        for (int c = 0; c < 8; ++c) r[c] *= sd;
        float m = r[0];
#pragma unroll
        for (int c = 1; c < 8; ++c) m = fmaxf(m, r[c]);
#pragma unroll
        for (int off = 1; off < 8; off <<= 1) m = fmaxf(m, __shfl_xor(m, off));
        float s = 0.f;
#pragma unroll
        for (int c = 0; c < 8; ++c) s += expf(r[c] - m);
#pragma unroll
        for (int off = 1; off < 8; off <<= 1) s += __shfl_xor(s, off);
        float ls = m + logf(s);
        f32x4 o0, o1;
#pragma unroll
        for (int c = 0; c < 4; ++c) { o0[c] = r[c] - ls; o1[c] = r[c + 4] - ls; }
        *(f32x4*)(zout + ((size_t)g << 6) + (l << 3)) = o0;
        *(f32x4*)(zout + ((size_t)g << 6) + (l << 3) + 4) = o1;
    }
}

extern "C" void kernel_launch(void* const* d_in, const int* in_sizes, int n_in,
                              void* d_out, int out_size, void* d_ws, size_t ws_size,
                              hipStream_t stream) {
    const float* x  = (const float*)d_in[0];
    const float* w0 = (const float*)d_in[1];
    const float* b0 = (const float*)d_in[2];
    const float* w1 = (const float*)d_in[3];
    const float* b1 = (const float*)d_in[4];
    const int*   ei = (const int*)d_in[5];

    char* ws = (char*)d_ws;
    size_t off = 0;
    auto take = [&](size_t n) { size_t r = off; off += (n + 255) & ~(size_t)255; return r; };
    size_t o_h0    = take((size_t)100096 * HH * 2);   // bf16 h0; later reused as vB
    size_t o_vA    = take((size_t)NN * CC * 2);       // bf16 v ping buffer
    size_t o_hv    = take((size_t)NN * CC * 2);       // bf16 0.1*dinv*h; earlier aliased as stg
    size_t o_ed    = take((size_t)(EE + NN) * 4);     // CSR src indices
    size_t o_rp    = take((size_t)(NN + 1) * 4);
    size_t o_cnt   = take((size_t)NN * 4);
    size_t o_dinv  = take((size_t)NN * 4);
    size_t o_wco   = take((size_t)NN * 4);
    size_t o_sdg   = take((size_t)NN * 4);
    size_t o_perm  = take((size_t)NN * 4);
    size_t o_w0t   = take((size_t)HH * FIN * 2);
    size_t o_w1t   = take((size_t)CC * HH * 2);
    size_t o_eboff = take((size_t)NBUC * 4);
    size_t o_dboff = take((size_t)64 * 4);
    size_t o_z     = take((size_t)(NBUC + NBUC + 64 + 64) * 4);  // bcnt,bfc,dbc,dfc (zeroed)
    size_t o_xb    = take((size_t)100096 * FIN * 2);  // bf16 x

    short*    h0    = (short*)(ws + o_h0);
    ushort_t* vA    = (ushort_t*)(ws + o_vA);
    ushort_t* vB    = (ushort_t*)(ws + o_h0);   // alias h0 (dead after gemm2)
    ushort_t* hvb   = (ushort_t*)(ws + o_hv);
    int*      stg   = (int*)(ws + o_hv);        // alias hvb (stg dead before gemm2 writes hvb)
    int*      eds   = (int*)(ws + o_ed);
    int*      rp    = (int*)(ws + o_rp);
    int*      cnt   = (int*)(ws + o_cnt);
    float*    dinv  = (float*)(ws + o_dinv);
    float*    wco   = (float*)(ws + o_wco);
    float*    sdg   = (float*)(ws + o_sdg);
    int*      perm  = (int*)(ws + o_perm);
    short*    w0t   = (short*)(ws + o_w0t);
    short*    w1t   = (short*)(ws + o_w1t);
    int*      eboff = (int*)(ws + o_eboff);
    int*      dboff = (int*)(ws + o_dboff);
    int*      bcnt  = (int*)(ws + o_z);
    int*      bfc   = bcnt + NBUC;
    int*      dbc   = bfc + NBUC;
    int*      dfc   = dbc + 64;
    ushort_t* xb    = (ushort_t*)(ws + o_xb);
    float*    zout  = (float*)d_out;

    hipMemsetAsync(ws + o_z, 0, (size_t)(NBUC + NBUC + 64 + 64) * 4, stream);

    fused1<<<NB_X2B + NEB + NB_PREP, 256, 0, stream>>>(x, xb, ei, bcnt, w0, w1, w0t, w1t);
    bscan<<<1, 1024, 0, stream>>>(bcnt, eboff);
    binfill<<<NEB, 256, 0, stream>>>(ei, eboff, bfc, stg);
    bucket_finish<<<NBUC, 256, 0, stream>>>(stg, eboff, bcnt, cnt, dinv, wco, sdg, rp, eds, dbc);
    dscan<<<1, 64, 0, stream>>>(dbc, dboff);
    dperm<<<SB, 256, 0, stream>>>(cnt, dboff, dfc, perm);

    gemm1<<<dim3(2, 782), 256, 0, stream>>>(xb, w0t, b0, h0);
    gemm2<<<782, 256, 0, stream>>>(h0, w1t, b1, dinv, hvb, vA);

    const ushort_t* in = vA;
    for (int k = 0; k < KSTEPS; ++k) {
        if (k == KSTEPS - 1) {
            prop<1><<<NN / 32, 256, 0, stream>>>(in, hvb, wco, sdg, nullptr, zout, rp, eds, perm);
        } else {
            ushort_t* o = (k & 1) ? vA : vB;
            prop<0><<<NN / 32, 256, 0, stream>>>(in, hvb, wco, sdg, o, nullptr, rp, eds, perm);
            in = o;
        }
    }
}

// Round 13
// 819.851 us; speedup vs baseline: 2.3513x; 1.0495x over previous
//
#include <hip/hip_runtime.h>
#include <hip/hip_bf16.h>

#define NN 100000
#define EE 3200000
#define FIN 512
#define HH 256
#define CC 64
#define KSTEPS 10
#define SB 391    // ceil(NN/256)
#define NBUC 782  // ceil(NN/128)
#define EPB 4096  // edges per block in binning kernels
#define NEB 782   // ceil(EE/EPB)
#define NB_X2B 2048
#define NB_PREP 576   // ceil((FIN*HH + HH*CC)/256)

typedef __attribute__((ext_vector_type(8))) short bf16x8;
typedef __attribute__((ext_vector_type(8))) short s16x8;
typedef __attribute__((ext_vector_type(4))) float f32x4;
typedef unsigned short ushort_t;

__device__ __forceinline__ short f2bf(float f) {
    union { __hip_bfloat16 h; short s; } u;
    u.h = __float2bfloat16(f);
    return u.s;
}

__device__ __forceinline__ void glds16(const void* g, void* l) {
    __builtin_amdgcn_global_load_lds(
        (const __attribute__((address_space(1))) void*)g,
        (__attribute__((address_space(3))) void*)l, 16, 0, 0);
}

// ================= fused1 bodies (disjoint buffers, proven race-free) =================

__device__ void dev_x2b(int bx, const float* __restrict__ x, ushort_t* __restrict__ xb) {
    const long NTOT = (long)NN * FIN;
    const long stride = (long)NB_X2B * 256 * 8;
    for (long i = ((long)bx * 256 + threadIdx.x) * 8; i < NTOT; i += stride) {
        float4 a = *(const float4*)(x + i);
        float4 b = *(const float4*)(x + i + 4);
        s16x8 o;
        o[0] = f2bf(a.x); o[1] = f2bf(a.y); o[2] = f2bf(a.z); o[3] = f2bf(a.w);
        o[4] = f2bf(b.x); o[5] = f2bf(b.y); o[6] = f2bf(b.z); o[7] = f2bf(b.w);
        *(s16x8*)(xb + i) = o;
    }
}

__device__ void dev_prep_w(int bx, const float* __restrict__ w0, const float* __restrict__ w1,
                           short* __restrict__ w0t, short* __restrict__ w1t) {
    int t = bx * 256 + threadIdx.x;
    if (t < FIN * HH) {
        int k = t >> 8, n = t & 255;
        w0t[n * FIN + k] = f2bf(w0[t]);
    } else if (t < FIN * HH + HH * CC) {
        int u = t - FIN * HH;
        int k = u >> 6, n = u & 63;
        w1t[n * HH + k] = f2bf(w1[u]);
    }
}

__device__ void dev_bincnt(int bx, const int* __restrict__ ei, int* __restrict__ bcnt,
                           int* __restrict__ hb) {
    int tid = threadIdx.x;
    int base = bx * EPB;
    for (int i = tid; i < NBUC; i += 256) hb[i] = 0;
    __syncthreads();
#pragma unroll 4
    for (int i = 0; i < EPB / 256; ++i) {
        int t = base + i * 256 + tid;
        if (t < EE) atomicAdd(&hb[(unsigned)ei[EE + t] >> 7], 1);
    }
    __syncthreads();
    for (int i = tid; i < NBUC; i += 256)
        if (hb[i]) atomicAdd(&bcnt[i], hb[i]);
}

__global__ __launch_bounds__(256) void fused1(const float* __restrict__ x,
                                              ushort_t* __restrict__ xb,
                                              const int* __restrict__ ei,
                                              int* __restrict__ bcnt,
                                              const float* __restrict__ w0,
                                              const float* __restrict__ w1,
                                              short* __restrict__ w0t,
                                              short* __restrict__ w1t) {
    __shared__ int hb[NBUC];
    int bx = blockIdx.x;
    if (bx < NB_X2B) dev_x2b(bx, x, xb);
    else if (bx < NB_X2B + NEB) dev_bincnt(bx - NB_X2B, ei, bcnt, hb);
    else dev_prep_w(bx - NB_X2B - NEB, w0, w1, w0t, w1t);
}

// ================= CSR build =================

__global__ __launch_bounds__(1024) void bscan(const int* __restrict__ bcnt,
                                              int* __restrict__ eboff) {
    __shared__ int sh[1024];
    int t = threadIdx.x;
    int v = (t < NBUC) ? bcnt[t] : 0;
    sh[t] = v;
    __syncthreads();
    for (int off = 1; off < 1024; off <<= 1) {
        int add = (t >= off) ? sh[t - off] : 0;
        __syncthreads();
        sh[t] += add;
        __syncthreads();
    }
    if (t < NBUC) eboff[t] = sh[t] - v;
}

// binfill body (LDS pool passed in)
__device__ void dev_binfill(int bx, const int* __restrict__ ei, const int* __restrict__ eboff,
                            int* __restrict__ bfc, int* __restrict__ stg, int* pool) {
    int* hb = pool;
    int* lb = pool + NBUC;
    int tid = threadIdx.x;
    int base = bx * EPB;
    for (int i = tid; i < NBUC; i += 256) hb[i] = 0;
    __syncthreads();
#pragma unroll 4
    for (int i = 0; i < EPB / 256; ++i) {
        int t = base + i * 256 + tid;
        if (t < EE) atomicAdd(&hb[(unsigned)ei[EE + t] >> 7], 1);
    }
    __syncthreads();
    for (int i = tid; i < NBUC; i += 256) {
        int c = hb[i];
        lb[i] = eboff[i] + (c ? atomicAdd(&bfc[i], c) : 0);
        hb[i] = 0;
    }
    __syncthreads();
#pragma unroll 4
    for (int i = 0; i < EPB / 256; ++i) {
        int t = base + i * 256 + tid;
        if (t < EE) {
            int s = ei[t];
            int d = ei[EE + t];
            int b = (unsigned)d >> 7;
            int o = atomicAdd(&hb[b], 1);
            stg[lb[b] + o] = (s << 7) | (d & 127);
        }
    }
}

// gemm1 body: g1 in [0, 1564); bn0 = (g1&1)*128, row0 = (g1>>1)*128
__device__ void dev_gemm1(int g1, const ushort_t* __restrict__ xb,
                          const short* __restrict__ w0t, const float* __restrict__ b0,
                          short* __restrict__ h0, char* sm) {
    short* AsP = (short*)sm;            // [2][8192]
    short* BsP = (short*)(sm + 32768);  // [2][8192]
    const int tid = threadIdx.x;
    const int lane = tid & 63;
    const int wid = tid >> 6;
    const int wm = wid >> 1, wn = wid & 1;
    const int bn0 = (g1 & 1) * 128;
    const long row0 = (long)(g1 >> 1) * 128;
    const int rl = lane >> 3;
    const int gko = (lane & 7) ^ rl;

    auto stage = [&](int kt, int buf) {
#pragma unroll
        for (int j = 0; j < 4; ++j) {
            int blk = wid * 4 + j;
            const ushort_t* g = xb + (row0 + blk * 8 + rl) * FIN + kt * 64 + gko * 8;
            glds16(g, &AsP[buf * 8192 + blk * 512]);
        }
#pragma unroll
        for (int j = 0; j < 4; ++j) {
            int blk = wid * 4 + j;
            const short* g = w0t + (size_t)(bn0 + blk * 8 + rl) * FIN + kt * 64 + gko * 8;
            glds16(g, &BsP[buf * 8192 + blk * 512]);
        }
    };

    f32x4 acc[4][4] = {};
    stage(0, 0);
    __syncthreads();
    for (int kt = 0; kt < FIN / 64; ++kt) {
        int cur = kt & 1;
        if (kt < FIN / 64 - 1) stage(kt + 1, cur ^ 1);
#pragma unroll
        for (int ks = 0; ks < 2; ++ks) {
            int ko = ks * 4 + (lane >> 4);
            int slot = ko ^ (lane & 7);
            bf16x8 af[4], bfr[4];
#pragma unroll
            for (int i = 0; i < 4; ++i) {
                int row = wm * 64 + i * 16 + (lane & 15);
                af[i] = *(const bf16x8*)(&AsP[cur * 8192 + (row * 8 + slot) * 8]);
            }
#pragma unroll
            for (int j = 0; j < 4; ++j) {
                int col = wn * 64 + j * 16 + (lane & 15);
                bfr[j] = *(const bf16x8*)(&BsP[cur * 8192 + (col * 8 + slot) * 8]);
            }
#pragma unroll
            for (int i = 0; i < 4; ++i)
#pragma unroll
                for (int j = 0; j < 4; ++j)
                    acc[i][j] = __builtin_amdgcn_mfma_f32_16x16x32_bf16(af[i], bfr[j], acc[i][j], 0, 0, 0);
        }
        __syncthreads();
    }
#pragma unroll
    for (int j = 0; j < 4; ++j) {
        int gcol = bn0 + wn * 64 + j * 16 + (lane & 15);
        float bias = b0[gcol];
#pragma unroll
        for (int i = 0; i < 4; ++i)
#pragma unroll
            for (int q = 0; q < 4; ++q) {
                long grow = row0 + wm * 64 + i * 16 + (lane >> 4) * 4 + q;
                float v = acc[i][j][q] + bias;
                if (v < 0.f) v = 0.f;
                h0[grow * HH + gcol] = f2bf(v);
            }
    }
}

// fused3: binfill ∥ gemm1 (disjoint reads/writes; the R13 bisect)
__global__ __launch_bounds__(256) void fused3(const int* __restrict__ ei,
                                              const int* __restrict__ eboff,
                                              int* __restrict__ bfc,
                                              int* __restrict__ stg,
                                              const ushort_t* __restrict__ xb,
                                              const short* __restrict__ w0t,
                                              const float* __restrict__ b0,
                                              short* __restrict__ h0) {
    __shared__ __align__(16) char sm[65536];
    int bx = blockIdx.x, r = bx % 3, q = bx / 3;
    if (r == 2) dev_binfill(q, ei, eboff, bfc, stg, (int*)sm);
    else dev_gemm1(q * 2 + r, xb, w0t, b0, h0, sm);
}

// fused per-bucket finish with src-range-ordered scatter (R10-proven, standalone)
__global__ __launch_bounds__(256) void bucket_finish(
    const int* __restrict__ stg, const int* __restrict__ eboff,
    const int* __restrict__ bcnt,
    int* __restrict__ cnt, float* __restrict__ dinv, float* __restrict__ wco,
    float* __restrict__ sdg, int* __restrict__ rp, int* __restrict__ eds,
    int* __restrict__ dbc) {
    __shared__ int nc8[128 * 8];
    __shared__ int nc[128];
    __shared__ int sc[128];
    __shared__ int lrp[128];
    __shared__ int h64[64];
    int b = blockIdx.x, tid = threadIdx.x;
    int nodes = min(128, NN - b * 128);
    for (int i = tid; i < 128 * 8; i += 256) nc8[i] = 0;
    if (tid < 64) h64[tid] = 0;
    __syncthreads();
    int s0 = eboff[b], n = bcnt[b];
    for (int i = tid; i < n; i += 256) {
        int e = stg[s0 + i];
        atomicAdd(&nc8[(e & 127) * 8 + ((e >> 7) >> 14)], 1);
    }
    __syncthreads();
    if (tid < 128) {
        int excl = 0;
#pragma unroll
        for (int r = 0; r < 8; ++r) {
            int c = nc8[tid * 8 + r];
            nc8[tid * 8 + r] = excl;
            excl += c;
        }
        nc[tid] = excl;
        sc[tid] = (tid < nodes) ? excl + 1 : 0;
    }
    __syncthreads();
    for (int off = 1; off < 128; off <<= 1) {
        int add = (tid < 128 && tid >= off) ? sc[tid - off] : 0;
        __syncthreads();
        if (tid < 128) sc[tid] += add;
        __syncthreads();
    }
    int base = eboff[b] + b * 128;
    if (tid < nodes) {
        int node = b * 128 + tid;
        int c = nc[tid];
        int excl = base + sc[tid] - (c + 1);
        lrp[tid] = excl;
        rp[node] = excl;
        cnt[node] = c;
        float fd = (float)(c + 1);
        dinv[node] = rsqrtf(fd);
        wco[node] = 0.9f / fd;
        sdg[node] = sqrtf(fd);
        atomicAdd(&h64[min(c, 63)], 1);
    }
    if (b == NBUC - 1 && tid == 0) rp[NN] = base + n + nodes;
    __syncthreads();
    if (tid < 64 && h64[tid]) atomicAdd(&dbc[tid], h64[tid]);
    for (int i = tid; i < n; i += 256) {
        int e = stg[s0 + i];
        int src = e >> 7, loc = e & 127;
        int o = atomicAdd(&nc8[loc * 8 + (src >> 14)], 1);
        eds[lrp[loc] + o] = src;
    }
    __syncthreads();
    if (tid < nodes) eds[lrp[tid] + nc[tid]] = b * 128 + tid;  // self loop (last slot)
}

__global__ void dscan(const int* __restrict__ dbc, int* __restrict__ dboff) {
    __shared__ int sh[64];
    int t = threadIdx.x;
    int v = dbc[t];
    sh[t] = v;
    __syncthreads();
    for (int off = 1; off < 64; off <<= 1) {
        int add = (t >= off) ? sh[t - off] : 0;
        __syncthreads();
        sh[t] += add;
        __syncthreads();
    }
    dboff[t] = sh[t] - v;
}

__global__ __launch_bounds__(256) void dperm(const int* __restrict__ cnt,
                                             const int* __restrict__ dboff,
                                             int* __restrict__ dfc,
                                             int* __restrict__ perm) {
    __shared__ int h[64];
    __shared__ int base[64];
    int tid = threadIdx.x;
    int i = blockIdx.x * 256 + tid;
    if (tid < 64) h[tid] = 0;
    __syncthreads();
    int bin = 0, r = 0;
    bool ok = i < NN;
    if (ok) {
        bin = min(cnt[i], 63);
        r = atomicAdd(&h[bin], 1);
    }
    __syncthreads();
    if (tid < 64) {
        int c = h[tid];
        base[tid] = dboff[tid] + (c ? atomicAdd(&dfc[tid], c) : 0);
    }
    __syncthreads();
    if (ok) perm[base[bin] + r] = i;
}

// ---------------- GEMM2: h = h0 @ w1 + b1; emits hvb = bf16(0.1*dinv*h) and v0 = bf16(dinv*h) ----
__global__ __launch_bounds__(256) void gemm2(const short* __restrict__ h0,
                                             const short* __restrict__ w1t,
                                             const float* __restrict__ b1,
                                             const float* __restrict__ dinv,
                                             ushort_t* __restrict__ hvb,
                                             ushort_t* __restrict__ v0) {
    __shared__ __align__(16) short As[2][128 * 64];
    __shared__ __align__(16) short Bs[2][64 * 64];
    const int tid = threadIdx.x;
    const int lane = tid & 63;
    const int wid = tid >> 6;
    const int wm = wid >> 1, wn = wid & 1;
    const long row0 = (long)blockIdx.x * 128;
    const int rl = lane >> 3;
    const int gko = (lane & 7) ^ rl;

    auto stage = [&](int kt, int buf) {
#pragma unroll
        for (int j = 0; j < 4; ++j) {
            int blk = wid * 4 + j;
            const short* g = h0 + (row0 + blk * 8 + rl) * HH + kt * 64 + gko * 8;
            glds16(g, &As[buf][blk * 512]);
        }
#pragma unroll
        for (int j = 0; j < 2; ++j) {
            int blk = wid * 2 + j;
            const short* g = w1t + (size_t)(blk * 8 + rl) * HH + kt * 64 + gko * 8;
            glds16(g, &Bs[buf][blk * 512]);
        }
    };

    f32x4 acc[4][2] = {};
    stage(0, 0);
    __syncthreads();
    for (int kt = 0; kt < HH / 64; ++kt) {
        int cur = kt & 1;
        if (kt < HH / 64 - 1) stage(kt + 1, cur ^ 1);
#pragma unroll
        for (int ks = 0; ks < 2; ++ks) {
            int ko = ks * 4 + (lane >> 4);
            int slot = ko ^ (lane & 7);
            bf16x8 af[4], bfr[2];
#pragma unroll
            for (int i = 0; i < 4; ++i) {
                int row = wm * 64 + i * 16 + (lane & 15);
                af[i] = *(const bf16x8*)(&As[cur][(row * 8 + slot) * 8]);
            }
#pragma unroll
            for (int j = 0; j < 2; ++j) {
                int col = wn * 32 + j * 16 + (lane & 15);
                bfr[j] = *(const bf16x8*)(&Bs[cur][(col * 8 + slot) * 8]);
            }
#pragma unroll
            for (int i = 0; i < 4; ++i)
#pragma unroll
                for (int j = 0; j < 2; ++j)
                    acc[i][j] = __builtin_amdgcn_mfma_f32_16x16x32_bf16(af[i], bfr[j], acc[i][j], 0, 0, 0);
        }
        __syncthreads();
    }
#pragma unroll
    for (int i = 0; i < 4; ++i)
#pragma unroll
        for (int j = 0; j < 2; ++j) {
            int col = wn * 32 + j * 16 + (lane & 15);
            float bias = b1[col];
#pragma unroll
            for (int q = 0; q < 4; ++q) {
                long grow = row0 + wm * 64 + i * 16 + (lane >> 4) * 4 + q;
                if (grow < NN) {
                    float hval = acc[i][j][q] + bias;
                    float dv = dinv[grow];
                    hvb[grow * CC + col] = (ushort_t)f2bf(0.1f * dv * hval);
                    v0[grow * CC + col] = (ushort_t)f2bf(dv * hval);
                }
            }
        }
}

// ---------------- propagation (degree-sorted node order, 64-ch rows) ----------------
__device__ __forceinline__ void gath(float a[8], const ushort_t* __restrict__ vin,
                                     int src, int l) {
    const int4 r = *(const int4*)(vin + ((size_t)src << 6) + (l << 3));
    a[0] += __int_as_float(r.x << 16);
    a[1] += __int_as_float(r.x & 0xffff0000);
    a[2] += __int_as_float(r.y << 16);
    a[3] += __int_as_float(r.y & 0xffff0000);
    a[4] += __int_as_float(r.z << 16);
    a[5] += __int_as_float(r.z & 0xffff0000);
    a[6] += __int_as_float(r.w << 16);
    a[7] += __int_as_float(r.w & 0xffff0000);
}

template <int LAST>
__global__ __launch_bounds__(256) void prop(const ushort_t* __restrict__ vin,
                                            const ushort_t* __restrict__ hvb,
                                            const float* __restrict__ wco,
                                            const float* __restrict__ sdg,
                                            ushort_t* __restrict__ vout,
                                            float* __restrict__ zout,
                                            const int* __restrict__ rp,
                                            const int* __restrict__ eds,
                                            const int* __restrict__ perm) {
    int g = perm[blockIdx.x * 32 + (threadIdx.x >> 3)];
    int l = threadIdx.x & 7;
    int beg = rp[g], end = rp[g + 1];
    float a0[8] = {}, a1[8] = {}, a2[8] = {}, a3[8] = {};
    int e = beg;
    int head = (beg + 3) & ~3;
    if (head > end) head = end;
    for (; e < head; ++e) gath(a0, vin, eds[e], l);
    for (; e + 3 < end; e += 4) {
        int4 ee = *(const int4*)(eds + e);
        gath(a0, vin, ee.x, l);
        gath(a1, vin, ee.y, l);
        gath(a2, vin, ee.z, l);
        gath(a3, vin, ee.w, l);
    }
    for (; e < end; ++e) gath(a1, vin, eds[e], l);

    float w = wco[g];
    const int4 hb = *(const int4*)(hvb + ((size_t)g << 6) + (l << 3));
    float tv[8];
    tv[0] = __int_as_float(hb.x << 16);
    tv[1] = __int_as_float(hb.x & 0xffff0000);
    tv[2] = __int_as_float(hb.y << 16);
    tv[3] = __int_as_float(hb.y & 0xffff0000);
    tv[4] = __int_as_float(hb.z << 16);
    tv[5] = __int_as_float(hb.z & 0xffff0000);
    tv[6] = __int_as_float(hb.w << 16);
    tv[7] = __int_as_float(hb.w & 0xffff0000);
    float r[8];
#pragma unroll
    for (int c = 0; c < 8; ++c)
        r[c] = w * ((a0[c] + a1[c]) + (a2[c] + a3[c])) + tv[c];
    if (!LAST) {
        s16x8 o;
#pragma unroll
        for (int c = 0; c < 8; ++c) o[c] = f2bf(r[c]);
        *(s16x8*)(vout + ((size_t)g << 6) + (l << 3)) = o;
    } else {
        float sd = sdg[g];
#pragma unroll
        for (int c = 0; c < 8; ++c) r[c] *= sd;
        float m = r[0];
#pragma unroll
        for (int c = 1; c < 8; ++c) m = fmaxf(m, r[c]);
#pragma unroll
        for (int off = 1; off < 8; off <<= 1) m = fmaxf(m, __shfl_xor(m, off));
        float s = 0.f;
#pragma unroll
        for (int c = 0; c < 8; ++c) s += expf(r[c] - m);
#pragma unroll
        for (int off = 1; off < 8; off <<= 1) s += __shfl_xor(s, off);
        float ls = m + logf(s);
        f32x4 o0, o1;
#pragma unroll
        for (int c = 0; c < 4; ++c) { o0[c] = r[c] - ls; o1[c] = r[c + 4] - ls; }
        *(f32x4*)(zout + ((size_t)g << 6) + (l << 3)) = o0;
        *(f32x4*)(zout + ((size_t)g << 6) + (l << 3) + 4) = o1;
    }
}

extern "C" void kernel_launch(void* const* d_in, const int* in_sizes, int n_in,
                              void* d_out, int out_size, void* d_ws, size_t ws_size,
                              hipStream_t stream) {
    const float* x  = (const float*)d_in[0];
    const float* w0 = (const float*)d_in[1];
    const float* b0 = (const float*)d_in[2];
    const float* w1 = (const float*)d_in[3];
    const float* b1 = (const float*)d_in[4];
    const int*   ei = (const int*)d_in[5];

    char* ws = (char*)d_ws;
    size_t off = 0;
    auto take = [&](size_t n) { size_t r = off; off += (n + 255) & ~(size_t)255; return r; };
    size_t o_h0    = take((size_t)100096 * HH * 2);   // bf16 h0; later reused as vB
    size_t o_vA    = take((size_t)NN * CC * 2);       // bf16 v ping buffer
    size_t o_hv    = take((size_t)NN * CC * 2);       // bf16 0.1*dinv*h; earlier aliased as stg
    size_t o_ed    = take((size_t)(EE + NN) * 4);     // CSR src indices
    size_t o_rp    = take((size_t)(NN + 1) * 4);
    size_t o_cnt   = take((size_t)NN * 4);
    size_t o_dinv  = take((size_t)NN * 4);
    size_t o_wco   = take((size_t)NN * 4);
    size_t o_sdg   = take((size_t)NN * 4);
    size_t o_perm  = take((size_t)NN * 4);
    size_t o_w0t   = take((size_t)HH * FIN * 2);
    size_t o_w1t   = take((size_t)CC * HH * 2);
    size_t o_eboff = take((size_t)NBUC * 4);
    size_t o_dboff = take((size_t)64 * 4);
    size_t o_z     = take((size_t)(NBUC + NBUC + 64 + 64) * 4);  // bcnt,bfc,dbc,dfc (zeroed)
    size_t o_xb    = take((size_t)100096 * FIN * 2);  // bf16 x

    short*    h0    = (short*)(ws + o_h0);
    ushort_t* vA    = (ushort_t*)(ws + o_vA);
    ushort_t* vB    = (ushort_t*)(ws + o_h0);   // alias h0 (dead after gemm2)
    ushort_t* hvb   = (ushort_t*)(ws + o_hv);
    int*      stg   = (int*)(ws + o_hv);        // alias hvb (stg dead before gemm2 writes hvb)
    int*      eds   = (int*)(ws + o_ed);
    int*      rp    = (int*)(ws + o_rp);
    int*      cnt   = (int*)(ws + o_cnt);
    float*    dinv  = (float*)(ws + o_dinv);
    float*    wco   = (float*)(ws + o_wco);
    float*    sdg   = (float*)(ws + o_sdg);
    int*      perm  = (int*)(ws + o_perm);
    short*    w0t   = (short*)(ws + o_w0t);
    short*    w1t   = (short*)(ws + o_w1t);
    int*      eboff = (int*)(ws + o_eboff);
    int*      dboff = (int*)(ws + o_dboff);
    int*      bcnt  = (int*)(ws + o_z);
    int*      bfc   = bcnt + NBUC;
    int*      dbc   = bfc + NBUC;
    int*      dfc   = dbc + 64;
    ushort_t* xb    = (ushort_t*)(ws + o_xb);
    float*    zout  = (float*)d_out;

    hipMemsetAsync(ws + o_z, 0, (size_t)(NBUC + NBUC + 64 + 64) * 4, stream);

    fused1<<<NB_X2B + NEB + NB_PREP, 256, 0, stream>>>(x, xb, ei, bcnt, w0, w1, w0t, w1t);
    bscan<<<1, 1024, 0, stream>>>(bcnt, eboff);
    fused3<<<NBUC * 3, 256, 0, stream>>>(ei, eboff, bfc, stg, xb, w0t, b0, h0);
    bucket_finish<<<NBUC, 256, 0, stream>>>(stg, eboff, bcnt, cnt, dinv, wco, sdg, rp, eds, dbc);
    dscan<<<1, 64, 0, stream>>>(dbc, dboff);
    dperm<<<SB, 256, 0, stream>>>(cnt, dboff, dfc, perm);

    gemm2<<<782, 256, 0, stream>>>(h0, w1t, b1, dinv, hvb, vA);

    const ushort_t* in = vA;
    for (int k = 0; k < KSTEPS; ++k) {
        if (k == KSTEPS - 1) {
            prop<1><<<NN / 32, 256, 0, stream>>>(in, hvb, wco, sdg, nullptr, zout, rp, eds, perm);
        } else {
            ushort_t* o = (k & 1) ? vA : vB;
            prop<0><<<NN / 32, 256, 0, stream>>>(in, hvb, wco, sdg, o, nullptr, rp, eds, perm);
            in = o;
        }
    }
}

// Round 14
// 816.114 us; speedup vs baseline: 2.3621x; 1.0046x over previous
//
#include <hip/hip_runtime.h>
#include <hip/hip_bf16.h>

#define NN 100000
#define EE 3200000
#define FIN 512
#define HH 256
#define CC 64
#define KSTEPS 10
#define SB 391    // ceil(NN/256)
#define NBUC 782  // ceil(NN/128)
#define EPB 4096  // edges per block in binning kernels
#define NEB 782   // ceil(EE/EPB)
#define NB_X2B 2048
#define NB_PREP 576   // ceil((FIN*HH + HH*CC)/256)

typedef __attribute__((ext_vector_type(8))) short bf16x8;
typedef __attribute__((ext_vector_type(8))) short s16x8;
typedef __attribute__((ext_vector_type(4))) float f32x4;
typedef unsigned short ushort_t;

__device__ __forceinline__ short f2bf(float f) {
    union { __hip_bfloat16 h; short s; } u;
    u.h = __float2bfloat16(f);
    return u.s;
}

__device__ __forceinline__ void glds16(const void* g, void* l) {
    __builtin_amdgcn_global_load_lds(
        (const __attribute__((address_space(1))) void*)g,
        (__attribute__((address_space(3))) void*)l, 16, 0, 0);
}

// ================= fused1 bodies (disjoint buffers, proven race-free) =================

__device__ void dev_x2b(int bx, const float* __restrict__ x, ushort_t* __restrict__ xb) {
    const long NTOT = (long)NN * FIN;
    const long stride = (long)NB_X2B * 256 * 8;
    for (long i = ((long)bx * 256 + threadIdx.x) * 8; i < NTOT; i += stride) {
        float4 a = *(const float4*)(x + i);
        float4 b = *(const float4*)(x + i + 4);
        s16x8 o;
        o[0] = f2bf(a.x); o[1] = f2bf(a.y); o[2] = f2bf(a.z); o[3] = f2bf(a.w);
        o[4] = f2bf(b.x); o[5] = f2bf(b.y); o[6] = f2bf(b.z); o[7] = f2bf(b.w);
        *(s16x8*)(xb + i) = o;
    }
}

__device__ void dev_prep_w(int bx, const float* __restrict__ w0, const float* __restrict__ w1,
                           short* __restrict__ w0t, short* __restrict__ w1t) {
    int t = bx * 256 + threadIdx.x;
    if (t < FIN * HH) {
        int k = t >> 8, n = t & 255;
        w0t[n * FIN + k] = f2bf(w0[t]);
    } else if (t < FIN * HH + HH * CC) {
        int u = t - FIN * HH;
        int k = u >> 6, n = u & 63;
        w1t[n * HH + k] = f2bf(w1[u]);
    }
}

__device__ void dev_bincnt(int bx, const int* __restrict__ ei, int* __restrict__ bcnt,
                           int* __restrict__ hb) {
    int tid = threadIdx.x;
    int base = bx * EPB;
    for (int i = tid; i < NBUC; i += 256) hb[i] = 0;
    __syncthreads();
#pragma unroll 4
    for (int i = 0; i < EPB / 256; ++i) {
        int t = base + i * 256 + tid;
        if (t < EE) atomicAdd(&hb[(unsigned)ei[EE + t] >> 7], 1);
    }
    __syncthreads();
    for (int i = tid; i < NBUC; i += 256)
        if (hb[i]) atomicAdd(&bcnt[i], hb[i]);
}

__global__ __launch_bounds__(256) void fused1(const float* __restrict__ x,
                                              ushort_t* __restrict__ xb,
                                              const int* __restrict__ ei,
                                              int* __restrict__ bcnt,
                                              const float* __restrict__ w0,
                                              const float* __restrict__ w1,
                                              short* __restrict__ w0t,
                                              short* __restrict__ w1t) {
    __shared__ int hb[NBUC];
    int bx = blockIdx.x;
    if (bx < NB_X2B) dev_x2b(bx, x, xb);
    else if (bx < NB_X2B + NEB) dev_bincnt(bx - NB_X2B, ei, bcnt, hb);
    else dev_prep_w(bx - NB_X2B - NEB, w0, w1, w0t, w1t);
}

// ================= CSR build =================

__global__ __launch_bounds__(1024) void bscan(const int* __restrict__ bcnt,
                                              int* __restrict__ eboff) {
    __shared__ int sh[1024];
    int t = threadIdx.x;
    int v = (t < NBUC) ? bcnt[t] : 0;
    sh[t] = v;
    __syncthreads();
    for (int off = 1; off < 1024; off <<= 1) {
        int add = (t >= off) ? sh[t - off] : 0;
        __syncthreads();
        sh[t] += add;
        __syncthreads();
    }
    if (t < NBUC) eboff[t] = sh[t] - v;
}

__device__ void dev_binfill(int bx, const int* __restrict__ ei, const int* __restrict__ eboff,
                            int* __restrict__ bfc, int* __restrict__ stg, int* pool) {
    int* hb = pool;
    int* lb = pool + NBUC;
    int tid = threadIdx.x;
    int base = bx * EPB;
    for (int i = tid; i < NBUC; i += 256) hb[i] = 0;
    __syncthreads();
#pragma unroll 4
    for (int i = 0; i < EPB / 256; ++i) {
        int t = base + i * 256 + tid;
        if (t < EE) atomicAdd(&hb[(unsigned)ei[EE + t] >> 7], 1);
    }
    __syncthreads();
    for (int i = tid; i < NBUC; i += 256) {
        int c = hb[i];
        lb[i] = eboff[i] + (c ? atomicAdd(&bfc[i], c) : 0);
        hb[i] = 0;
    }
    __syncthreads();
#pragma unroll 4
    for (int i = 0; i < EPB / 256; ++i) {
        int t = base + i * 256 + tid;
        if (t < EE) {
            int s = ei[t];
            int d = ei[EE + t];
            int b = (unsigned)d >> 7;
            int o = atomicAdd(&hb[b], 1);
            stg[lb[b] + o] = (s << 7) | (d & 127);
        }
    }
}

__device__ void dev_gemm1(int g1, const ushort_t* __restrict__ xb,
                          const short* __restrict__ w0t, const float* __restrict__ b0,
                          short* __restrict__ h0, char* sm) {
    short* AsP = (short*)sm;            // [2][8192]
    short* BsP = (short*)(sm + 32768);  // [2][8192]
    const int tid = threadIdx.x;
    const int lane = tid & 63;
    const int wid = tid >> 6;
    const int wm = wid >> 1, wn = wid & 1;
    const int bn0 = (g1 & 1) * 128;
    const long row0 = (long)(g1 >> 1) * 128;
    const int rl = lane >> 3;
    const int gko = (lane & 7) ^ rl;

    auto stage = [&](int kt, int buf) {
#pragma unroll
        for (int j = 0; j < 4; ++j) {
            int blk = wid * 4 + j;
            const ushort_t* g = xb + (row0 + blk * 8 + rl) * FIN + kt * 64 + gko * 8;
            glds16(g, &AsP[buf * 8192 + blk * 512]);
        }
#pragma unroll
        for (int j = 0; j < 4; ++j) {
            int blk = wid * 4 + j;
            const short* g = w0t + (size_t)(bn0 + blk * 8 + rl) * FIN + kt * 64 + gko * 8;
            glds16(g, &BsP[buf * 8192 + blk * 512]);
        }
    };

    f32x4 acc[4][4] = {};
    stage(0, 0);
    __syncthreads();
    for (int kt = 0; kt < FIN / 64; ++kt) {
        int cur = kt & 1;
        if (kt < FIN / 64 - 1) stage(kt + 1, cur ^ 1);
#pragma unroll
        for (int ks = 0; ks < 2; ++ks) {
            int ko = ks * 4 + (lane >> 4);
            int slot = ko ^ (lane & 7);
            bf16x8 af[4], bfr[4];
#pragma unroll
            for (int i = 0; i < 4; ++i) {
                int row = wm * 64 + i * 16 + (lane & 15);
                af[i] = *(const bf16x8*)(&AsP[cur * 8192 + (row * 8 + slot) * 8]);
            }
#pragma unroll
            for (int j = 0; j < 4; ++j) {
                int col = wn * 64 + j * 16 + (lane & 15);
                bfr[j] = *(const bf16x8*)(&BsP[cur * 8192 + (col * 8 + slot) * 8]);
            }
#pragma unroll
            for (int i = 0; i < 4; ++i)
#pragma unroll
                for (int j = 0; j < 4; ++j)
                    acc[i][j] = __builtin_amdgcn_mfma_f32_16x16x32_bf16(af[i], bfr[j], acc[i][j], 0, 0, 0);
        }
        __syncthreads();
    }
#pragma unroll
    for (int j = 0; j < 4; ++j) {
        int gcol = bn0 + wn * 64 + j * 16 + (lane & 15);
        float bias = b0[gcol];
#pragma unroll
        for (int i = 0; i < 4; ++i)
#pragma unroll
            for (int q = 0; q < 4; ++q) {
                long grow = row0 + wm * 64 + i * 16 + (lane >> 4) * 4 + q;
                float v = acc[i][j][q] + bias;
                if (v < 0.f) v = 0.f;
                h0[grow * HH + gcol] = f2bf(v);
            }
    }
}

__global__ __launch_bounds__(256) void fused3(const int* __restrict__ ei,
                                              const int* __restrict__ eboff,
                                              int* __restrict__ bfc,
                                              int* __restrict__ stg,
                                              const ushort_t* __restrict__ xb,
                                              const short* __restrict__ w0t,
                                              const float* __restrict__ b0,
                                              short* __restrict__ h0) {
    __shared__ __align__(16) char sm[65536];
    int bx = blockIdx.x, r = bx % 3, q = bx / 3;
    if (r == 2) dev_binfill(q, ei, eboff, bfc, stg, (int*)sm);
    else dev_gemm1(q * 2 + r, xb, w0t, b0, h0, sm);
}

__global__ __launch_bounds__(256) void bucket_finish(
    const int* __restrict__ stg, const int* __restrict__ eboff,
    const int* __restrict__ bcnt,
    int* __restrict__ cnt, float* __restrict__ dinv, float* __restrict__ wco,
    float* __restrict__ sdg, int* __restrict__ rp, int* __restrict__ eds,
    int* __restrict__ dbc) {
    __shared__ int nc8[128 * 8];
    __shared__ int nc[128];
    __shared__ int sc[128];
    __shared__ int lrp[128];
    __shared__ int h64[64];
    int b = blockIdx.x, tid = threadIdx.x;
    int nodes = min(128, NN - b * 128);
    for (int i = tid; i < 128 * 8; i += 256) nc8[i] = 0;
    if (tid < 64) h64[tid] = 0;
    __syncthreads();
    int s0 = eboff[b], n = bcnt[b];
    for (int i = tid; i < n; i += 256) {
        int e = stg[s0 + i];
        atomicAdd(&nc8[(e & 127) * 8 + ((e >> 7) >> 14)], 1);
    }
    __syncthreads();
    if (tid < 128) {
        int excl = 0;
#pragma unroll
        for (int r = 0; r < 8; ++r) {
            int c = nc8[tid * 8 + r];
            nc8[tid * 8 + r] = excl;
            excl += c;
        }
        nc[tid] = excl;
        sc[tid] = (tid < nodes) ? excl + 1 : 0;
    }
    __syncthreads();
    for (int off = 1; off < 128; off <<= 1) {
        int add = (tid < 128 && tid >= off) ? sc[tid - off] : 0;
        __syncthreads();
        if (tid < 128) sc[tid] += add;
        __syncthreads();
    }
    int base = eboff[b] + b * 128;
    if (tid < nodes) {
        int node = b * 128 + tid;
        int c = nc[tid];
        int excl = base + sc[tid] - (c + 1);
        lrp[tid] = excl;
        rp[node] = excl;
        cnt[node] = c;
        float fd = (float)(c + 1);
        dinv[node] = rsqrtf(fd);
        wco[node] = 0.9f / fd;
        sdg[node] = sqrtf(fd);
        atomicAdd(&h64[min(c, 63)], 1);
    }
    if (b == NBUC - 1 && tid == 0) rp[NN] = base + n + nodes;
    __syncthreads();
    if (tid < 64 && h64[tid]) atomicAdd(&dbc[tid], h64[tid]);
    for (int i = tid; i < n; i += 256) {
        int e = stg[s0 + i];
        int src = e >> 7, loc = e & 127;
        int o = atomicAdd(&nc8[loc * 8 + (src >> 14)], 1);
        eds[lrp[loc] + o] = src;
    }
    __syncthreads();
    if (tid < nodes) eds[lrp[tid] + nc[tid]] = b * 128 + tid;  // self loop (last slot)
}

__global__ void dscan(const int* __restrict__ dbc, int* __restrict__ dboff) {
    __shared__ int sh[64];
    int t = threadIdx.x;
    int v = dbc[t];
    sh[t] = v;
    __syncthreads();
    for (int off = 1; off < 64; off <<= 1) {
        int add = (t >= off) ? sh[t - off] : 0;
        __syncthreads();
        sh[t] += add;
        __syncthreads();
    }
    dboff[t] = sh[t] - v;
}

__global__ __launch_bounds__(256) void dperm(const int* __restrict__ cnt,
                                             const int* __restrict__ dboff,
                                             int* __restrict__ dfc,
                                             int* __restrict__ perm) {
    __shared__ int h[64];
    __shared__ int base[64];
    int tid = threadIdx.x;
    int i = blockIdx.x * 256 + tid;
    if (tid < 64) h[tid] = 0;
    __syncthreads();
    int bin = 0, r = 0;
    bool ok = i < NN;
    if (ok) {
        bin = min(cnt[i], 63);
        r = atomicAdd(&h[bin], 1);
    }
    __syncthreads();
    if (tid < 64) {
        int c = h[tid];
        base[tid] = dboff[tid] + (c ? atomicAdd(&dfc[tid], c) : 0);
    }
    __syncthreads();
    if (ok) perm[base[bin] + r] = i;
}

// ---------------- GEMM2: h = h0 @ w1 + b1; emits hvb = bf16(0.1*dinv*h) and v0 = bf16(dinv*h) ----
__global__ __launch_bounds__(256) void gemm2(const short* __restrict__ h0,
                                             const short* __restrict__ w1t,
                                             const float* __restrict__ b1,
                                             const float* __restrict__ dinv,
                                             ushort_t* __restrict__ hvb,
                                             ushort_t* __restrict__ v0) {
    __shared__ __align__(16) short As[2][128 * 64];
    __shared__ __align__(16) short Bs[2][64 * 64];
    const int tid = threadIdx.x;
    const int lane = tid & 63;
    const int wid = tid >> 6;
    const int wm = wid >> 1, wn = wid & 1;
    const long row0 = (long)blockIdx.x * 128;
    const int rl = lane >> 3;
    const int gko = (lane & 7) ^ rl;

    auto stage = [&](int kt, int buf) {
#pragma unroll
        for (int j = 0; j < 4; ++j) {
            int blk = wid * 4 + j;
            const short* g = h0 + (row0 + blk * 8 + rl) * HH + kt * 64 + gko * 8;
            glds16(g, &As[buf][blk * 512]);
        }
#pragma unroll
        for (int j = 0; j < 2; ++j) {
            int blk = wid * 2 + j;
            const short* g = w1t + (size_t)(blk * 8 + rl) * HH + kt * 64 + gko * 8;
            glds16(g, &Bs[buf][blk * 512]);
        }
    };

    f32x4 acc[4][2] = {};
    stage(0, 0);
    __syncthreads();
    for (int kt = 0; kt < HH / 64; ++kt) {
        int cur = kt & 1;
        if (kt < HH / 64 - 1) stage(kt + 1, cur ^ 1);
#pragma unroll
        for (int ks = 0; ks < 2; ++ks) {
            int ko = ks * 4 + (lane >> 4);
            int slot = ko ^ (lane & 7);
            bf16x8 af[4], bfr[2];
#pragma unroll
            for (int i = 0; i < 4; ++i) {
                int row = wm * 64 + i * 16 + (lane & 15);
                af[i] = *(const bf16x8*)(&As[cur][(row * 8 + slot) * 8]);
            }
#pragma unroll
            for (int j = 0; j < 2; ++j) {
                int col = wn * 32 + j * 16 + (lane & 15);
                bfr[j] = *(const bf16x8*)(&Bs[cur][(col * 8 + slot) * 8]);
            }
#pragma unroll
            for (int i = 0; i < 4; ++i)
#pragma unroll
                for (int j = 0; j < 2; ++j)
                    acc[i][j] = __builtin_amdgcn_mfma_f32_16x16x32_bf16(af[i], bfr[j], acc[i][j], 0, 0, 0);
        }
        __syncthreads();
    }
#pragma unroll
    for (int i = 0; i < 4; ++i)
#pragma unroll
        for (int j = 0; j < 2; ++j) {
            int col = wn * 32 + j * 16 + (lane & 15);
            float bias = b1[col];
#pragma unroll
            for (int q = 0; q < 4; ++q) {
                long grow = row0 + wm * 64 + i * 16 + (lane >> 4) * 4 + q;
                if (grow < NN) {
                    float hval = acc[i][j][q] + bias;
                    float dv = dinv[grow];
                    hvb[grow * CC + col] = (ushort_t)f2bf(0.1f * dv * hval);
                    v0[grow * CC + col] = (ushort_t)f2bf(dv * hval);
                }
            }
        }
}

// ---------------- propagation: 16 lanes/node, 4 ch/lane, 8-edge batches ----------------
__device__ __forceinline__ int2 grow2(const ushort_t* __restrict__ vin, int src, int l) {
    return *(const int2*)(vin + ((size_t)src << 6) + (l << 2));
}
__device__ __forceinline__ void acc2(float a[4], int2 r) {
    a[0] += __int_as_float(r.x << 16);
    a[1] += __int_as_float(r.x & 0xffff0000);
    a[2] += __int_as_float(r.y << 16);
    a[3] += __int_as_float(r.y & 0xffff0000);
}

template <int LAST>
__global__ __launch_bounds__(256) void prop(const ushort_t* __restrict__ vin,
                                            const ushort_t* __restrict__ hvb,
                                            const float* __restrict__ wco,
                                            const float* __restrict__ sdg,
                                            ushort_t* __restrict__ vout,
                                            float* __restrict__ zout,
                                            const int* __restrict__ rp,
                                            const int* __restrict__ eds,
                                            const int* __restrict__ perm) {
    int g = perm[blockIdx.x * 16 + (threadIdx.x >> 4)];
    int l = threadIdx.x & 15;                 // channels l*4 .. l*4+3
    int beg = rp[g], end = rp[g + 1];
    float a0[4] = {}, a1[4] = {}, a2[4] = {}, a3[4] = {};
    int e = beg;
    int head = (beg + 3) & ~3;
    if (head > end) head = end;
    for (; e < head; ++e) acc2(a0, grow2(vin, eds[e], l));
    // 8-edge batches: 8 gathers in flight before any consume
    for (; e + 7 < end; e += 8) {
        int4 ea = *(const int4*)(eds + e);
        int4 eb = *(const int4*)(eds + e + 4);
        int2 r0 = grow2(vin, ea.x, l);
        int2 r1 = grow2(vin, ea.y, l);
        int2 r2 = grow2(vin, ea.z, l);
        int2 r3 = grow2(vin, ea.w, l);
        int2 r4 = grow2(vin, eb.x, l);
        int2 r5 = grow2(vin, eb.y, l);
        int2 r6 = grow2(vin, eb.z, l);
        int2 r7 = grow2(vin, eb.w, l);
        acc2(a0, r0); acc2(a1, r1); acc2(a2, r2); acc2(a3, r3);
        acc2(a0, r4); acc2(a1, r5); acc2(a2, r6); acc2(a3, r7);
    }
    for (; e + 3 < end; e += 4) {
        int4 ea = *(const int4*)(eds + e);
        int2 r0 = grow2(vin, ea.x, l);
        int2 r1 = grow2(vin, ea.y, l);
        int2 r2 = grow2(vin, ea.z, l);
        int2 r3 = grow2(vin, ea.w, l);
        acc2(a0, r0); acc2(a1, r1); acc2(a2, r2); acc2(a3, r3);
    }
    for (; e < end; ++e) acc2(a1, grow2(vin, eds[e], l));

    float w = wco[g];
    const int2 hb = *(const int2*)(hvb + ((size_t)g << 6) + (l << 2));
    float tv[4];
    tv[0] = __int_as_float(hb.x << 16);
    tv[1] = __int_as_float(hb.x & 0xffff0000);
    tv[2] = __int_as_float(hb.y << 16);
    tv[3] = __int_as_float(hb.y & 0xffff0000);
    float r[4];
#pragma unroll
    for (int c = 0; c < 4; ++c)
        r[c] = w * ((a0[c] + a1[c]) + (a2[c] + a3[c])) + tv[c];
    if (!LAST) {
        int o0 = ((int)(unsigned short)f2bf(r[0])) | (((int)(unsigned short)f2bf(r[1])) << 16);
        int o1 = ((int)(unsigned short)f2bf(r[2])) | (((int)(unsigned short)f2bf(r[3])) << 16);
        *(int2*)(vout + ((size_t)g << 6) + (l << 2)) = make_int2(o0, o1);
    } else {
        float sd = sdg[g];
#pragma unroll
        for (int c = 0; c < 4; ++c) r[c] *= sd;
        float m = fmaxf(fmaxf(r[0], r[1]), fmaxf(r[2], r[3]));
#pragma unroll
        for (int off = 1; off < 16; off <<= 1) m = fmaxf(m, __shfl_xor(m, off));
        float s = expf(r[0] - m) + expf(r[1] - m) + expf(r[2] - m) + expf(r[3] - m);
#pragma unroll
        for (int off = 1; off < 16; off <<= 1) s += __shfl_xor(s, off);
        float ls = m + logf(s);
        f32x4 o;
#pragma unroll
        for (int c = 0; c < 4; ++c) o[c] = r[c] - ls;
        *(f32x4*)(zout + ((size_t)g << 6) + (l << 2)) = o;
    }
}

extern "C" void kernel_launch(void* const* d_in, const int* in_sizes, int n_in,
                              void* d_out, int out_size, void* d_ws, size_t ws_size,
                              hipStream_t stream) {
    const float* x  = (const float*)d_in[0];
    const float* w0 = (const float*)d_in[1];
    const float* b0 = (const float*)d_in[2];
    const float* w1 = (const float*)d_in[3];
    const float* b1 = (const float*)d_in[4];
    const int*   ei = (const int*)d_in[5];

    char* ws = (char*)d_ws;
    size_t off = 0;
    auto take = [&](size_t n) { size_t r = off; off += (n + 255) & ~(size_t)255; return r; };
    size_t o_h0    = take((size_t)100096 * HH * 2);   // bf16 h0; later reused as vB
    size_t o_vA    = take((size_t)NN * CC * 2);       // bf16 v ping buffer
    size_t o_hv    = take((size_t)NN * CC * 2);       // bf16 0.1*dinv*h; earlier aliased as stg
    size_t o_ed    = take((size_t)(EE + NN) * 4);     // CSR src indices
    size_t o_rp    = take((size_t)(NN + 1) * 4);
    size_t o_cnt   = take((size_t)NN * 4);
    size_t o_dinv  = take((size_t)NN * 4);
    size_t o_wco   = take((size_t)NN * 4);
    size_t o_sdg   = take((size_t)NN * 4);
    size_t o_perm  = take((size_t)NN * 4);
    size_t o_w0t   = take((size_t)HH * FIN * 2);
    size_t o_w1t   = take((size_t)CC * HH * 2);
    size_t o_eboff = take((size_t)NBUC * 4);
    size_t o_dboff = take((size_t)64 * 4);
    size_t o_z     = take((size_t)(NBUC + NBUC + 64 + 64) * 4);  // bcnt,bfc,dbc,dfc (zeroed)
    size_t o_xb    = take((size_t)100096 * FIN * 2);  // bf16 x

    short*    h0    = (short*)(ws + o_h0);
    ushort_t* vA    = (ushort_t*)(ws + o_vA);
    ushort_t* vB    = (ushort_t*)(ws + o_h0);   // alias h0 (dead after gemm2)
    ushort_t* hvb   = (ushort_t*)(ws + o_hv);
    int*      stg   = (int*)(ws + o_hv);        // alias hvb (stg dead before gemm2 writes hvb)
    int*      eds   = (int*)(ws + o_ed);
    int*      rp    = (int*)(ws + o_rp);
    int*      cnt   = (int*)(ws + o_cnt);
    float*    dinv  = (float*)(ws + o_dinv);
    float*    wco   = (float*)(ws + o_wco);
    float*    sdg   = (float*)(ws + o_sdg);
    int*      perm  = (int*)(ws + o_perm);
    short*    w0t   = (short*)(ws + o_w0t);
    short*    w1t   = (short*)(ws + o_w1t);
    int*      eboff = (int*)(ws + o_eboff);
    int*      dboff = (int*)(ws + o_dboff);
    int*      bcnt  = (int*)(ws + o_z);
    int*      bfc   = bcnt + NBUC;
    int*      dbc   = bfc + NBUC;
    int*      dfc   = dbc + 64;
    ushort_t* xb    = (ushort_t*)(ws + o_xb);
    float*    zout  = (float*)d_out;

    hipMemsetAsync(ws + o_z, 0, (size_t)(NBUC + NBUC + 64 + 64) * 4, stream);

    fused1<<<NB_X2B + NEB + NB_PREP, 256, 0, stream>>>(x, xb, ei, bcnt, w0, w1, w0t, w1t);
    bscan<<<1, 1024, 0, stream>>>(bcnt, eboff);
    fused3<<<NBUC * 3, 256, 0, stream>>>(ei, eboff, bfc, stg, xb, w0t, b0, h0);
    bucket_finish<<<NBUC, 256, 0, stream>>>(stg, eboff, bcnt, cnt, dinv, wco, sdg, rp, eds, dbc);
    dscan<<<1, 64, 0, stream>>>(dbc, dboff);
    dperm<<<SB, 256, 0, stream>>>(cnt, dboff, dfc, perm);

    gemm2<<<782, 256, 0, stream>>>(h0, w1t, b1, dinv, hvb, vA);

    const ushort_t* in = vA;
    for (int k = 0; k < KSTEPS; ++k) {
        if (k == KSTEPS - 1) {
            prop<1><<<NN / 16, 256, 0, stream>>>(in, hvb, wco, sdg, nullptr, zout, rp, eds, perm);
        } else {
            ushort_t* o = (k & 1) ? vA : vB;
            prop<0><<<NN / 16, 256, 0, stream>>>(in, hvb, wco, sdg, o, nullptr, rp, eds, perm);
            in = o;
        }
    }
}

// Round 15
// 807.385 us; speedup vs baseline: 2.3876x; 1.0108x over previous
//
#include <hip/hip_runtime.h>
#include <hip/hip_bf16.h>

#define NN 100000
#define EE 3200000
#define FIN 512
#define HH 256
#define CC 64
#define KSTEPS 10
#define SB 391    // ceil(NN/256)
#define NBUC 782  // ceil(NN/128)
#define EPB 4096  // edges per block in binning kernels
#define NEB 782   // ceil(EE/EPB)
#define NB_X2B 2048
#define NB_PREP 576   // ceil((FIN*HH + HH*CC)/256)
#define NRNG 16   // range bins (src>>13 -> 13 used)

typedef __attribute__((ext_vector_type(8))) short bf16x8;
typedef __attribute__((ext_vector_type(8))) short s16x8;
typedef __attribute__((ext_vector_type(4))) float f32x4;
typedef unsigned short ushort_t;

__device__ __forceinline__ short f2bf(float f) {
    union { __hip_bfloat16 h; short s; } u;
    u.h = __float2bfloat16(f);
    return u.s;
}

__device__ __forceinline__ void glds16(const void* g, void* l) {
    __builtin_amdgcn_global_load_lds(
        (const __attribute__((address_space(1))) void*)g,
        (__attribute__((address_space(3))) void*)l, 16, 0, 0);
}

// ================= fused1 bodies (disjoint buffers, proven race-free) =================

__device__ void dev_x2b(int bx, const float* __restrict__ x, ushort_t* __restrict__ xb) {
    const long NTOT = (long)NN * FIN;
    const long stride = (long)NB_X2B * 256 * 8;
    for (long i = ((long)bx * 256 + threadIdx.x) * 8; i < NTOT; i += stride) {
        float4 a = *(const float4*)(x + i);
        float4 b = *(const float4*)(x + i + 4);
        s16x8 o;
        o[0] = f2bf(a.x); o[1] = f2bf(a.y); o[2] = f2bf(a.z); o[3] = f2bf(a.w);
        o[4] = f2bf(b.x); o[5] = f2bf(b.y); o[6] = f2bf(b.z); o[7] = f2bf(b.w);
        *(s16x8*)(xb + i) = o;
    }
}

__device__ void dev_prep_w(int bx, const float* __restrict__ w0, const float* __restrict__ w1,
                           short* __restrict__ w0t, short* __restrict__ w1t) {
    int t = bx * 256 + threadIdx.x;
    if (t < FIN * HH) {
        int k = t >> 8, n = t & 255;
        w0t[n * FIN + k] = f2bf(w0[t]);
    } else if (t < FIN * HH + HH * CC) {
        int u = t - FIN * HH;
        int k = u >> 6, n = u & 63;
        w1t[n * HH + k] = f2bf(w1[u]);
    }
}

__device__ void dev_bincnt(int bx, const int* __restrict__ ei, int* __restrict__ bcnt,
                           int* __restrict__ hb) {
    int tid = threadIdx.x;
    int base = bx * EPB;
    for (int i = tid; i < NBUC; i += 256) hb[i] = 0;
    __syncthreads();
#pragma unroll 4
    for (int i = 0; i < EPB / 256; ++i) {
        int t = base + i * 256 + tid;
        if (t < EE) atomicAdd(&hb[(unsigned)ei[EE + t] >> 7], 1);
    }
    __syncthreads();
    for (int i = tid; i < NBUC; i += 256)
        if (hb[i]) atomicAdd(&bcnt[i], hb[i]);
}

__global__ __launch_bounds__(256) void fused1(const float* __restrict__ x,
                                              ushort_t* __restrict__ xb,
                                              const int* __restrict__ ei,
                                              int* __restrict__ bcnt,
                                              const float* __restrict__ w0,
                                              const float* __restrict__ w1,
                                              short* __restrict__ w0t,
                                              short* __restrict__ w1t) {
    __shared__ int hb[NBUC];
    int bx = blockIdx.x;
    if (bx < NB_X2B) dev_x2b(bx, x, xb);
    else if (bx < NB_X2B + NEB) dev_bincnt(bx - NB_X2B, ei, bcnt, hb);
    else dev_prep_w(bx - NB_X2B - NEB, w0, w1, w0t, w1t);
}

// ================= CSR build =================

__global__ __launch_bounds__(1024) void bscan(const int* __restrict__ bcnt,
                                              int* __restrict__ eboff) {
    __shared__ int sh[1024];
    int t = threadIdx.x;
    int v = (t < NBUC) ? bcnt[t] : 0;
    sh[t] = v;
    __syncthreads();
    for (int off = 1; off < 1024; off <<= 1) {
        int add = (t >= off) ? sh[t - off] : 0;
        __syncthreads();
        sh[t] += add;
        __syncthreads();
    }
    if (t < NBUC) eboff[t] = sh[t] - v;
}

__device__ void dev_binfill(int bx, const int* __restrict__ ei, const int* __restrict__ eboff,
                            int* __restrict__ bfc, int* __restrict__ stg, int* pool) {
    int* hb = pool;
    int* lb = pool + NBUC;
    int tid = threadIdx.x;
    int base = bx * EPB;
    for (int i = tid; i < NBUC; i += 256) hb[i] = 0;
    __syncthreads();
#pragma unroll 4
    for (int i = 0; i < EPB / 256; ++i) {
        int t = base + i * 256 + tid;
        if (t < EE) atomicAdd(&hb[(unsigned)ei[EE + t] >> 7], 1);
    }
    __syncthreads();
    for (int i = tid; i < NBUC; i += 256) {
        int c = hb[i];
        lb[i] = eboff[i] + (c ? atomicAdd(&bfc[i], c) : 0);
        hb[i] = 0;
    }
    __syncthreads();
#pragma unroll 4
    for (int i = 0; i < EPB / 256; ++i) {
        int t = base + i * 256 + tid;
        if (t < EE) {
            int s = ei[t];
            int d = ei[EE + t];
            int b = (unsigned)d >> 7;
            int o = atomicAdd(&hb[b], 1);
            stg[lb[b] + o] = (s << 7) | (d & 127);
        }
    }
}

__device__ void dev_gemm1(int g1, const ushort_t* __restrict__ xb,
                          const short* __restrict__ w0t, const float* __restrict__ b0,
                          short* __restrict__ h0, char* sm) {
    short* AsP = (short*)sm;            // [2][8192]
    short* BsP = (short*)(sm + 32768);  // [2][8192]
    const int tid = threadIdx.x;
    const int lane = tid & 63;
    const int wid = tid >> 6;
    const int wm = wid >> 1, wn = wid & 1;
    const int bn0 = (g1 & 1) * 128;
    const long row0 = (long)(g1 >> 1) * 128;
    const int rl = lane >> 3;
    const int gko = (lane & 7) ^ rl;

    auto stage = [&](int kt, int buf) {
#pragma unroll
        for (int j = 0; j < 4; ++j) {
            int blk = wid * 4 + j;
            const ushort_t* g = xb + (row0 + blk * 8 + rl) * FIN + kt * 64 + gko * 8;
            glds16(g, &AsP[buf * 8192 + blk * 512]);
        }
#pragma unroll
        for (int j = 0; j < 4; ++j) {
            int blk = wid * 4 + j;
            const short* g = w0t + (size_t)(bn0 + blk * 8 + rl) * FIN + kt * 64 + gko * 8;
            glds16(g, &BsP[buf * 8192 + blk * 512]);
        }
    };

    f32x4 acc[4][4] = {};
    stage(0, 0);
    __syncthreads();
    for (int kt = 0; kt < FIN / 64; ++kt) {
        int cur = kt & 1;
        if (kt < FIN / 64 - 1) stage(kt + 1, cur ^ 1);
#pragma unroll
        for (int ks = 0; ks < 2; ++ks) {
            int ko = ks * 4 + (lane >> 4);
            int slot = ko ^ (lane & 7);
            bf16x8 af[4], bfr[4];
#pragma unroll
            for (int i = 0; i < 4; ++i) {
                int row = wm * 64 + i * 16 + (lane & 15);
                af[i] = *(const bf16x8*)(&AsP[cur * 8192 + (row * 8 + slot) * 8]);
            }
#pragma unroll
            for (int j = 0; j < 4; ++j) {
                int col = wn * 64 + j * 16 + (lane & 15);
                bfr[j] = *(const bf16x8*)(&BsP[cur * 8192 + (col * 8 + slot) * 8]);
            }
#pragma unroll
            for (int i = 0; i < 4; ++i)
#pragma unroll
                for (int j = 0; j < 4; ++j)
                    acc[i][j] = __builtin_amdgcn_mfma_f32_16x16x32_bf16(af[i], bfr[j], acc[i][j], 0, 0, 0);
        }
        __syncthreads();
    }
#pragma unroll
    for (int j = 0; j < 4; ++j) {
        int gcol = bn0 + wn * 64 + j * 16 + (lane & 15);
        float bias = b0[gcol];
#pragma unroll
        for (int i = 0; i < 4; ++i)
#pragma unroll
            for (int q = 0; q < 4; ++q) {
                long grow = row0 + wm * 64 + i * 16 + (lane >> 4) * 4 + q;
                float v = acc[i][j][q] + bias;
                if (v < 0.f) v = 0.f;
                h0[grow * HH + gcol] = f2bf(v);
            }
    }
}

__global__ __launch_bounds__(256) void fused3(const int* __restrict__ ei,
                                              const int* __restrict__ eboff,
                                              int* __restrict__ bfc,
                                              int* __restrict__ stg,
                                              const ushort_t* __restrict__ xb,
                                              const short* __restrict__ w0t,
                                              const float* __restrict__ b0,
                                              short* __restrict__ h0) {
    __shared__ __align__(16) char sm[65536];
    int bx = blockIdx.x, r = bx % 3, q = bx / 3;
    if (r == 2) dev_binfill(q, ei, eboff, bfc, stg, (int*)sm);
    else dev_gemm1(q * 2 + r, xb, w0t, b0, h0, sm);
}

// per-bucket finish with 13x1MB src-range-ordered scatter
__global__ __launch_bounds__(256) void bucket_finish(
    const int* __restrict__ stg, const int* __restrict__ eboff,
    const int* __restrict__ bcnt,
    int* __restrict__ cnt, float* __restrict__ dinv, float* __restrict__ wco,
    float* __restrict__ sdg, int* __restrict__ rp, int* __restrict__ eds,
    int* __restrict__ dbc) {
    __shared__ int ncr[128 * NRNG];
    __shared__ int nc[128];
    __shared__ int sc[128];
    __shared__ int lrp[128];
    __shared__ int h64[64];
    int b = blockIdx.x, tid = threadIdx.x;
    int nodes = min(128, NN - b * 128);
    for (int i = tid; i < 128 * NRNG; i += 256) ncr[i] = 0;
    if (tid < 64) h64[tid] = 0;
    __syncthreads();
    int s0 = eboff[b], n = bcnt[b];
    for (int i = tid; i < n; i += 256) {
        int e = stg[s0 + i];
        atomicAdd(&ncr[(e & 127) * NRNG + ((e >> 7) >> 13)], 1);
    }
    __syncthreads();
    if (tid < 128) {
        int excl = 0;
#pragma unroll
        for (int r = 0; r < NRNG; ++r) {
            int c = ncr[tid * NRNG + r];
            ncr[tid * NRNG + r] = excl;
            excl += c;
        }
        nc[tid] = excl;
        sc[tid] = (tid < nodes) ? excl + 1 : 0;
    }
    __syncthreads();
    for (int off = 1; off < 128; off <<= 1) {
        int add = (tid < 128 && tid >= off) ? sc[tid - off] : 0;
        __syncthreads();
        if (tid < 128) sc[tid] += add;
        __syncthreads();
    }
    int base = eboff[b] + b * 128;
    if (tid < nodes) {
        int node = b * 128 + tid;
        int c = nc[tid];
        int excl = base + sc[tid] - (c + 1);
        lrp[tid] = excl;
        rp[node] = excl;
        cnt[node] = c;
        float fd = (float)(c + 1);
        dinv[node] = rsqrtf(fd);
        wco[node] = 0.9f / fd;
        sdg[node] = sqrtf(fd);
        atomicAdd(&h64[min(c, 63)], 1);
    }
    if (b == NBUC - 1 && tid == 0) rp[NN] = base + n + nodes;
    __syncthreads();
    if (tid < 64 && h64[tid]) atomicAdd(&dbc[tid], h64[tid]);
    for (int i = tid; i < n; i += 256) {
        int e = stg[s0 + i];
        int src = e >> 7, loc = e & 127;
        int o = atomicAdd(&ncr[loc * NRNG + (src >> 13)], 1);
        eds[lrp[loc] + o] = src;
    }
    __syncthreads();
    if (tid < nodes) eds[lrp[tid] + nc[tid]] = b * 128 + tid;  // self loop (last slot)
}

// ================= fused5: gemm2 ∥ dperm (disjoint buffers) =================

__device__ void dev_gemm2(int g2, const short* __restrict__ h0,
                          const short* __restrict__ w1t, const float* __restrict__ b1,
                          const float* __restrict__ dinv,
                          ushort_t* __restrict__ hvb, ushort_t* __restrict__ v0, char* sm) {
    short* AsP = (short*)sm;            // [2][8192]
    short* BsP = (short*)(sm + 32768);  // [2][4096]
    const int tid = threadIdx.x;
    const int lane = tid & 63;
    const int wid = tid >> 6;
    const int wm = wid >> 1, wn = wid & 1;
    const long row0 = (long)g2 * 128;
    const int rl = lane >> 3;
    const int gko = (lane & 7) ^ rl;

    auto stage = [&](int kt, int buf) {
#pragma unroll
        for (int j = 0; j < 4; ++j) {
            int blk = wid * 4 + j;
            const short* g = h0 + (row0 + blk * 8 + rl) * HH + kt * 64 + gko * 8;
            glds16(g, &AsP[buf * 8192 + blk * 512]);
        }
#pragma unroll
        for (int j = 0; j < 2; ++j) {
            int blk = wid * 2 + j;
            const short* g = w1t + (size_t)(blk * 8 + rl) * HH + kt * 64 + gko * 8;
            glds16(g, &BsP[buf * 4096 + blk * 512]);
        }
    };

    f32x4 acc[4][2] = {};
    stage(0, 0);
    __syncthreads();
    for (int kt = 0; kt < HH / 64; ++kt) {
        int cur = kt & 1;
        if (kt < HH / 64 - 1) stage(kt + 1, cur ^ 1);
#pragma unroll
        for (int ks = 0; ks < 2; ++ks) {
            int ko = ks * 4 + (lane >> 4);
            int slot = ko ^ (lane & 7);
            bf16x8 af[4], bfr[2];
#pragma unroll
            for (int i = 0; i < 4; ++i) {
                int row = wm * 64 + i * 16 + (lane & 15);
                af[i] = *(const bf16x8*)(&AsP[cur * 8192 + (row * 8 + slot) * 8]);
            }
#pragma unroll
            for (int j = 0; j < 2; ++j) {
                int col = wn * 32 + j * 16 + (lane & 15);
                bfr[j] = *(const bf16x8*)(&BsP[cur * 4096 + (col * 8 + slot) * 8]);
            }
#pragma unroll
            for (int i = 0; i < 4; ++i)
#pragma unroll
                for (int j = 0; j < 2; ++j)
                    acc[i][j] = __builtin_amdgcn_mfma_f32_16x16x32_bf16(af[i], bfr[j], acc[i][j], 0, 0, 0);
        }
        __syncthreads();
    }
#pragma unroll
    for (int i = 0; i < 4; ++i)
#pragma unroll
        for (int j = 0; j < 2; ++j) {
            int col = wn * 32 + j * 16 + (lane & 15);
            float bias = b1[col];
#pragma unroll
            for (int q = 0; q < 4; ++q) {
                long grow = row0 + wm * 64 + i * 16 + (lane >> 4) * 4 + q;
                if (grow < NN) {
                    float hval = acc[i][j][q] + bias;
                    float dv = dinv[grow];
                    hvb[grow * CC + col] = (ushort_t)f2bf(0.1f * dv * hval);
                    v0[grow * CC + col] = (ushort_t)f2bf(dv * hval);
                }
            }
        }
}

// dperm with per-block local scan of dbc (drops the dscan launch)
__device__ void dev_dperm(int bx, const int* __restrict__ cnt, const int* __restrict__ dbc,
                          int* __restrict__ dfc, int* __restrict__ perm, int* pool) {
    int* h    = pool;        // 64
    int* base = pool + 64;   // 64
    int* sh   = pool + 128;  // 64 (scan)
    int tid = threadIdx.x;
    if (tid < 64) { h[tid] = 0; sh[tid] = dbc[tid]; }
    __syncthreads();
    for (int off = 1; off < 64; off <<= 1) {
        int add = (tid < 64 && tid >= off) ? sh[tid - off] : 0;
        __syncthreads();
        if (tid < 64) sh[tid] += add;
        __syncthreads();
    }
    // sh now inclusive scan; exclusive offset = sh[t] - dbc[t]
    int i = bx * 256 + tid;
    int bin = 0, r = 0;
    bool ok = i < NN;
    if (ok) {
        bin = min(cnt[i], 63);
        r = atomicAdd(&h[bin], 1);
    }
    __syncthreads();
    if (tid < 64) {
        int c = h[tid];
        base[tid] = (sh[tid] - dbc[tid]) + (c ? atomicAdd(&dfc[tid], c) : 0);
    }
    __syncthreads();
    if (ok) perm[base[bin] + r] = i;
}

__global__ __launch_bounds__(256) void fused5(const short* __restrict__ h0,
                                              const short* __restrict__ w1t,
                                              const float* __restrict__ b1,
                                              const float* __restrict__ dinv,
                                              ushort_t* __restrict__ hvb,
                                              ushort_t* __restrict__ v0,
                                              const int* __restrict__ cnt,
                                              const int* __restrict__ dbc,
                                              int* __restrict__ dfc,
                                              int* __restrict__ perm) {
    __shared__ __align__(16) char sm[49152];
    int bx = blockIdx.x;
    if (bx < NBUC) dev_gemm2(bx, h0, w1t, b1, dinv, hvb, v0, sm);
    else dev_dperm(bx - NBUC, cnt, dbc, dfc, perm, (int*)sm);
}

// ---------------- propagation: 16 lanes/node, 4 ch/lane, 8-edge batches ----------------
__device__ __forceinline__ int2 grow2(const ushort_t* __restrict__ vin, int src, int l) {
    return *(const int2*)(vin + ((size_t)src << 6) + (l << 2));
}
__device__ __forceinline__ void acc2(float a[4], int2 r) {
    a[0] += __int_as_float(r.x << 16);
    a[1] += __int_as_float(r.x & 0xffff0000);
    a[2] += __int_as_float(r.y << 16);
    a[3] += __int_as_float(r.y & 0xffff0000);
}

template <int LAST>
__global__ __launch_bounds__(256) void prop(const ushort_t* __restrict__ vin,
                                            const ushort_t* __restrict__ hvb,
                                            const float* __restrict__ wco,
                                            const float* __restrict__ sdg,
                                            ushort_t* __restrict__ vout,
                                            float* __restrict__ zout,
                                            const int* __restrict__ rp,
                                            const int* __restrict__ eds,
                                            const int* __restrict__ perm) {
    int g = perm[blockIdx.x * 16 + (threadIdx.x >> 4)];
    int l = threadIdx.x & 15;
    int beg = rp[g], end = rp[g + 1];
    float a0[4] = {}, a1[4] = {}, a2[4] = {}, a3[4] = {};
    int e = beg;
    int head = (beg + 3) & ~3;
    if (head > end) head = end;
    for (; e < head; ++e) acc2(a0, grow2(vin, eds[e], l));
    for (; e + 7 < end; e += 8) {
        int4 ea = *(const int4*)(eds + e);
        int4 eb = *(const int4*)(eds + e + 4);
        int2 r0 = grow2(vin, ea.x, l);
        int2 r1 = grow2(vin, ea.y, l);
        int2 r2 = grow2(vin, ea.z, l);
        int2 r3 = grow2(vin, ea.w, l);
        int2 r4 = grow2(vin, eb.x, l);
        int2 r5 = grow2(vin, eb.y, l);
        int2 r6 = grow2(vin, eb.z, l);
        int2 r7 = grow2(vin, eb.w, l);
        acc2(a0, r0); acc2(a1, r1); acc2(a2, r2); acc2(a3, r3);
        acc2(a0, r4); acc2(a1, r5); acc2(a2, r6); acc2(a3, r7);
    }
    for (; e + 3 < end; e += 4) {
        int4 ea = *(const int4*)(eds + e);
        int2 r0 = grow2(vin, ea.x, l);
        int2 r1 = grow2(vin, ea.y, l);
        int2 r2 = grow2(vin, ea.z, l);
        int2 r3 = grow2(vin, ea.w, l);
        acc2(a0, r0); acc2(a1, r1); acc2(a2, r2); acc2(a3, r3);
    }
    for (; e < end; ++e) acc2(a1, grow2(vin, eds[e], l));

    float w = wco[g];
    const int2 hb = *(const int2*)(hvb + ((size_t)g << 6) + (l << 2));
    float tv[4];
    tv[0] = __int_as_float(hb.x << 16);
    tv[1] = __int_as_float(hb.x & 0xffff0000);
    tv[2] = __int_as_float(hb.y << 16);
    tv[3] = __int_as_float(hb.y & 0xffff0000);
    float r[4];
#pragma unroll
    for (int c = 0; c < 4; ++c)
        r[c] = w * ((a0[c] + a1[c]) + (a2[c] + a3[c])) + tv[c];
    if (!LAST) {
        int o0 = ((int)(unsigned short)f2bf(r[0])) | (((int)(unsigned short)f2bf(r[1])) << 16);
        int o1 = ((int)(unsigned short)f2bf(r[2])) | (((int)(unsigned short)f2bf(r[3])) << 16);
        *(int2*)(vout + ((size_t)g << 6) + (l << 2)) = make_int2(o0, o1);
    } else {
        float sd = sdg[g];
#pragma unroll
        for (int c = 0; c < 4; ++c) r[c] *= sd;
        float m = fmaxf(fmaxf(r[0], r[1]), fmaxf(r[2], r[3]));
#pragma unroll
        for (int off = 1; off < 16; off <<= 1) m = fmaxf(m, __shfl_xor(m, off));
        float s = expf(r[0] - m) + expf(r[1] - m) + expf(r[2] - m) + expf(r[3] - m);
#pragma unroll
        for (int off = 1; off < 16; off <<= 1) s += __shfl_xor(s, off);
        float ls = m + logf(s);
        f32x4 o;
#pragma unroll
        for (int c = 0; c < 4; ++c) o[c] = r[c] - ls;
        *(f32x4*)(zout + ((size_t)g << 6) + (l << 2)) = o;
    }
}

extern "C" void kernel_launch(void* const* d_in, const int* in_sizes, int n_in,
                              void* d_out, int out_size, void* d_ws, size_t ws_size,
                              hipStream_t stream) {
    const float* x  = (const float*)d_in[0];
    const float* w0 = (const float*)d_in[1];
    const float* b0 = (const float*)d_in[2];
    const float* w1 = (const float*)d_in[3];
    const float* b1 = (const float*)d_in[4];
    const int*   ei = (const int*)d_in[5];

    char* ws = (char*)d_ws;
    size_t off = 0;
    auto take = [&](size_t n) { size_t r = off; off += (n + 255) & ~(size_t)255; return r; };
    size_t o_h0    = take((size_t)100096 * HH * 2);   // bf16 h0; later reused as vB
    size_t o_vA    = take((size_t)NN * CC * 2);       // bf16 v ping buffer
    size_t o_hv    = take((size_t)NN * CC * 2);       // bf16 0.1*dinv*h; earlier aliased as stg
    size_t o_ed    = take((size_t)(EE + NN) * 4);     // CSR src indices
    size_t o_rp    = take((size_t)(NN + 1) * 4);
    size_t o_cnt   = take((size_t)NN * 4);
    size_t o_dinv  = take((size_t)NN * 4);
    size_t o_wco   = take((size_t)NN * 4);
    size_t o_sdg   = take((size_t)NN * 4);
    size_t o_perm  = take((size_t)NN * 4);
    size_t o_w0t   = take((size_t)HH * FIN * 2);
    size_t o_w1t   = take((size_t)CC * HH * 2);
    size_t o_eboff = take((size_t)NBUC * 4);
    size_t o_z     = take((size_t)(NBUC + NBUC + 64 + 64) * 4);  // bcnt,bfc,dbc,dfc (zeroed)
    size_t o_xb    = take((size_t)100096 * FIN * 2);  // bf16 x

    short*    h0    = (short*)(ws + o_h0);
    ushort_t* vA    = (ushort_t*)(ws + o_vA);
    ushort_t* vB    = (ushort_t*)(ws + o_h0);   // alias h0 (dead after fused5)
    ushort_t* hvb   = (ushort_t*)(ws + o_hv);
    int*      stg   = (int*)(ws + o_hv);        // alias hvb (stg dead before fused5 writes hvb)
    int*      eds   = (int*)(ws + o_ed);
    int*      rp    = (int*)(ws + o_rp);
    int*      cnt   = (int*)(ws + o_cnt);
    float*    dinv  = (float*)(ws + o_dinv);
    float*    wco   = (float*)(ws + o_wco);
    float*    sdg   = (float*)(ws + o_sdg);
    int*      perm  = (int*)(ws + o_perm);
    short*    w0t   = (short*)(ws + o_w0t);
    short*    w1t   = (short*)(ws + o_w1t);
    int*      eboff = (int*)(ws + o_eboff);
    int*      bcnt  = (int*)(ws + o_z);
    int*      bfc   = bcnt + NBUC;
    int*      dbc   = bfc + NBUC;
    int*      dfc   = dbc + 64;
    ushort_t* xb    = (ushort_t*)(ws + o_xb);
    float*    zout  = (float*)d_out;

    hipMemsetAsync(ws + o_z, 0, (size_t)(NBUC + NBUC + 64 + 64) * 4, stream);

    fused1<<<NB_X2B + NEB + NB_PREP, 256, 0, stream>>>(x, xb, ei, bcnt, w0, w1, w0t, w1t);
    bscan<<<1, 1024, 0, stream>>>(bcnt, eboff);
    fused3<<<NBUC * 3, 256, 0, stream>>>(ei, eboff, bfc, stg, xb, w0t, b0, h0);
    bucket_finish<<<NBUC, 256, 0, stream>>>(stg, eboff, bcnt, cnt, dinv, wco, sdg, rp, eds, dbc);
    fused5<<<NBUC + SB, 256, 0, stream>>>(h0, w1t, b1, dinv, hvb, vA, cnt, dbc, dfc, perm);

    const ushort_t* in = vA;
    for (int k = 0; k < KSTEPS; ++k) {
        if (k == KSTEPS - 1) {
            prop<1><<<NN / 16, 256, 0, stream>>>(in, hvb, wco, sdg, nullptr, zout, rp, eds, perm);
        } else {
            ushort_t* o = (k & 1) ? vA : vB;
            prop<0><<<NN / 16, 256, 0, stream>>>(in, hvb, wco, sdg, o, nullptr, rp, eds, perm);
            in = o;
        }
    }
}